// Round 3
// baseline (1309.975 us; speedup 1.0000x reference)
//
#include <hip/hip_runtime.h>
#include <math.h>

// Problem constants
#define BB    8
#define CIN   16
#define SS    1024
#define EE    128
#define HH    8
#define DHH   16
#define O1    512      // E*4
#define DFFN  512
#define K2TOT 8192     // O1*CIN

// Workspace layout (float offsets)
#define PE_OFF    0            // 131072  (S*E)
#define BN1SC_OFF 131072       // 512
#define BN1SH_OFF 131584       // 512
#define BN2SC_OFF 132096       // 128
#define BN2SH_OFF 132224       // 128
#define XSRC_OFF  262144       // 1048576 (B*S*E)
#define Q_OFF     1310720      // 1048576 (B,H,S,DH)
#define KK_OFF    2359296      // 1048576
#define V_OFF     3407872      // 1048576
#define ATTN_OFF  4456448      // 1048576 (B,S,E) pre-LN attention out
#define ATT_OFF   5505024      // 1048576 (B,S,E) post-LN1
#define FFH_OFF   6553600      // 4194304 (B*S,DFF)
// end: 10747904 floats = 43.0 MB

__device__ __forceinline__ float wave_sum(float v) {
    #pragma unroll
    for (int o = 32; o > 0; o >>= 1) v += __shfl_xor(v, o);
    return v;
}

__device__ __forceinline__ float gelu_exact(float x) {
    return 0.5f * x * (1.0f + erff(x * 0.7071067811865476f));
}

// ---------------- K0a: positional encoding table ----------------
__global__ __launch_bounds__(256) void k0_pe(float* __restrict__ ws) {
    int idx = blockIdx.x * 256 + threadIdx.x;   // 131072 total
    int s = idx >> 7, e = idx & 127;
    int i = e >> 1;
    // div = exp(2i * (-ln(10000)/128)), ang = s * div * (128/1024)
    float freq = expf((float)(2 * i) * (-9.210340371976184f / 128.0f));
    float ang = (float)s * freq * 0.125f;
    ws[PE_OFF + idx] = (e & 1) ? cosf(ang) : sinf(ang);
}

// ---------------- K0b: fold conv-bias + BN into scale/shift ----------------
__global__ void k0_bn(const float* __restrict__ conv1_b, const float* __restrict__ bn1_g,
                      const float* __restrict__ bn1_b, const float* __restrict__ bn1_m,
                      const float* __restrict__ bn1_v,
                      const float* __restrict__ conv2_b, const float* __restrict__ bn2_g,
                      const float* __restrict__ bn2_b, const float* __restrict__ bn2_m,
                      const float* __restrict__ bn2_v,
                      float* __restrict__ ws) {
    int t = threadIdx.x;
    if (t < 512) {
        float sc = bn1_g[t] * rsqrtf(bn1_v[t] + 1e-5f);
        ws[BN1SC_OFF + t] = sc;
        ws[BN1SH_OFF + t] = (conv1_b[t] - bn1_m[t]) * sc + bn1_b[t];
    } else if (t < 640) {
        int e = t - 512;
        float sc = bn2_g[e] * rsqrtf(bn2_v[e] + 1e-5f);
        ws[BN2SC_OFF + e] = sc;
        ws[BN2SH_OFF + e] = (conv2_b[e] - bn2_m[e]) * sc + bn2_b[e];
    }
}

// ---------------- K1: fused conv1+bn1+gelu -> conv2+bn2+gelu -> x_src ----------------
// grid (S/16, B), 256 threads. Recomputes h1 tiles (32 o at a time) in LDS,
// accumulates the K=8192 GEMM per (e, s), then bn2+gelu epilogue.
// LDS total: 1.5 + 16 + 4 + 34.8 KB = 56.8 KB -> 2 workgroups/CU.
#define TS1 16
#define OB1 32
__global__ __launch_bounds__(256) void k1_conv(const float* __restrict__ x,
                                               const float* __restrict__ w1,
                                               const float* __restrict__ w2,
                                               float* __restrict__ ws) {
    __shared__ float xt[CIN][24];                 // x[b, c, s0-3 .. s0+18]
    __shared__ float w1s[O1][8];
    __shared__ float sc1[O1], sh1[O1];
    __shared__ float hs[OB1 * CIN][TS1 + 1];      // [512][17] = 34.8 KB

    int b = blockIdx.y, s0 = blockIdx.x * TS1;
    int t = threadIdx.x;

    for (int i = t; i < CIN * 22; i += 256) {
        int c = i / 22, j = i % 22;
        int gs = s0 + j - 3;
        xt[c][j] = (gs >= 0 && gs < SS) ? x[(b * CIN + c) * SS + gs] : 0.f;
    }
    for (int i = t; i < O1 * 7; i += 256) w1s[i / 7][i % 7] = w1[i];
    for (int i = t; i < O1; i += 256) { sc1[i] = ws[BN1SC_OFF + i]; sh1[i] = ws[BN1SH_OFF + i]; }

    float acc[8];
    #pragma unroll
    for (int i = 0; i < 8; i++) acc[i] = 0.f;
    int s = t & 15, eg = t >> 4;
    int ebase = eg * 8;

    for (int o0 = 0; o0 < O1; o0 += OB1) {
        __syncthreads();
        // stage h1 chunk: kk = (o-o0)*16 + c in [0,512), s in [0,16)
        for (int idx = t; idx < OB1 * CIN * TS1; idx += 256) {
            int kk = idx >> 4, sj = idx & 15;
            int o = o0 + (kk >> 4), c = kk & 15;
            float pre = 0.f;
            #pragma unroll
            for (int u = 0; u < 7; u++) pre += w1s[o][u] * xt[c][sj + u];
            float hpre = pre * sc1[o] + sh1[o];
            hs[kk][sj] = gelu_exact(hpre);
        }
        __syncthreads();
        const float* w2p = w2 + o0 * CIN;   // w2[e][k], k = o*16+c
        for (int kk = 0; kk < OB1 * CIN; kk++) {
            float hv = hs[kk][s];
            #pragma unroll
            for (int i = 0; i < 8; i++)
                acc[i] += hv * w2p[(ebase + i) * K2TOT + kk];
        }
    }

    int srow = s0 + s;
    float* xsrc = ws + XSRC_OFF + ((size_t)(b * SS + srow)) * EE;
    #pragma unroll
    for (int i = 0; i < 8; i++) {
        int e = ebase + i;
        float h2 = acc[i] * ws[BN2SC_OFF + e] + ws[BN2SH_OFF + e];
        xsrc[e] = gelu_exact(h2);
    }
}

// ---------------- K2: QKV projection (adds PE on the fly) ----------------
// grid (B*S/16), 256 threads; 16 rows per block, outputs in (B,H,S,DH).
__global__ __launch_bounds__(256) void k2_qkv(const float* __restrict__ wq,
                                              const float* __restrict__ wk,
                                              const float* __restrict__ wv,
                                              float* __restrict__ ws) {
    __shared__ float xs[16][128];
    int bs0 = blockIdx.x * 16;
    int t = threadIdx.x;
    for (int i = t; i < 16 * 128; i += 256) {
        int r = i >> 7, d = i & 127;
        int bs = bs0 + r;
        int sl = bs & (SS - 1);
        xs[r][d] = ws[XSRC_OFF + (size_t)bs * EE + d] + ws[PE_OFF + sl * EE + d];
    }
    __syncthreads();
    int e = t & 127, rg = t >> 7;
    float aq[8], ak[8], av[8];
    #pragma unroll
    for (int i = 0; i < 8; i++) { aq[i] = 0.f; ak[i] = 0.f; av[i] = 0.f; }
    for (int d = 0; d < 128; d++) {
        float wqv = wq[e * 128 + d], wkv = wk[e * 128 + d], wvv = wv[e * 128 + d];
        #pragma unroll
        for (int r = 0; r < 8; r++) {
            float xv = xs[rg * 8 + r][d];
            aq[r] += xv * wqv; ak[r] += xv * wkv; av[r] += xv * wvv;
        }
    }
    int h = e >> 4, d2 = e & 15;
    #pragma unroll
    for (int r = 0; r < 8; r++) {
        int bs = bs0 + rg * 8 + r;
        int bb = bs >> 10, sl = bs & 1023;
        size_t off = (((size_t)(bb * HH + h)) * SS + sl) * DHH + d2;
        ws[Q_OFF + off] = aq[r];
        ws[KK_OFF + off] = ak[r];
        ws[V_OFF + off] = av[r];
    }
}

// ---------------- K3: attention, one thread per q-row ----------------
// out_i = (sum_j p_ij v_j)/l_i + sum_j bias(i-j) v_j   (bias added AFTER softmax)
__global__ __launch_bounds__(256) void k3_attn(const float* __restrict__ rel_tab,
                                               float* __restrict__ ws) {
    __shared__ float kt[64][16];
    __shared__ float vt[64][16];
    __shared__ float tbl[1280];
    int bh = blockIdx.x;            // b*H + h
    int i0 = blockIdx.y * 256;
    int h = bh & 7;
    int t = threadIdx.x;
    for (int r = t; r < 1279; r += 256) tbl[r] = rel_tab[(i0 + r) * HH + h];

    int i = i0 + t;
    const float* qp = ws + Q_OFF + ((size_t)bh * SS + i) * DHH;
    float q[16], U[16], Bv[16];
    #pragma unroll
    for (int d = 0; d < 16; d++) { q[d] = qp[d]; U[d] = 0.f; Bv[d] = 0.f; }
    float m = -1e30f, l = 0.f;
    const float scale = 0.08838834764831845f;   // 128^-0.5
    const float* kbase = ws + KK_OFF + (size_t)bh * SS * DHH;
    const float* vbase = ws + V_OFF + (size_t)bh * SS * DHH;

    for (int j0 = 0; j0 < SS; j0 += 64) {
        __syncthreads();
        for (int idx = t; idx < 64 * 16; idx += 256) {
            ((float*)kt)[idx] = kbase[j0 * 16 + idx];
            ((float*)vt)[idx] = vbase[j0 * 16 + idx];
        }
        __syncthreads();
        for (int jj = 0; jj < 64; jj++) {
            float sdot = 0.f;
            #pragma unroll
            for (int d = 0; d < 16; d++) sdot += q[d] * kt[jj][d];
            sdot *= scale;
            float p;
            if (sdot > m) {
                float f = __expf(m - sdot);
                l *= f;
                #pragma unroll
                for (int d = 0; d < 16; d++) U[d] *= f;
                m = sdot;
                p = 1.f;
            } else {
                p = __expf(sdot - m);
            }
            l += p;
            float bvv = tbl[t + 1023 - (j0 + jj)];
            #pragma unroll
            for (int d = 0; d < 16; d++) {
                U[d] += p * vt[jj][d];
                Bv[d] += bvv * vt[jj][d];
            }
        }
    }
    float inv_l = 1.f / l;
    int b = bh >> 3;
    float* op = ws + ATTN_OFF + ((size_t)(b * SS) + i) * EE + h * DHH;
    #pragma unroll
    for (int d = 0; d < 16; d++) op[d] = U[d] * inv_l + Bv[d];
}

// ---------------- K4: LN(attn) -> +x_src -> LN1 -> att ----------------
__global__ __launch_bounds__(256) void k4_ln(const float* __restrict__ g_attn, const float* __restrict__ b_attn,
                                             const float* __restrict__ g1, const float* __restrict__ b1,
                                             float* __restrict__ ws) {
    int row = blockIdx.x * 4 + (threadIdx.x >> 6);
    int lane = threadIdx.x & 63;
    int e0 = lane * 2;
    const float* ain = ws + ATTN_OFF + (size_t)row * EE;
    const float* xsr = ws + XSRC_OFF + (size_t)row * EE;
    float2 a = *(const float2*)(ain + e0);
    float mean = wave_sum(a.x + a.y) * (1.f / 128.f);
    float dx = a.x - mean, dy = a.y - mean;
    float var = wave_sum(dx * dx + dy * dy) * (1.f / 128.f);
    float inv = rsqrtf(var + 1e-5f);
    float n0 = dx * inv * g_attn[e0] + b_attn[e0];
    float n1 = dy * inv * g_attn[e0 + 1] + b_attn[e0 + 1];
    float2 xs2 = *(const float2*)(xsr + e0);
    float z0 = xs2.x + n0, z1 = xs2.y + n1;
    float m2 = wave_sum(z0 + z1) * (1.f / 128.f);
    float d0 = z0 - m2, d1 = z1 - m2;
    float v2 = wave_sum(d0 * d0 + d1 * d1) * (1.f / 128.f);
    float inv2 = rsqrtf(v2 + 1e-5f);
    float o0 = d0 * inv2 * g1[e0] + b1[e0];
    float o1 = d1 * inv2 * g1[e0 + 1] + b1[e0 + 1];
    *(float2*)(ws + ATT_OFF + (size_t)row * EE + e0) = make_float2(o0, o1);
}

// ---------------- K5: FF1 + bias + relu ----------------
// grid (B*S/16); thread t owns cols t and t+256 over 16 rows.
__global__ __launch_bounds__(256) void k5_ff1(const float* __restrict__ w1,
                                              const float* __restrict__ b1,
                                              float* __restrict__ ws) {
    __shared__ float xs[16][128];
    int bs0 = blockIdx.x * 16;
    int t = threadIdx.x;
    for (int i = t; i < 2048; i += 256) ((float*)xs)[i] = ws[ATT_OFF + (size_t)bs0 * EE + i];
    __syncthreads();
    float accA[16], accB[16];
    #pragma unroll
    for (int r = 0; r < 16; r++) { accA[r] = 0.f; accB[r] = 0.f; }
    int c = t;
    for (int d = 0; d < 128; d++) {
        float wa = w1[c * 128 + d], wb = w1[(c + 256) * 128 + d];
        #pragma unroll
        for (int r = 0; r < 16; r++) {
            float xv = xs[r][d];
            accA[r] += xv * wa;
            accB[r] += xv * wb;
        }
    }
    float ba = b1[c], bb = b1[c + 256];
    #pragma unroll
    for (int r = 0; r < 16; r++) {
        ws[FFH_OFF + (size_t)(bs0 + r) * DFFN + c]       = fmaxf(accA[r] + ba, 0.f);
        ws[FFH_OFF + (size_t)(bs0 + r) * DFFN + c + 256] = fmaxf(accB[r] + bb, 0.f);
    }
}

// ---------------- K6: FF2 + bias + residual + LN2 + transposed store ----------------
__global__ __launch_bounds__(256) void k6_ff2(const float* __restrict__ w2,
                                              const float* __restrict__ b2,
                                              const float* __restrict__ g2, const float* __restrict__ bb2,
                                              float* __restrict__ ws, float* __restrict__ out) {
    __shared__ float fs[16][512];     // 32 KB
    __shared__ float y[16][132];      // padded
    int bs0 = blockIdx.x * 16;
    int t = threadIdx.x;
    for (int i = t; i < 16 * 512; i += 256) ((float*)fs)[i] = ws[FFH_OFF + (size_t)bs0 * DFFN + i];
    __syncthreads();
    int c = t & 127, rg = t >> 7;
    float acc[8];
    #pragma unroll
    for (int r = 0; r < 8; r++) acc[r] = 0.f;
    for (int f = 0; f < 512; f++) {
        float wv = w2[c * 512 + f];
        #pragma unroll
        for (int r = 0; r < 8; r++) acc[r] += fs[rg * 8 + r][f] * wv;
    }
    float bv = b2[c];
    #pragma unroll
    for (int r = 0; r < 8; r++) {
        int row = rg * 8 + r;
        y[row][c] = acc[r] + bv + ws[ATT_OFF + (size_t)(bs0 + row) * EE + c];
    }
    __syncthreads();
    int wid = t >> 6, lane = t & 63;
    int e0 = lane * 2;
    for (int rr = 0; rr < 4; rr++) {
        int row = wid * 4 + rr;
        float z0 = y[row][e0], z1 = y[row][e0 + 1];
        float mean = wave_sum(z0 + z1) * (1.f / 128.f);
        float d0 = z0 - mean, d1 = z1 - mean;
        float var = wave_sum(d0 * d0 + d1 * d1) * (1.f / 128.f);
        float inv = rsqrtf(var + 1e-5f);
        y[row][e0]     = d0 * inv * g2[e0] + bb2[e0];
        y[row][e0 + 1] = d1 * inv * g2[e0 + 1] + bb2[e0 + 1];
    }
    __syncthreads();
    int b = bs0 >> 10, s0 = bs0 & 1023;
    int sl = t & 15, egr = t >> 4;
    #pragma unroll
    for (int rep = 0; rep < 8; rep++) {
        int e = egr + rep * 16;
        out[(size_t)b * EE * SS + (size_t)e * SS + s0 + sl] = y[sl][e];
    }
}

extern "C" void kernel_launch(void* const* d_in, const int* in_sizes, int n_in,
                              void* d_out, int out_size, void* d_ws, size_t ws_size,
                              hipStream_t stream) {
    const float* x        = (const float*)d_in[0];
    const float* conv1_w  = (const float*)d_in[1];
    const float* conv1_b  = (const float*)d_in[2];
    const float* bn1_g    = (const float*)d_in[3];
    const float* bn1_b    = (const float*)d_in[4];
    const float* bn1_m    = (const float*)d_in[5];
    const float* bn1_v    = (const float*)d_in[6];
    const float* conv2_w  = (const float*)d_in[7];
    const float* conv2_b  = (const float*)d_in[8];
    const float* bn2_g    = (const float*)d_in[9];
    const float* bn2_b    = (const float*)d_in[10];
    const float* bn2_m    = (const float*)d_in[11];
    const float* bn2_v    = (const float*)d_in[12];
    const float* wq       = (const float*)d_in[13];
    const float* wk       = (const float*)d_in[14];
    const float* wv       = (const float*)d_in[15];
    const float* rel_tab  = (const float*)d_in[16];
    const float* ln_attn_g = (const float*)d_in[17];
    const float* ln_attn_b = (const float*)d_in[18];
    const float* ln1_g    = (const float*)d_in[19];
    const float* ln1_b    = (const float*)d_in[20];
    const float* ln2_g    = (const float*)d_in[21];
    const float* ln2_b    = (const float*)d_in[22];
    const float* ff_w1    = (const float*)d_in[23];
    const float* ff_b1    = (const float*)d_in[24];
    const float* ff_w2    = (const float*)d_in[25];
    const float* ff_b2    = (const float*)d_in[26];

    float* ws  = (float*)d_ws;
    float* out = (float*)d_out;

    hipLaunchKernelGGL(k0_pe, dim3(512), dim3(256), 0, stream, ws);
    hipLaunchKernelGGL(k0_bn, dim3(1), dim3(640), 0, stream,
                       conv1_b, bn1_g, bn1_b, bn1_m, bn1_v,
                       conv2_b, bn2_g, bn2_b, bn2_m, bn2_v, ws);
    hipLaunchKernelGGL(k1_conv, dim3(SS / TS1, BB), dim3(256), 0, stream, x, conv1_w, conv2_w, ws);
    hipLaunchKernelGGL(k2_qkv, dim3(BB * SS / 16), dim3(256), 0, stream, wq, wk, wv, ws);
    hipLaunchKernelGGL(k3_attn, dim3(BB * HH, SS / 256), dim3(256), 0, stream, rel_tab, ws);
    hipLaunchKernelGGL(k4_ln, dim3(BB * SS / 4), dim3(256), 0, stream, ln_attn_g, ln_attn_b, ln1_g, ln1_b, ws);
    hipLaunchKernelGGL(k5_ff1, dim3(BB * SS / 16), dim3(256), 0, stream, ff_w1, ff_b1, ws);
    hipLaunchKernelGGL(k6_ff2, dim3(BB * SS / 16), dim3(256), 0, stream, ff_w2, ff_b2, ln2_g, ln2_b, ws, out);
}

// Round 4
// 492.188 us; speedup vs baseline: 2.6615x; 2.6615x over previous
//
#include <hip/hip_runtime.h>
#include <math.h>

// Problem constants
#define BB    8
#define CIN   16
#define SS    1024
#define EE    128
#define HH    8
#define DHH   16
#define O1    512      // E*4
#define DFFN  512
#define K2TOT 8192     // O1*CIN

// Workspace layout (float offsets)
#define PE_OFF    0            // 131072  (S*E)
#define BN1SC_OFF 131072       // 512
#define BN1SH_OFF 131584       // 512
#define BN2SC_OFF 132096       // 128
#define BN2SH_OFF 132224       // 128
#define XSRC_OFF  262144       // 1048576 (B*S*E)
#define Q_OFF     1310720      // 1048576 (B,H,S,DH)
#define KK_OFF    2359296      // 1048576
#define V_OFF     3407872      // 1048576
#define ATTN_OFF  4456448      // 1048576 (B,S,E) pre-LN attention out
#define ATT_OFF   5505024      // 1048576 (B,S,E) post-LN1
#define FFH_OFF   6553600      // 4194304 (B*S,DFF)
// W2BF (bf16 w2, 1M elems = 512K floats) OVERLAYS FFH region: written by
// k0_w2cast + read by k1_mfma, both before k5_ff1 overwrites FFH. Rewritten
// every launch -> deterministic under graph replay.
// end: 10747904 floats = 43.0 MB

typedef __attribute__((ext_vector_type(8))) short short8;
typedef __attribute__((ext_vector_type(8))) unsigned short ushort8;
typedef __attribute__((ext_vector_type(4))) float f32x4;

__device__ __forceinline__ float wave_sum(float v) {
    #pragma unroll
    for (int o = 32; o > 0; o >>= 1) v += __shfl_xor(v, o);
    return v;
}

__device__ __forceinline__ float gelu_exact(float x) {
    return 0.5f * x * (1.0f + erff(x * 0.7071067811865476f));
}

// tanh-form gelu: max abs err ~3e-4 at |x|~2, ~1e-5 for |x|<0.5 (h1 std 0.13).
// Downstream error through conv2: random-sign w2 -> random walk, ~5e-5. Safe.
__device__ __forceinline__ float gelu_tanh(float x) {
    float x2 = x * x;
    float y = x * fmaf(0.0356774081f, x2, 0.7978845608f);
    float E = __expf(2.0f * y);
    float r = __builtin_amdgcn_rcpf(E + 1.0f);
    return x - x * r;            // x * E/(E+1)
}

__device__ __forceinline__ unsigned short f2bf(float f) {   // RNE fp32->bf16
    unsigned int u = __float_as_uint(f);
    unsigned int r = u + 0x7FFFu + ((u >> 16) & 1u);
    return (unsigned short)(r >> 16);
}

// ---------------- K0a: positional encoding table ----------------
__global__ __launch_bounds__(256) void k0_pe(float* __restrict__ ws) {
    int idx = blockIdx.x * 256 + threadIdx.x;   // 131072 total
    int s = idx >> 7, e = idx & 127;
    int i = e >> 1;
    float freq = expf((float)(2 * i) * (-9.210340371976184f / 128.0f));
    float ang = (float)s * freq * 0.125f;
    ws[PE_OFF + idx] = (e & 1) ? cosf(ang) : sinf(ang);
}

// ---------------- K0b: fold conv-bias + BN into scale/shift ----------------
__global__ void k0_bn(const float* __restrict__ conv1_b, const float* __restrict__ bn1_g,
                      const float* __restrict__ bn1_b, const float* __restrict__ bn1_m,
                      const float* __restrict__ bn1_v,
                      const float* __restrict__ conv2_b, const float* __restrict__ bn2_g,
                      const float* __restrict__ bn2_b, const float* __restrict__ bn2_m,
                      const float* __restrict__ bn2_v,
                      float* __restrict__ ws) {
    int t = threadIdx.x;
    if (t < 512) {
        float sc = bn1_g[t] * rsqrtf(bn1_v[t] + 1e-5f);
        ws[BN1SC_OFF + t] = sc;
        ws[BN1SH_OFF + t] = (conv1_b[t] - bn1_m[t]) * sc + bn1_b[t];
    } else if (t < 640) {
        int e = t - 512;
        float sc = bn2_g[e] * rsqrtf(bn2_v[e] + 1e-5f);
        ws[BN2SC_OFF + e] = sc;
        ws[BN2SH_OFF + e] = (conv2_b[e] - bn2_m[e]) * sc + bn2_b[e];
    }
}

// ---------------- K0c: pre-cast w2 -> bf16, chunk-major, pre-swizzled ----------------
// Layout: chunk kb (k-range kb*64..+64), within chunk: [e][g][j] (e<128, g<8, j<8)
// where the 8 bf16 at (e,g) are w2[e][kb*64 + (g^(e&7))*8 .. +8].  This bakes the
// LDS XOR-swizzle into global so k1's global_load_lds stays linear (m173 pattern).
__global__ __launch_bounds__(256) void k0_w2cast(const float* __restrict__ w2,
                                                 float* __restrict__ ws) {
    int tid = blockIdx.x * 256 + threadIdx.x;   // 131072 = 128kb * 128e * 8g
    int kb = tid >> 10, e = (tid >> 3) & 127, g = tid & 7;
    const float* src = w2 + (size_t)e * K2TOT + kb * 64 + ((g ^ (e & 7)) << 3);
    ushort8 v;
    #pragma unroll
    for (int j = 0; j < 8; j++) v[j] = f2bf(src[j]);
    unsigned short* dst = (unsigned short*)(ws + FFH_OFF)
                        + ((size_t)kb << 13) + (e << 6) + (g << 3);
    *(ushort8*)dst = v;
}

// ---------------- K1: fused conv1+bn1+gelu -> conv2 (bf16 MFMA) + bn2+gelu ----------------
// GEMM: C[row=(b,s)][e] = sum_k h1[row][k] * w2[e][k], M=8192 N=128 K=8192.
// Tile BM=32 x BN=128, BK=64; grid 256 blocks x 256 threads (4 waves, 2Mx2N).
// A (h1) recomputed per chunk from conv1 into swizzled LDS; B staged via
// global_load_lds from the pre-swizzled bf16 w2. Double-buffered, 1 barrier/chunk.
__global__ __launch_bounds__(256) void k1_mfma(const float* __restrict__ x,
                                               const float* __restrict__ w1,
                                               float* __restrict__ ws) {
    __shared__ float xt[CIN][41];                 // x[b,c, s0-3 .. s0+34], padded (bank-spread)
    __shared__ float w1s[O1][8];                  // 7 taps + pad
    __shared__ float sc1s[O1], sh1s[O1];
    __shared__ unsigned short Ab[2][32 * 64];     // h1 tile, swizzled: [s][slot][k&7]
    __shared__ unsigned short Bbuf[2][128 * 64];  // w2 tile, swizzled: [e][slot][k&7]

    const int t = threadIdx.x;
    const int wave = t >> 6, lane = t & 63;
    const int row0 = blockIdx.x * 32;
    const int b = row0 >> 10, s0 = row0 & 1023;

    for (int i = t; i < CIN * 38; i += 256) {
        int c = i / 38, j = i % 38;
        int gs = s0 + j - 3;
        xt[c][j] = (gs >= 0 && gs < SS) ? x[(b * CIN + c) * SS + gs] : 0.f;
    }
    for (int i = t; i < O1 * 7; i += 256) w1s[i / 7][i % 7] = w1[i];
    for (int i = t; i < O1; i += 256) { sc1s[i] = ws[BN1SC_OFF + i]; sh1s[i] = ws[BN1SH_OFF + i]; }

    const char* w2g = (const char*)(ws + FFH_OFF);

    // ---- async B-tile stage: 16KB linear (swizzle pre-baked in global) ----
    auto stageB = [&](int kb, int buf) {
        const char* g = w2g + ((size_t)kb << 14);
        #pragma unroll
        for (int c4 = 0; c4 < 4; ++c4) {
            int off = c4 * 4096 + wave * 1024;    // wave-uniform LDS dest
            __builtin_amdgcn_global_load_lds(
                (const __attribute__((address_space(1))) unsigned int*)(g + off + lane * 16),
                (__attribute__((address_space(3))) unsigned int*)(&Bbuf[buf][off >> 1]),
                16, 0, 0);
        }
    };

    // ---- A-tile: conv1+bn1+gelu for k-range kb*64..+64, rows s0..s0+31 ----
    // thread: fixed k=lane (o=kb*4+(lane>>4), c=lane&15), 8 s-rows (wave*8..+8)
    auto computeH1 = [&](int kb, int buf) {
        int o = (kb << 2) + (lane >> 4);
        int c = lane & 15;
        float4 wA = *(const float4*)&w1s[o][0];
        float4 wB = *(const float4*)&w1s[o][4];
        float sc = sc1s[o], sh = sh1s[o];
        float xv[14];
        #pragma unroll
        for (int j = 0; j < 14; j++) xv[j] = xt[c][(wave << 3) + j];
        #pragma unroll
        for (int i = 0; i < 8; i++) {
            int ss = (wave << 3) + i;
            float p = xv[i]   * wA.x + xv[i+1] * wA.y + xv[i+2] * wA.z + xv[i+3] * wA.w
                    + xv[i+4] * wB.x + xv[i+5] * wB.y + xv[i+6] * wB.z;
            float g = gelu_tanh(fmaf(p, sc, sh));
            int slot = ((lane & 63) >> 3) ^ (ss & 7);
            Ab[buf][(ss << 6) + (slot << 3) + (lane & 7)] = f2bf(g);
        }
    };

    const int wr = wave >> 1, wc = wave & 1;      // wave -> (m-frag, n-half)
    const int lrow = lane & 15, lq = lane >> 4;
    f32x4 acc[4];
    #pragma unroll
    for (int i = 0; i < 4; i++) acc[i] = (f32x4){0.f, 0.f, 0.f, 0.f};

    auto mfmaPhase = [&](int buf) {
        #pragma unroll
        for (int ks = 0; ks < 2; ++ks) {
            int G = (ks << 2) + lq;               // k-group 0..7 within chunk
            int arow = (wr << 4) + lrow;
            short8 a = *(const short8*)&Ab[buf][(arow << 6) + ((G ^ (arow & 7)) << 3)];
            #pragma unroll
            for (int nf = 0; nf < 4; ++nf) {
                int e = (wc << 6) + (nf << 4) + lrow;
                short8 bf = *(const short8*)&Bbuf[buf][(e << 6) + ((G ^ (e & 7)) << 3)];
                acc[nf] = __builtin_amdgcn_mfma_f32_16x16x32_bf16(a, bf, acc[nf], 0, 0, 0);
            }
        }
    };

    stageB(0, 0);
    __syncthreads();                              // xt/w1s ready; B[0] drained (vmcnt@barrier)
    computeH1(0, 0);
    __syncthreads();                              // A[0] ready
    for (int kb = 0; kb < 128; ++kb) {
        int cur = kb & 1;
        if (kb < 127) stageB(kb + 1, cur ^ 1);    // async loads overlap MFMA+VALU
        mfmaPhase(cur);
        if (kb < 127) computeH1(kb + 1, cur ^ 1);
        __syncthreads();                          // drains vmcnt+lgkm: next bufs ready
    }

    // ---- epilogue: bn2 + exact gelu -> x_src (fp32) ----
    #pragma unroll
    for (int nf = 0; nf < 4; ++nf) {
        int e = (wc << 6) + (nf << 4) + lrow;
        float sc2 = ws[BN2SC_OFF + e], sh2 = ws[BN2SH_OFF + e];
        #pragma unroll
        for (int r = 0; r < 4; ++r) {
            int srow = s0 + (wr << 4) + (lq << 2) + r;
            float h2 = fmaf(acc[nf][r], sc2, sh2);
            ws[XSRC_OFF + (((size_t)(b * SS + srow)) << 7) + e] = gelu_exact(h2);
        }
    }
}

// ---------------- K2: QKV projection (adds PE on the fly) ----------------
__global__ __launch_bounds__(256) void k2_qkv(const float* __restrict__ wq,
                                              const float* __restrict__ wk,
                                              const float* __restrict__ wv,
                                              float* __restrict__ ws) {
    __shared__ float xs[16][128];
    int bs0 = blockIdx.x * 16;
    int t = threadIdx.x;
    for (int i = t; i < 16 * 128; i += 256) {
        int r = i >> 7, d = i & 127;
        int bs = bs0 + r;
        int sl = bs & (SS - 1);
        xs[r][d] = ws[XSRC_OFF + (size_t)bs * EE + d] + ws[PE_OFF + sl * EE + d];
    }
    __syncthreads();
    int e = t & 127, rg = t >> 7;
    float aq[8], ak[8], av[8];
    #pragma unroll
    for (int i = 0; i < 8; i++) { aq[i] = 0.f; ak[i] = 0.f; av[i] = 0.f; }
    for (int d = 0; d < 128; d++) {
        float wqv = wq[e * 128 + d], wkv = wk[e * 128 + d], wvv = wv[e * 128 + d];
        #pragma unroll
        for (int r = 0; r < 8; r++) {
            float xv = xs[rg * 8 + r][d];
            aq[r] += xv * wqv; ak[r] += xv * wkv; av[r] += xv * wvv;
        }
    }
    int h = e >> 4, d2 = e & 15;
    #pragma unroll
    for (int r = 0; r < 8; r++) {
        int bs = bs0 + rg * 8 + r;
        int bb = bs >> 10, sl = bs & 1023;
        size_t off = (((size_t)(bb * HH + h)) * SS + sl) * DHH + d2;
        ws[Q_OFF + off] = aq[r];
        ws[KK_OFF + off] = ak[r];
        ws[V_OFF + off] = av[r];
    }
}

// ---------------- K3: attention, one thread per q-row ----------------
__global__ __launch_bounds__(256) void k3_attn(const float* __restrict__ rel_tab,
                                               float* __restrict__ ws) {
    __shared__ float kt[64][16];
    __shared__ float vt[64][16];
    __shared__ float tbl[1280];
    int bh = blockIdx.x;            // b*H + h
    int i0 = blockIdx.y * 256;
    int h = bh & 7;
    int t = threadIdx.x;
    for (int r = t; r < 1279; r += 256) tbl[r] = rel_tab[(i0 + r) * HH + h];

    int i = i0 + t;
    const float* qp = ws + Q_OFF + ((size_t)bh * SS + i) * DHH;
    float q[16], U[16], Bv[16];
    #pragma unroll
    for (int d = 0; d < 16; d++) { q[d] = qp[d]; U[d] = 0.f; Bv[d] = 0.f; }
    float m = -1e30f, l = 0.f;
    const float scale = 0.08838834764831845f;   // 128^-0.5
    const float* kbase = ws + KK_OFF + (size_t)bh * SS * DHH;
    const float* vbase = ws + V_OFF + (size_t)bh * SS * DHH;

    for (int j0 = 0; j0 < SS; j0 += 64) {
        __syncthreads();
        for (int idx = t; idx < 64 * 16; idx += 256) {
            ((float*)kt)[idx] = kbase[j0 * 16 + idx];
            ((float*)vt)[idx] = vbase[j0 * 16 + idx];
        }
        __syncthreads();
        for (int jj = 0; jj < 64; jj++) {
            float sdot = 0.f;
            #pragma unroll
            for (int d = 0; d < 16; d++) sdot += q[d] * kt[jj][d];
            sdot *= scale;
            float p;
            if (sdot > m) {
                float f = __expf(m - sdot);
                l *= f;
                #pragma unroll
                for (int d = 0; d < 16; d++) U[d] *= f;
                m = sdot;
                p = 1.f;
            } else {
                p = __expf(sdot - m);
            }
            l += p;
            float bvv = tbl[t + 1023 - (j0 + jj)];
            #pragma unroll
            for (int d = 0; d < 16; d++) {
                U[d] += p * vt[jj][d];
                Bv[d] += bvv * vt[jj][d];
            }
        }
    }
    float inv_l = 1.f / l;
    int b = bh >> 3;
    float* op = ws + ATTN_OFF + ((size_t)(b * SS) + i) * EE + h * DHH;
    #pragma unroll
    for (int d = 0; d < 16; d++) op[d] = U[d] * inv_l + Bv[d];
}

// ---------------- K4: LN(attn) -> +x_src -> LN1 -> att ----------------
__global__ __launch_bounds__(256) void k4_ln(const float* __restrict__ g_attn, const float* __restrict__ b_attn,
                                             const float* __restrict__ g1, const float* __restrict__ b1,
                                             float* __restrict__ ws) {
    int row = blockIdx.x * 4 + (threadIdx.x >> 6);
    int lane = threadIdx.x & 63;
    int e0 = lane * 2;
    const float* ain = ws + ATTN_OFF + (size_t)row * EE;
    const float* xsr = ws + XSRC_OFF + (size_t)row * EE;
    float2 a = *(const float2*)(ain + e0);
    float mean = wave_sum(a.x + a.y) * (1.f / 128.f);
    float dx = a.x - mean, dy = a.y - mean;
    float var = wave_sum(dx * dx + dy * dy) * (1.f / 128.f);
    float inv = rsqrtf(var + 1e-5f);
    float n0 = dx * inv * g_attn[e0] + b_attn[e0];
    float n1 = dy * inv * g_attn[e0 + 1] + b_attn[e0 + 1];
    float2 xs2 = *(const float2*)(xsr + e0);
    float z0 = xs2.x + n0, z1 = xs2.y + n1;
    float m2 = wave_sum(z0 + z1) * (1.f / 128.f);
    float d0 = z0 - m2, d1 = z1 - m2;
    float v2 = wave_sum(d0 * d0 + d1 * d1) * (1.f / 128.f);
    float inv2 = rsqrtf(v2 + 1e-5f);
    float o0 = d0 * inv2 * g1[e0] + b1[e0];
    float o1 = d1 * inv2 * g1[e0 + 1] + b1[e0 + 1];
    *(float2*)(ws + ATT_OFF + (size_t)row * EE + e0) = make_float2(o0, o1);
}

// ---------------- K5: FF1 + bias + relu ----------------
__global__ __launch_bounds__(256) void k5_ff1(const float* __restrict__ w1,
                                              const float* __restrict__ b1,
                                              float* __restrict__ ws) {
    __shared__ float xs[16][128];
    int bs0 = blockIdx.x * 16;
    int t = threadIdx.x;
    for (int i = t; i < 2048; i += 256) ((float*)xs)[i] = ws[ATT_OFF + (size_t)bs0 * EE + i];
    __syncthreads();
    float accA[16], accB[16];
    #pragma unroll
    for (int r = 0; r < 16; r++) { accA[r] = 0.f; accB[r] = 0.f; }
    int c = t;
    for (int d = 0; d < 128; d++) {
        float wa = w1[c * 128 + d], wb = w1[(c + 256) * 128 + d];
        #pragma unroll
        for (int r = 0; r < 16; r++) {
            float xv = xs[r][d];
            accA[r] += xv * wa;
            accB[r] += xv * wb;
        }
    }
    float ba = b1[c], bb = b1[c + 256];
    #pragma unroll
    for (int r = 0; r < 16; r++) {
        ws[FFH_OFF + (size_t)(bs0 + r) * DFFN + c]       = fmaxf(accA[r] + ba, 0.f);
        ws[FFH_OFF + (size_t)(bs0 + r) * DFFN + c + 256] = fmaxf(accB[r] + bb, 0.f);
    }
}

// ---------------- K6: FF2 + bias + residual + LN2 + transposed store ----------------
__global__ __launch_bounds__(256) void k6_ff2(const float* __restrict__ w2,
                                              const float* __restrict__ b2,
                                              const float* __restrict__ g2, const float* __restrict__ bb2,
                                              float* __restrict__ ws, float* __restrict__ out) {
    __shared__ float fs[16][512];     // 32 KB
    __shared__ float y[16][132];      // padded
    int bs0 = blockIdx.x * 16;
    int t = threadIdx.x;
    for (int i = t; i < 16 * 512; i += 256) ((float*)fs)[i] = ws[FFH_OFF + (size_t)bs0 * DFFN + i];
    __syncthreads();
    int c = t & 127, rg = t >> 7;
    float acc[8];
    #pragma unroll
    for (int r = 0; r < 8; r++) acc[r] = 0.f;
    for (int f = 0; f < 512; f++) {
        float wv = w2[c * 512 + f];
        #pragma unroll
        for (int r = 0; r < 8; r++) acc[r] += fs[rg * 8 + r][f] * wv;
    }
    float bv = b2[c];
    #pragma unroll
    for (int r = 0; r < 8; r++) {
        int row = rg * 8 + r;
        y[row][c] = acc[r] + bv + ws[ATT_OFF + (size_t)(bs0 + row) * EE + c];
    }
    __syncthreads();
    int wid = t >> 6, lane = t & 63;
    int e0 = lane * 2;
    for (int rr = 0; rr < 4; rr++) {
        int row = wid * 4 + rr;
        float z0 = y[row][e0], z1 = y[row][e0 + 1];
        float mean = wave_sum(z0 + z1) * (1.f / 128.f);
        float d0 = z0 - mean, d1 = z1 - mean;
        float var = wave_sum(d0 * d0 + d1 * d1) * (1.f / 128.f);
        float inv = rsqrtf(var + 1e-5f);
        y[row][e0]     = d0 * inv * g2[e0] + bb2[e0];
        y[row][e0 + 1] = d1 * inv * g2[e0 + 1] + bb2[e0 + 1];
    }
    __syncthreads();
    int b = bs0 >> 10, s0 = bs0 & 1023;
    int sl = t & 15, egr = t >> 4;
    #pragma unroll
    for (int rep = 0; rep < 8; rep++) {
        int e = egr + rep * 16;
        out[(size_t)b * EE * SS + (size_t)e * SS + s0 + sl] = y[sl][e];
    }
}

extern "C" void kernel_launch(void* const* d_in, const int* in_sizes, int n_in,
                              void* d_out, int out_size, void* d_ws, size_t ws_size,
                              hipStream_t stream) {
    const float* x        = (const float*)d_in[0];
    const float* conv1_w  = (const float*)d_in[1];
    const float* conv1_b  = (const float*)d_in[2];
    const float* bn1_g    = (const float*)d_in[3];
    const float* bn1_b    = (const float*)d_in[4];
    const float* bn1_m    = (const float*)d_in[5];
    const float* bn1_v    = (const float*)d_in[6];
    const float* conv2_w  = (const float*)d_in[7];
    const float* conv2_b  = (const float*)d_in[8];
    const float* bn2_g    = (const float*)d_in[9];
    const float* bn2_b    = (const float*)d_in[10];
    const float* bn2_m    = (const float*)d_in[11];
    const float* bn2_v    = (const float*)d_in[12];
    const float* wq       = (const float*)d_in[13];
    const float* wk       = (const float*)d_in[14];
    const float* wv       = (const float*)d_in[15];
    const float* rel_tab  = (const float*)d_in[16];
    const float* ln_attn_g = (const float*)d_in[17];
    const float* ln_attn_b = (const float*)d_in[18];
    const float* ln1_g    = (const float*)d_in[19];
    const float* ln1_b    = (const float*)d_in[20];
    const float* ln2_g    = (const float*)d_in[21];
    const float* ln2_b    = (const float*)d_in[22];
    const float* ff_w1    = (const float*)d_in[23];
    const float* ff_b1    = (const float*)d_in[24];
    const float* ff_w2    = (const float*)d_in[25];
    const float* ff_b2    = (const float*)d_in[26];

    float* ws  = (float*)d_ws;
    float* out = (float*)d_out;

    hipLaunchKernelGGL(k0_pe, dim3(512), dim3(256), 0, stream, ws);
    hipLaunchKernelGGL(k0_bn, dim3(1), dim3(640), 0, stream,
                       conv1_b, bn1_g, bn1_b, bn1_m, bn1_v,
                       conv2_b, bn2_g, bn2_b, bn2_m, bn2_v, ws);
    hipLaunchKernelGGL(k0_w2cast, dim3(512), dim3(256), 0, stream, conv2_w, ws);
    hipLaunchKernelGGL(k1_mfma, dim3(256), dim3(256), 0, stream, x, conv1_w, ws);
    hipLaunchKernelGGL(k2_qkv, dim3(BB * SS / 16), dim3(256), 0, stream, wq, wk, wv, ws);
    hipLaunchKernelGGL(k3_attn, dim3(BB * HH, SS / 256), dim3(256), 0, stream, rel_tab, ws);
    hipLaunchKernelGGL(k4_ln, dim3(BB * SS / 4), dim3(256), 0, stream, ln_attn_g, ln_attn_b, ln1_g, ln1_b, ws);
    hipLaunchKernelGGL(k5_ff1, dim3(BB * SS / 16), dim3(256), 0, stream, ff_w1, ff_b1, ws);
    hipLaunchKernelGGL(k6_ff2, dim3(BB * SS / 16), dim3(256), 0, stream, ff_w2, ff_b2, ln2_g, ln2_b, ws, out);
}

// Round 5
// 368.580 us; speedup vs baseline: 3.5541x; 1.3354x over previous
//
#include <hip/hip_runtime.h>
#include <math.h>

// Problem constants
#define BB    8
#define CIN   16
#define SS    1024
#define EE    128
#define HH    8
#define DHH   16
#define O1    512      // E*4
#define DFFN  512
#define K2TOT 8192     // O1*CIN

// Workspace layout (float offsets)
#define PE_OFF    0            // 131072  (S*E)
#define BN1SC_OFF 131072       // 512
#define BN1SH_OFF 131584       // 512
#define BN2SC_OFF 132096       // 128
#define BN2SH_OFF 132224       // 128
#define XSRC_OFF  262144       // 1048576 (B*S*E)
#define Q_OFF     1310720      // QH: f16[B*H*S*16] scaled  (uses half the slot)
#define KK_OFF    2359296      // KH: f16[B*H*S*16]
#define V_OFF     3407872      // VHT: f16[B*H*16*S] (d-major, transposed)
#define ATTN_OFF  4456448      // 1048576 (B,S,E) attention out (k3a writes, k3b adds)
#define ATT_OFF   5505024      // 1048576 (B,S,E) post-LN1
#define FFH_OFF   6553600      // 4194304 (B*S,DFF)
// W2BF (bf16 w2) OVERLAYS FFH region (k0_w2cast -> k1_mfma, both before k5).
// end: 10747904 floats = 43.0 MB

typedef __attribute__((ext_vector_type(8))) short short8;
typedef __attribute__((ext_vector_type(8))) unsigned short ushort8;
typedef __attribute__((ext_vector_type(4))) float f32x4;
typedef _Float16 f16_t;
typedef __attribute__((ext_vector_type(4))) _Float16 half4;
typedef __attribute__((ext_vector_type(8))) _Float16 half8;

__device__ __forceinline__ float wave_sum(float v) {
    #pragma unroll
    for (int o = 32; o > 0; o >>= 1) v += __shfl_xor(v, o);
    return v;
}

__device__ __forceinline__ float gelu_exact(float x) {
    return 0.5f * x * (1.0f + erff(x * 0.7071067811865476f));
}

__device__ __forceinline__ float gelu_tanh(float x) {
    float x2 = x * x;
    float y = x * fmaf(0.0356774081f, x2, 0.7978845608f);
    float E = __expf(2.0f * y);
    float r = __builtin_amdgcn_rcpf(E + 1.0f);
    return x - x * r;            // x * E/(E+1)
}

__device__ __forceinline__ unsigned short f2bf(float f) {   // RNE fp32->bf16
    unsigned int u = __float_as_uint(f);
    unsigned int r = u + 0x7FFFu + ((u >> 16) & 1u);
    return (unsigned short)(r >> 16);
}

// ---------------- K0a: positional encoding table ----------------
__global__ __launch_bounds__(256) void k0_pe(float* __restrict__ ws) {
    int idx = blockIdx.x * 256 + threadIdx.x;   // 131072 total
    int s = idx >> 7, e = idx & 127;
    int i = e >> 1;
    float freq = expf((float)(2 * i) * (-9.210340371976184f / 128.0f));
    float ang = (float)s * freq * 0.125f;
    ws[PE_OFF + idx] = (e & 1) ? cosf(ang) : sinf(ang);
}

// ---------------- K0b: fold conv-bias + BN into scale/shift ----------------
__global__ void k0_bn(const float* __restrict__ conv1_b, const float* __restrict__ bn1_g,
                      const float* __restrict__ bn1_b, const float* __restrict__ bn1_m,
                      const float* __restrict__ bn1_v,
                      const float* __restrict__ conv2_b, const float* __restrict__ bn2_g,
                      const float* __restrict__ bn2_b, const float* __restrict__ bn2_m,
                      const float* __restrict__ bn2_v,
                      float* __restrict__ ws) {
    int t = threadIdx.x;
    if (t < 512) {
        float sc = bn1_g[t] * rsqrtf(bn1_v[t] + 1e-5f);
        ws[BN1SC_OFF + t] = sc;
        ws[BN1SH_OFF + t] = (conv1_b[t] - bn1_m[t]) * sc + bn1_b[t];
    } else if (t < 640) {
        int e = t - 512;
        float sc = bn2_g[e] * rsqrtf(bn2_v[e] + 1e-5f);
        ws[BN2SC_OFF + e] = sc;
        ws[BN2SH_OFF + e] = (conv2_b[e] - bn2_m[e]) * sc + bn2_b[e];
    }
}

// ---------------- K0c: pre-cast w2 -> bf16, chunk-major, pre-swizzled ----------------
__global__ __launch_bounds__(256) void k0_w2cast(const float* __restrict__ w2,
                                                 float* __restrict__ ws) {
    int tid = blockIdx.x * 256 + threadIdx.x;   // 131072 = 128kb * 128e * 8g
    int kb = tid >> 10, e = (tid >> 3) & 127, g = tid & 7;
    const float* src = w2 + (size_t)e * K2TOT + kb * 64 + ((g ^ (e & 7)) << 3);
    ushort8 v;
    #pragma unroll
    for (int j = 0; j < 8; j++) v[j] = f2bf(src[j]);
    unsigned short* dst = (unsigned short*)(ws + FFH_OFF)
                        + ((size_t)kb << 13) + (e << 6) + (g << 3);
    *(ushort8*)dst = v;
}

// ---------------- K1: fused conv1+bn1+gelu -> conv2 (bf16 MFMA) + bn2+gelu ----------------
__global__ __launch_bounds__(256) void k1_mfma(const float* __restrict__ x,
                                               const float* __restrict__ w1,
                                               float* __restrict__ ws) {
    __shared__ float xt[CIN][41];
    __shared__ float w1s[O1][8];
    __shared__ float sc1s[O1], sh1s[O1];
    __shared__ unsigned short Ab[2][32 * 64];
    __shared__ unsigned short Bbuf[2][128 * 64];

    const int t = threadIdx.x;
    const int wave = t >> 6, lane = t & 63;
    const int row0 = blockIdx.x * 32;
    const int b = row0 >> 10, s0 = row0 & 1023;

    for (int i = t; i < CIN * 38; i += 256) {
        int c = i / 38, j = i % 38;
        int gs = s0 + j - 3;
        xt[c][j] = (gs >= 0 && gs < SS) ? x[(b * CIN + c) * SS + gs] : 0.f;
    }
    for (int i = t; i < O1 * 7; i += 256) w1s[i / 7][i % 7] = w1[i];
    for (int i = t; i < O1; i += 256) { sc1s[i] = ws[BN1SC_OFF + i]; sh1s[i] = ws[BN1SH_OFF + i]; }

    const char* w2g = (const char*)(ws + FFH_OFF);

    auto stageB = [&](int kb, int buf) {
        const char* g = w2g + ((size_t)kb << 14);
        #pragma unroll
        for (int c4 = 0; c4 < 4; ++c4) {
            int off = c4 * 4096 + wave * 1024;
            __builtin_amdgcn_global_load_lds(
                (const __attribute__((address_space(1))) unsigned int*)(g + off + lane * 16),
                (__attribute__((address_space(3))) unsigned int*)(&Bbuf[buf][off >> 1]),
                16, 0, 0);
        }
    };

    auto computeH1 = [&](int kb, int buf) {
        int o = (kb << 2) + (lane >> 4);
        int c = lane & 15;
        float4 wA = *(const float4*)&w1s[o][0];
        float4 wB = *(const float4*)&w1s[o][4];
        float sc = sc1s[o], sh = sh1s[o];
        float xv[14];
        #pragma unroll
        for (int j = 0; j < 14; j++) xv[j] = xt[c][(wave << 3) + j];
        #pragma unroll
        for (int i = 0; i < 8; i++) {
            int ss = (wave << 3) + i;
            float p = xv[i]   * wA.x + xv[i+1] * wA.y + xv[i+2] * wA.z + xv[i+3] * wA.w
                    + xv[i+4] * wB.x + xv[i+5] * wB.y + xv[i+6] * wB.z;
            float g = gelu_tanh(fmaf(p, sc, sh));
            int slot = ((lane & 63) >> 3) ^ (ss & 7);
            Ab[buf][(ss << 6) + (slot << 3) + (lane & 7)] = f2bf(g);
        }
    };

    const int wr = wave >> 1, wc = wave & 1;
    const int lrow = lane & 15, lq = lane >> 4;
    f32x4 acc[4];
    #pragma unroll
    for (int i = 0; i < 4; i++) acc[i] = (f32x4){0.f, 0.f, 0.f, 0.f};

    auto mfmaPhase = [&](int buf) {
        #pragma unroll
        for (int ks = 0; ks < 2; ++ks) {
            int G = (ks << 2) + lq;
            int arow = (wr << 4) + lrow;
            short8 a = *(const short8*)&Ab[buf][(arow << 6) + ((G ^ (arow & 7)) << 3)];
            #pragma unroll
            for (int nf = 0; nf < 4; ++nf) {
                int e = (wc << 6) + (nf << 4) + lrow;
                short8 bf = *(const short8*)&Bbuf[buf][(e << 6) + ((G ^ (e & 7)) << 3)];
                acc[nf] = __builtin_amdgcn_mfma_f32_16x16x32_bf16(a, bf, acc[nf], 0, 0, 0);
            }
        }
    };

    stageB(0, 0);
    __syncthreads();
    computeH1(0, 0);
    __syncthreads();
    for (int kb = 0; kb < 128; ++kb) {
        int cur = kb & 1;
        if (kb < 127) stageB(kb + 1, cur ^ 1);
        mfmaPhase(cur);
        if (kb < 127) computeH1(kb + 1, cur ^ 1);
        __syncthreads();
    }

    #pragma unroll
    for (int nf = 0; nf < 4; ++nf) {
        int e = (wc << 6) + (nf << 4) + lrow;
        float sc2 = ws[BN2SC_OFF + e], sh2 = ws[BN2SH_OFF + e];
        #pragma unroll
        for (int r = 0; r < 4; ++r) {
            int srow = s0 + (wr << 4) + (lq << 2) + r;
            float h2 = fmaf(acc[nf][r], sc2, sh2);
            ws[XSRC_OFF + (((size_t)(b * SS + srow)) << 7) + e] = gelu_exact(h2);
        }
    }
}

// ---------------- K2: QKV projection -> f16 QH(scaled)/KH/VHT ----------------
__global__ __launch_bounds__(256) void k2_qkv(const float* __restrict__ wq,
                                              const float* __restrict__ wk,
                                              const float* __restrict__ wv,
                                              float* __restrict__ ws) {
    __shared__ float xs[16][128];
    int bs0 = blockIdx.x * 16;
    int t = threadIdx.x;
    for (int i = t; i < 16 * 128; i += 256) {
        int r = i >> 7, d = i & 127;
        int bs = bs0 + r;
        int sl = bs & (SS - 1);
        xs[r][d] = ws[XSRC_OFF + (size_t)bs * EE + d] + ws[PE_OFF + sl * EE + d];
    }
    __syncthreads();
    int e = t & 127, rg = t >> 7;
    float aq[8], ak[8], av[8];
    #pragma unroll
    for (int i = 0; i < 8; i++) { aq[i] = 0.f; ak[i] = 0.f; av[i] = 0.f; }
    for (int d = 0; d < 128; d++) {
        float wqv = wq[e * 128 + d], wkv = wk[e * 128 + d], wvv = wv[e * 128 + d];
        #pragma unroll
        for (int r = 0; r < 8; r++) {
            float xv = xs[rg * 8 + r][d];
            aq[r] += xv * wqv; ak[r] += xv * wkv; av[r] += xv * wvv;
        }
    }
    int h = e >> 4, d2 = e & 15;
    f16_t* qh  = (f16_t*)(ws + Q_OFF);
    f16_t* kh  = (f16_t*)(ws + KK_OFF);
    f16_t* vht = (f16_t*)(ws + V_OFF);
    int bs_first = bs0 + rg * 8;
    int bb = bs_first >> 10, sl0 = bs_first & 1023;
    half8 vv;
    #pragma unroll
    for (int r = 0; r < 8; r++) {
        size_t off = (((size_t)(bb * HH + h)) * SS + sl0 + r) * DHH + d2;
        qh[off] = (f16_t)(aq[r] * 0.08838834764831845f);   // fold E^-0.5 into Q
        kh[off] = (f16_t)ak[r];
        vv[r] = (f16_t)av[r];
    }
    *(half8*)&vht[(((size_t)(bb * HH + h)) * DHH + d2) * SS + sl0] = vv;
}

// ---------------- K3a: flash softmax attention via mfma 16x16x16 f16 ----------------
// Per wave: 16 q-rows. S^T-tile = mfma(A=K-frag, B=Q-frag); lane holds 4 scores of
// ONE q-row (j=4g+r) -> exp in regs -> exactly the B-frag layout PV needs:
// out^T = mfma(A=V^T-frag, B=P^T). No LDS, no barriers, no shuffles (except final l).
__global__ __launch_bounds__(256) void k3a_flash(float* __restrict__ ws) {
    const int bh = blockIdx.x;              // b*H + h
    const int w = threadIdx.x >> 6, lane = threadIdx.x & 63;
    const int q = lane & 15, g = lane >> 4;
    const int i = blockIdx.y * 64 + w * 16 + q;

    const f16_t* QH  = (const f16_t*)(ws + Q_OFF)  + (size_t)bh * SS * DHH;
    const f16_t* KH  = (const f16_t*)(ws + KK_OFF) + (size_t)bh * SS * DHH;
    const f16_t* VHT = (const f16_t*)(ws + V_OFF)  + (size_t)bh * DHH * SS;

    half4 qf = *(const half4*)&QH[(size_t)i * DHH + 4 * g];
    f32x4 o = {0.f, 0.f, 0.f, 0.f};
    const f32x4 zf = {0.f, 0.f, 0.f, 0.f};
    float lp = 0.f;

    #pragma unroll 4
    for (int jt = 0; jt < 64; ++jt) {
        half4 kf = *(const half4*)&KH[(size_t)(jt * 16 + q) * DHH + 4 * g];
        f32x4 s = __builtin_amdgcn_mfma_f32_16x16x16f16(kf, qf, zf, 0, 0, 0);
        float p0 = __expf(s[0]), p1 = __expf(s[1]), p2 = __expf(s[2]), p3 = __expf(s[3]);
        lp += (p0 + p1) + (p2 + p3);
        half4 pf;
        pf[0] = (f16_t)p0; pf[1] = (f16_t)p1; pf[2] = (f16_t)p2; pf[3] = (f16_t)p3;
        half4 vf = *(const half4*)&VHT[(size_t)q * SS + jt * 16 + 4 * g];
        o = __builtin_amdgcn_mfma_f32_16x16x16f16(vf, pf, o, 0, 0, 0);
    }
    lp += __shfl_xor(lp, 16);
    lp += __shfl_xor(lp, 32);
    float inv = 1.f / lp;
    int b = bh >> 3, h = bh & 7;
    float4 ov = make_float4(o[0] * inv, o[1] * inv, o[2] * inv, o[3] * inv);
    *(float4*)&ws[ATTN_OFF + ((size_t)(b * SS) + i) * EE + h * DHH + 4 * g] = ov;
}

// ---------------- K3b: rel-bias term Bv = Toeplitz(tbl_h) . V, added into ATTN ----------------
// bias applied AFTER softmax in the reference => out += sum_j tbl[i-j+1023] v_j.
// B-frag (bias) built from reversed LDS table, reused across all 8 batches.
__global__ __launch_bounds__(256) void k3b_bias(const float* __restrict__ rel_tab,
                                                float* __restrict__ ws) {
    __shared__ f16_t rtbl[1092];
    const int h = blockIdx.x;              // 8
    const int i0b = blockIdx.y * 64;       // 16 chunks
    const int t = threadIdx.x;
    for (int u = t; u < 1087; u += 256)
        rtbl[u] = (f16_t)rel_tab[(i0b + 1086 - u) * HH + h];
    __syncthreads();

    const int w = t >> 6, lane = t & 63;
    const int q = lane & 15, g = lane >> 4;
    const int r = w * 16 + q;              // i-offset within block (B-frag col)
    const f16_t* VHT = (const f16_t*)(ws + V_OFF);

    f32x4 acc[8];
    #pragma unroll
    for (int b = 0; b < 8; ++b) acc[b] = (f32x4){0.f, 0.f, 0.f, 0.f};

    for (int jt = 0; jt < 64; ++jt) {
        int vb = 63 - r + jt * 16 + 4 * g;
        half4 bfrag;
        bfrag[0] = rtbl[vb]; bfrag[1] = rtbl[vb + 1];
        bfrag[2] = rtbl[vb + 2]; bfrag[3] = rtbl[vb + 3];
        #pragma unroll
        for (int b = 0; b < 8; ++b) {
            half4 vf = *(const half4*)&VHT[((size_t)(b * HH + h) * DHH + q) * SS + jt * 16 + 4 * g];
            acc[b] = __builtin_amdgcn_mfma_f32_16x16x16f16(vf, bfrag, acc[b], 0, 0, 0);
        }
    }
    int i = i0b + r;
    #pragma unroll
    for (int b = 0; b < 8; ++b) {
        float4* p = (float4*)&ws[ATTN_OFF + ((size_t)(b * SS) + i) * EE + h * DHH + 4 * g];
        float4 o = *p;
        o.x += acc[b][0]; o.y += acc[b][1]; o.z += acc[b][2]; o.w += acc[b][3];
        *p = o;
    }
}

// ---------------- K4: LN(attn) -> +x_src -> LN1 -> att ----------------
__global__ __launch_bounds__(256) void k4_ln(const float* __restrict__ g_attn, const float* __restrict__ b_attn,
                                             const float* __restrict__ g1, const float* __restrict__ b1,
                                             float* __restrict__ ws) {
    int row = blockIdx.x * 4 + (threadIdx.x >> 6);
    int lane = threadIdx.x & 63;
    int e0 = lane * 2;
    const float* ain = ws + ATTN_OFF + (size_t)row * EE;
    const float* xsr = ws + XSRC_OFF + (size_t)row * EE;
    float2 a = *(const float2*)(ain + e0);
    float mean = wave_sum(a.x + a.y) * (1.f / 128.f);
    float dx = a.x - mean, dy = a.y - mean;
    float var = wave_sum(dx * dx + dy * dy) * (1.f / 128.f);
    float inv = rsqrtf(var + 1e-5f);
    float n0 = dx * inv * g_attn[e0] + b_attn[e0];
    float n1 = dy * inv * g_attn[e0 + 1] + b_attn[e0 + 1];
    float2 xs2 = *(const float2*)(xsr + e0);
    float z0 = xs2.x + n0, z1 = xs2.y + n1;
    float m2 = wave_sum(z0 + z1) * (1.f / 128.f);
    float d0 = z0 - m2, d1 = z1 - m2;
    float v2 = wave_sum(d0 * d0 + d1 * d1) * (1.f / 128.f);
    float inv2 = rsqrtf(v2 + 1e-5f);
    float o0 = d0 * inv2 * g1[e0] + b1[e0];
    float o1 = d1 * inv2 * g1[e0 + 1] + b1[e0 + 1];
    *(float2*)(ws + ATT_OFF + (size_t)row * EE + e0) = make_float2(o0, o1);
}

// ---------------- K5: FF1 + bias + relu ----------------
__global__ __launch_bounds__(256) void k5_ff1(const float* __restrict__ w1,
                                              const float* __restrict__ b1,
                                              float* __restrict__ ws) {
    __shared__ float xs[16][128];
    int bs0 = blockIdx.x * 16;
    int t = threadIdx.x;
    for (int i = t; i < 2048; i += 256) ((float*)xs)[i] = ws[ATT_OFF + (size_t)bs0 * EE + i];
    __syncthreads();
    float accA[16], accB[16];
    #pragma unroll
    for (int r = 0; r < 16; r++) { accA[r] = 0.f; accB[r] = 0.f; }
    int c = t;
    for (int d = 0; d < 128; d++) {
        float wa = w1[c * 128 + d], wb = w1[(c + 256) * 128 + d];
        #pragma unroll
        for (int r = 0; r < 16; r++) {
            float xv = xs[r][d];
            accA[r] += xv * wa;
            accB[r] += xv * wb;
        }
    }
    float ba = b1[c], bb = b1[c + 256];
    #pragma unroll
    for (int r = 0; r < 16; r++) {
        ws[FFH_OFF + (size_t)(bs0 + r) * DFFN + c]       = fmaxf(accA[r] + ba, 0.f);
        ws[FFH_OFF + (size_t)(bs0 + r) * DFFN + c + 256] = fmaxf(accB[r] + bb, 0.f);
    }
}

// ---------------- K6: FF2 + bias + residual + LN2 + transposed store ----------------
__global__ __launch_bounds__(256) void k6_ff2(const float* __restrict__ w2,
                                              const float* __restrict__ b2,
                                              const float* __restrict__ g2, const float* __restrict__ bb2,
                                              float* __restrict__ ws, float* __restrict__ out) {
    __shared__ float fs[16][512];     // 32 KB
    __shared__ float y[16][132];      // padded
    int bs0 = blockIdx.x * 16;
    int t = threadIdx.x;
    for (int i = t; i < 16 * 512; i += 256) ((float*)fs)[i] = ws[FFH_OFF + (size_t)bs0 * DFFN + i];
    __syncthreads();
    int c = t & 127, rg = t >> 7;
    float acc[8];
    #pragma unroll
    for (int r = 0; r < 8; r++) acc[r] = 0.f;
    for (int f = 0; f < 512; f++) {
        float wv = w2[c * 512 + f];
        #pragma unroll
        for (int r = 0; r < 8; r++) acc[r] += fs[rg * 8 + r][f] * wv;
    }
    float bv = b2[c];
    #pragma unroll
    for (int r = 0; r < 8; r++) {
        int row = rg * 8 + r;
        y[row][c] = acc[r] + bv + ws[ATT_OFF + (size_t)(bs0 + row) * EE + c];
    }
    __syncthreads();
    int wid = t >> 6, lane = t & 63;
    int e0 = lane * 2;
    for (int rr = 0; rr < 4; rr++) {
        int row = wid * 4 + rr;
        float z0 = y[row][e0], z1 = y[row][e0 + 1];
        float mean = wave_sum(z0 + z1) * (1.f / 128.f);
        float d0 = z0 - mean, d1 = z1 - mean;
        float var = wave_sum(d0 * d0 + d1 * d1) * (1.f / 128.f);
        float inv = rsqrtf(var + 1e-5f);
        y[row][e0]     = d0 * inv * g2[e0] + bb2[e0];
        y[row][e0 + 1] = d1 * inv * g2[e0 + 1] + bb2[e0 + 1];
    }
    __syncthreads();
    int b = bs0 >> 10, s0 = bs0 & 1023;
    int sl = t & 15, egr = t >> 4;
    #pragma unroll
    for (int rep = 0; rep < 8; rep++) {
        int e = egr + rep * 16;
        out[(size_t)b * EE * SS + (size_t)e * SS + s0 + sl] = y[sl][e];
    }
}

extern "C" void kernel_launch(void* const* d_in, const int* in_sizes, int n_in,
                              void* d_out, int out_size, void* d_ws, size_t ws_size,
                              hipStream_t stream) {
    const float* x        = (const float*)d_in[0];
    const float* conv1_w  = (const float*)d_in[1];
    const float* conv1_b  = (const float*)d_in[2];
    const float* bn1_g    = (const float*)d_in[3];
    const float* bn1_b    = (const float*)d_in[4];
    const float* bn1_m    = (const float*)d_in[5];
    const float* bn1_v    = (const float*)d_in[6];
    const float* conv2_w  = (const float*)d_in[7];
    const float* conv2_b  = (const float*)d_in[8];
    const float* bn2_g    = (const float*)d_in[9];
    const float* bn2_b    = (const float*)d_in[10];
    const float* bn2_m    = (const float*)d_in[11];
    const float* bn2_v    = (const float*)d_in[12];
    const float* wq       = (const float*)d_in[13];
    const float* wk       = (const float*)d_in[14];
    const float* wv       = (const float*)d_in[15];
    const float* rel_tab  = (const float*)d_in[16];
    const float* ln_attn_g = (const float*)d_in[17];
    const float* ln_attn_b = (const float*)d_in[18];
    const float* ln1_g    = (const float*)d_in[19];
    const float* ln1_b    = (const float*)d_in[20];
    const float* ln2_g    = (const float*)d_in[21];
    const float* ln2_b    = (const float*)d_in[22];
    const float* ff_w1    = (const float*)d_in[23];
    const float* ff_b1    = (const float*)d_in[24];
    const float* ff_w2    = (const float*)d_in[25];
    const float* ff_b2    = (const float*)d_in[26];

    float* ws  = (float*)d_ws;
    float* out = (float*)d_out;

    hipLaunchKernelGGL(k0_pe, dim3(512), dim3(256), 0, stream, ws);
    hipLaunchKernelGGL(k0_bn, dim3(1), dim3(640), 0, stream,
                       conv1_b, bn1_g, bn1_b, bn1_m, bn1_v,
                       conv2_b, bn2_g, bn2_b, bn2_m, bn2_v, ws);
    hipLaunchKernelGGL(k0_w2cast, dim3(512), dim3(256), 0, stream, conv2_w, ws);
    hipLaunchKernelGGL(k1_mfma, dim3(256), dim3(256), 0, stream, x, conv1_w, ws);
    hipLaunchKernelGGL(k2_qkv, dim3(BB * SS / 16), dim3(256), 0, stream, wq, wk, wv, ws);
    hipLaunchKernelGGL(k3a_flash, dim3(BB * HH, SS / 64), dim3(256), 0, stream, ws);
    hipLaunchKernelGGL(k3b_bias, dim3(HH, SS / 64), dim3(256), 0, stream, rel_tab, ws);
    hipLaunchKernelGGL(k4_ln, dim3(BB * SS / 4), dim3(256), 0, stream, ln_attn_g, ln_attn_b, ln1_g, ln1_b, ws);
    hipLaunchKernelGGL(k5_ff1, dim3(BB * SS / 16), dim3(256), 0, stream, ff_w1, ff_b1, ws);
    hipLaunchKernelGGL(k6_ff2, dim3(BB * SS / 16), dim3(256), 0, stream, ff_w2, ff_b2, ln2_g, ln2_b, ws, out);
}

// Round 6
// 249.882 us; speedup vs baseline: 5.2424x; 1.4750x over previous
//
#include <hip/hip_runtime.h>
#include <math.h>

// Problem constants
#define BB    8
#define CIN   16
#define SS    1024
#define EE    128
#define HH    8
#define DHH   16
#define O1    512      // E*4
#define DFFN  512
#define K2TOT 8192     // O1*CIN

// Workspace layout (float offsets)
#define PE_OFF    0            // 131072  (S*E)
#define BN1SC_OFF 131072       // 512
#define BN1SH_OFF 131584       // 512
#define BN2SC_OFF 132096       // 128
#define BN2SH_OFF 132224       // 128
#define WQKV_BF_OFF 135168     // bf16 wq|wk|wv, each [2kb][128e][64] = 16384 elems (24576 floats)
#define W1FF_BF_OFF 159744     // bf16 ff_w1 [4nb][2kb][128][64] = 65536 elems (32768 floats)
#define W2FF_BF_OFF 192512     // bf16 ff_w2 [8kb][128][64] = 65536 elems (32768 floats)
#define XSRC_OFF  262144       // 1048576 (B*S*E) fp32
#define Q_OFF     1310720      // QH: f16[B*H*S*16] scaled
#define KK_OFF    2359296      // KH: f16[B*H*S*16]
#define V_OFF     3407872      // VHT: f16[B*H*16*S] (d-major, transposed)
#define ATTN_OFF  4456448      // 1048576 (B,S,E) attention out (k3a writes, k3b adds)
#define ATT_OFF   5505024      // 1048576 (B,S,E) post-LN1 fp32
#define FFHB_OFF  6553600      // bf16 FF1 out, swizzled [256rt][8kb][32ss][64] = 4M elems (2M floats)
#define W2CONV_BF_OFF 8650752  // bf16 conv2_w [128kb][128e][64] = 1M elems (512K floats)
// end: 9175040 floats = 36.7 MB

typedef __attribute__((ext_vector_type(8))) short short8;
typedef __attribute__((ext_vector_type(8))) unsigned short ushort8;
typedef __attribute__((ext_vector_type(4))) unsigned short us4;
typedef __attribute__((ext_vector_type(4))) float f32x4;
typedef _Float16 f16_t;
typedef __attribute__((ext_vector_type(4))) _Float16 half4;
typedef __attribute__((ext_vector_type(8))) _Float16 half8;

__device__ __forceinline__ float wave_sum(float v) {
    #pragma unroll
    for (int o = 32; o > 0; o >>= 1) v += __shfl_xor(v, o);
    return v;
}

__device__ __forceinline__ float gelu_exact(float x) {
    return 0.5f * x * (1.0f + erff(x * 0.7071067811865476f));
}

__device__ __forceinline__ float gelu_tanh(float x) {
    float x2 = x * x;
    float y = x * fmaf(0.0356774081f, x2, 0.7978845608f);
    float E = __expf(2.0f * y);
    float r = __builtin_amdgcn_rcpf(E + 1.0f);
    return x - x * r;            // x * E/(E+1)
}

__device__ __forceinline__ unsigned short f2bf(float f) {   // RNE fp32->bf16
    unsigned int u = __float_as_uint(f);
    unsigned int r = u + 0x7FFFu + ((u >> 16) & 1u);
    return (unsigned short)(r >> 16);
}

// ---------------- K0a: positional encoding table ----------------
__global__ __launch_bounds__(256) void k0_pe(float* __restrict__ ws) {
    int idx = blockIdx.x * 256 + threadIdx.x;   // 131072 total
    int s = idx >> 7, e = idx & 127;
    int i = e >> 1;
    float freq = expf((float)(2 * i) * (-9.210340371976184f / 128.0f));
    float ang = (float)s * freq * 0.125f;
    ws[PE_OFF + idx] = (e & 1) ? cosf(ang) : sinf(ang);
}

// ---------------- K0b: fold conv-bias + BN into scale/shift ----------------
__global__ void k0_bn(const float* __restrict__ conv1_b, const float* __restrict__ bn1_g,
                      const float* __restrict__ bn1_b, const float* __restrict__ bn1_m,
                      const float* __restrict__ bn1_v,
                      const float* __restrict__ conv2_b, const float* __restrict__ bn2_g,
                      const float* __restrict__ bn2_b, const float* __restrict__ bn2_m,
                      const float* __restrict__ bn2_v,
                      float* __restrict__ ws) {
    int t = threadIdx.x;
    if (t < 512) {
        float sc = bn1_g[t] * rsqrtf(bn1_v[t] + 1e-5f);
        ws[BN1SC_OFF + t] = sc;
        ws[BN1SH_OFF + t] = (conv1_b[t] - bn1_m[t]) * sc + bn1_b[t];
    } else if (t < 640) {
        int e = t - 512;
        float sc = bn2_g[e] * rsqrtf(bn2_v[e] + 1e-5f);
        ws[BN2SC_OFF + e] = sc;
        ws[BN2SH_OFF + e] = (conv2_b[e] - bn2_m[e]) * sc + bn2_b[e];
    }
}

// ---------------- K0c: generic weight cast fp32 -> bf16, chunk-major, pre-swizzled ----------
// dst layout [nb][kb][e 128][g 8][j 8]; dst[e][g] holds src k-group g^(e&7) so a linear
// global_load_lds stage + swizzled ds_read yields bank-conflict-free B-frags (m173 pattern).
__global__ __launch_bounds__(256) void k0_castw(const float* __restrict__ src,
                                                unsigned short* __restrict__ dst, int K) {
    int tid = blockIdx.x * 256 + threadIdx.x;   // total = ncols*K/8
    int g = tid & 7, e = (tid >> 3) & 127, rest = tid >> 10;
    int KB = K >> 6;
    int kb = rest % KB, nb = rest / KB;
    int col = nb * 128 + e;
    const float* s = src + (size_t)col * K + kb * 64 + ((g ^ (e & 7)) << 3);
    ushort8 v;
    #pragma unroll
    for (int j = 0; j < 8; j++) v[j] = f2bf(s[j]);
    *(ushort8*)&dst[(size_t)tid << 3] = v;
}

// ---------------- K1: fused conv1+bn1+gelu -> conv2 (bf16 MFMA) + bn2+gelu ----------------
// BM=16, grid 512 -> 2 blocks/CU (LDS ~58KB) so independent blocks overlap barrier drains.
__global__ __launch_bounds__(256) void k1_mfma(const float* __restrict__ x,
                                               const float* __restrict__ w1,
                                               float* __restrict__ ws) {
    __shared__ float xt[CIN][24];                 // x[b,c, s0-3 .. s0+18]
    __shared__ float w1s[O1][8];
    __shared__ float sc1s[O1], sh1s[O1];
    __shared__ unsigned short Ab[2][16 * 64];     // 2x2KB
    __shared__ unsigned short Bbuf[2][128 * 64];  // 2x16KB

    const int t = threadIdx.x;
    const int wave = t >> 6, lane = t & 63;
    const int row0 = blockIdx.x * 16;
    const int b = row0 >> 10, s0 = row0 & 1023;

    for (int i = t; i < CIN * 22; i += 256) {
        int c = i / 22, j = i % 22;
        int gs = s0 + j - 3;
        xt[c][j] = (gs >= 0 && gs < SS) ? x[(b * CIN + c) * SS + gs] : 0.f;
    }
    for (int i = t; i < O1 * 7; i += 256) w1s[i / 7][i % 7] = w1[i];
    for (int i = t; i < O1; i += 256) { sc1s[i] = ws[BN1SC_OFF + i]; sh1s[i] = ws[BN1SH_OFF + i]; }

    const char* w2g = (const char*)(ws + W2CONV_BF_OFF);

    auto stageB = [&](int kb, int buf) {
        const char* g = w2g + ((size_t)kb << 14);
        #pragma unroll
        for (int c4 = 0; c4 < 4; ++c4) {
            int off = c4 * 4096 + wave * 1024;
            __builtin_amdgcn_global_load_lds(
                (const __attribute__((address_space(1))) unsigned int*)(g + off + lane * 16),
                (__attribute__((address_space(3))) unsigned int*)(&Bbuf[buf][off >> 1]),
                16, 0, 0);
        }
    };

    stageB(0, 0);
    __syncthreads();                              // xt/w1s ready; B[0] drained

    // hoist kb-invariant x taps into registers (was 14 ds_reads per chunk)
    const int c_ = lane & 15;
    float xv[10];
    #pragma unroll
    for (int j = 0; j < 10; j++) xv[j] = xt[c_][(wave << 2) + j];

    auto computeH1 = [&](int kb, int buf) {
        int o = (kb << 2) + (lane >> 4);
        float4 wA = *(const float4*)&w1s[o][0];
        float4 wB = *(const float4*)&w1s[o][4];
        float sc = sc1s[o], sh = sh1s[o];
        #pragma unroll
        for (int i = 0; i < 4; i++) {
            int ss = (wave << 2) + i;
            float p = xv[i]   * wA.x + xv[i+1] * wA.y + xv[i+2] * wA.z + xv[i+3] * wA.w
                    + xv[i+4] * wB.x + xv[i+5] * wB.y + xv[i+6] * wB.z;
            float g = gelu_tanh(fmaf(p, sc, sh));
            int slot = (lane >> 3) ^ (ss & 7);
            Ab[buf][(ss << 6) + (slot << 3) + (lane & 7)] = f2bf(g);
        }
    };

    const int lrow = lane & 15, lq = lane >> 4;
    f32x4 acc[2];
    acc[0] = (f32x4){0.f, 0.f, 0.f, 0.f};
    acc[1] = (f32x4){0.f, 0.f, 0.f, 0.f};

    auto mfmaPhase = [&](int buf) {
        #pragma unroll
        for (int ks = 0; ks < 2; ++ks) {
            int G = (ks << 2) + lq;
            short8 a = *(const short8*)&Ab[buf][(lrow << 6) + ((G ^ (lrow & 7)) << 3)];
            #pragma unroll
            for (int nf = 0; nf < 2; ++nf) {
                int e = (wave << 5) + (nf << 4) + lrow;
                short8 bf = *(const short8*)&Bbuf[buf][(e << 6) + ((G ^ (e & 7)) << 3)];
                acc[nf] = __builtin_amdgcn_mfma_f32_16x16x32_bf16(a, bf, acc[nf], 0, 0, 0);
            }
        }
    };

    computeH1(0, 0);
    __syncthreads();
    for (int kb = 0; kb < 128; ++kb) {
        int cur = kb & 1;
        if (kb < 127) stageB(kb + 1, cur ^ 1);
        mfmaPhase(cur);
        if (kb < 127) computeH1(kb + 1, cur ^ 1);
        __syncthreads();
    }

    #pragma unroll
    for (int nf = 0; nf < 2; ++nf) {
        int e = (wave << 5) + (nf << 4) + lrow;
        float sc2 = ws[BN2SC_OFF + e], sh2 = ws[BN2SH_OFF + e];
        #pragma unroll
        for (int r = 0; r < 4; ++r) {
            int srow = s0 + (lq << 2) + r;
            float h2 = fmaf(acc[nf][r], sc2, sh2);
            ws[XSRC_OFF + (((size_t)(b * SS + srow)) << 7) + e] = gelu_exact(h2);
        }
    }
}

// ---------------- K2: QKV projection via MFMA -> f16 QH(scaled)/KH/VHT ----------------
// grid (256 row-tiles, 3 matrices). A = (XSRC+PE) cast to swizzled LDS; B = pre-swizzled bf16.
__global__ __launch_bounds__(256) void k2_mfma(float* __restrict__ ws) {
    __shared__ unsigned short As[32 * 128];       // 8KB
    __shared__ unsigned short Bs[128 * 128];      // 32KB
    const int t = threadIdx.x;
    const int rt = blockIdx.x, mat = blockIdx.y;
    const int wave = t >> 6, lane = t & 63;

    const char* bg = (const char*)((const unsigned short*)(ws + WQKV_BF_OFF) + mat * 16384);
    #pragma unroll
    for (int c8 = 0; c8 < 8; ++c8) {
        int off = c8 * 4096 + wave * 1024;
        __builtin_amdgcn_global_load_lds(
            (const __attribute__((address_space(1))) unsigned int*)(bg + off + lane * 16),
            (__attribute__((address_space(3))) unsigned int*)(&Bs[off >> 1]), 16, 0, 0);
    }
    const int bs0 = rt * 32;
    const int sl0 = bs0 & 1023;
    for (int i = t; i < 1024; i += 256) {
        int row = i >> 5, d0 = (i & 31) << 2;
        float4 xv = *(const float4*)&ws[XSRC_OFF + (size_t)(bs0 + row) * EE + d0];
        float4 pv = *(const float4*)&ws[PE_OFF + (size_t)(sl0 + row) * EE + d0];
        us4 o;
        o[0] = f2bf(xv.x + pv.x); o[1] = f2bf(xv.y + pv.y);
        o[2] = f2bf(xv.z + pv.z); o[3] = f2bf(xv.w + pv.w);
        int slot = (d0 >> 3) ^ (row & 7);
        *(us4*)&As[(row << 7) + (slot << 3) + (d0 & 7)] = o;
    }
    __syncthreads();

    const int wr = wave >> 1, wc = wave & 1;
    const int lrow = lane & 15, lq = lane >> 4;
    f32x4 acc[4];
    #pragma unroll
    for (int i = 0; i < 4; i++) acc[i] = (f32x4){0.f, 0.f, 0.f, 0.f};

    #pragma unroll
    for (int ks = 0; ks < 4; ++ks) {
        int G = (ks << 2) + lq;
        int arow = (wr << 4) + lrow;
        short8 a = *(const short8*)&As[(arow << 7) + ((G ^ (arow & 7)) << 3)];
        #pragma unroll
        for (int nf = 0; nf < 4; ++nf) {
            int e = (wc << 6) + (nf << 4) + lrow;
            short8 bf = *(const short8*)&Bs[((G >> 3) << 13) + (e << 6) + (((G & 7) ^ (e & 7)) << 3)];
            acc[nf] = __builtin_amdgcn_mfma_f32_16x16x32_bf16(a, bf, acc[nf], 0, 0, 0);
        }
    }

    f16_t* qh  = (f16_t*)(ws + Q_OFF);
    f16_t* kh  = (f16_t*)(ws + KK_OFF);
    f16_t* vht = (f16_t*)(ws + V_OFF);
    #pragma unroll
    for (int nf = 0; nf < 4; ++nf) {
        int e = (wc << 6) + (nf << 4) + lrow;
        int h = e >> 4, d2 = e & 15;
        #pragma unroll
        for (int r = 0; r < 4; ++r) {
            int bs = bs0 + (wr << 4) + (lq << 2) + r;
            int b = bs >> 10, sl = bs & 1023;
            float v = acc[nf][r];
            if (mat == 0)      qh[(((size_t)(b * HH + h)) * SS + sl) * DHH + d2] = (f16_t)(v * 0.08838834764831845f);
            else if (mat == 1) kh[(((size_t)(b * HH + h)) * SS + sl) * DHH + d2] = (f16_t)v;
            else               vht[(((size_t)(b * HH + h)) * DHH + d2) * SS + sl] = (f16_t)v;
        }
    }
}

// ---------------- K3a: flash softmax attention via mfma 16x16x16 f16 ----------------
__global__ __launch_bounds__(256) void k3a_flash(float* __restrict__ ws) {
    const int bh = blockIdx.x;              // b*H + h
    const int w = threadIdx.x >> 6, lane = threadIdx.x & 63;
    const int q = lane & 15, g = lane >> 4;
    const int i = blockIdx.y * 64 + w * 16 + q;

    const f16_t* QH  = (const f16_t*)(ws + Q_OFF)  + (size_t)bh * SS * DHH;
    const f16_t* KH  = (const f16_t*)(ws + KK_OFF) + (size_t)bh * SS * DHH;
    const f16_t* VHT = (const f16_t*)(ws + V_OFF)  + (size_t)bh * DHH * SS;

    half4 qf = *(const half4*)&QH[(size_t)i * DHH + 4 * g];
    f32x4 o = {0.f, 0.f, 0.f, 0.f};
    const f32x4 zf = {0.f, 0.f, 0.f, 0.f};
    float lp = 0.f;

    #pragma unroll 4
    for (int jt = 0; jt < 64; ++jt) {
        half4 kf = *(const half4*)&KH[(size_t)(jt * 16 + q) * DHH + 4 * g];
        f32x4 s = __builtin_amdgcn_mfma_f32_16x16x16f16(kf, qf, zf, 0, 0, 0);
        float p0 = __expf(s[0]), p1 = __expf(s[1]), p2 = __expf(s[2]), p3 = __expf(s[3]);
        lp += (p0 + p1) + (p2 + p3);
        half4 pf;
        pf[0] = (f16_t)p0; pf[1] = (f16_t)p1; pf[2] = (f16_t)p2; pf[3] = (f16_t)p3;
        half4 vf = *(const half4*)&VHT[(size_t)q * SS + jt * 16 + 4 * g];
        o = __builtin_amdgcn_mfma_f32_16x16x16f16(vf, pf, o, 0, 0, 0);
    }
    lp += __shfl_xor(lp, 16);
    lp += __shfl_xor(lp, 32);
    float inv = 1.f / lp;
    int b = bh >> 3, h = bh & 7;
    float4 ov = make_float4(o[0] * inv, o[1] * inv, o[2] * inv, o[3] * inv);
    *(float4*)&ws[ATTN_OFF + ((size_t)(b * SS) + i) * EE + h * DHH + 4 * g] = ov;
}

// ---------------- K3b: rel-bias term Bv = Toeplitz(tbl_h) . V, added into ATTN ----------------
__global__ __launch_bounds__(256) void k3b_bias(const float* __restrict__ rel_tab,
                                                float* __restrict__ ws) {
    __shared__ f16_t rtbl[1092];
    const int h = blockIdx.x;              // 8
    const int i0b = blockIdx.y * 64;       // 16 chunks
    const int t = threadIdx.x;
    for (int u = t; u < 1087; u += 256)
        rtbl[u] = (f16_t)rel_tab[(i0b + 1086 - u) * HH + h];
    __syncthreads();

    const int w = t >> 6, lane = t & 63;
    const int q = lane & 15, g = lane >> 4;
    const int r = w * 16 + q;
    const f16_t* VHT = (const f16_t*)(ws + V_OFF);

    f32x4 acc[8];
    #pragma unroll
    for (int b = 0; b < 8; ++b) acc[b] = (f32x4){0.f, 0.f, 0.f, 0.f};

    for (int jt = 0; jt < 64; ++jt) {
        int vb = 63 - r + jt * 16 + 4 * g;
        half4 bfrag;
        bfrag[0] = rtbl[vb]; bfrag[1] = rtbl[vb + 1];
        bfrag[2] = rtbl[vb + 2]; bfrag[3] = rtbl[vb + 3];
        #pragma unroll
        for (int b = 0; b < 8; ++b) {
            half4 vf = *(const half4*)&VHT[((size_t)(b * HH + h) * DHH + q) * SS + jt * 16 + 4 * g];
            acc[b] = __builtin_amdgcn_mfma_f32_16x16x16f16(vf, bfrag, acc[b], 0, 0, 0);
        }
    }
    int i = i0b + r;
    #pragma unroll
    for (int b = 0; b < 8; ++b) {
        float4* p = (float4*)&ws[ATTN_OFF + ((size_t)(b * SS) + i) * EE + h * DHH + 4 * g];
        float4 o = *p;
        o.x += acc[b][0]; o.y += acc[b][1]; o.z += acc[b][2]; o.w += acc[b][3];
        *p = o;
    }
}

// ---------------- K4: LN(attn) -> +x_src -> LN1 -> att ----------------
__global__ __launch_bounds__(256) void k4_ln(const float* __restrict__ g_attn, const float* __restrict__ b_attn,
                                             const float* __restrict__ g1, const float* __restrict__ b1,
                                             float* __restrict__ ws) {
    int row = blockIdx.x * 4 + (threadIdx.x >> 6);
    int lane = threadIdx.x & 63;
    int e0 = lane * 2;
    const float* ain = ws + ATTN_OFF + (size_t)row * EE;
    const float* xsr = ws + XSRC_OFF + (size_t)row * EE;
    float2 a = *(const float2*)(ain + e0);
    float mean = wave_sum(a.x + a.y) * (1.f / 128.f);
    float dx = a.x - mean, dy = a.y - mean;
    float var = wave_sum(dx * dx + dy * dy) * (1.f / 128.f);
    float inv = rsqrtf(var + 1e-5f);
    float n0 = dx * inv * g_attn[e0] + b_attn[e0];
    float n1 = dy * inv * g_attn[e0 + 1] + b_attn[e0 + 1];
    float2 xs2 = *(const float2*)(xsr + e0);
    float z0 = xs2.x + n0, z1 = xs2.y + n1;
    float m2 = wave_sum(z0 + z1) * (1.f / 128.f);
    float d0 = z0 - m2, d1 = z1 - m2;
    float v2 = wave_sum(d0 * d0 + d1 * d1) * (1.f / 128.f);
    float inv2 = rsqrtf(v2 + 1e-5f);
    float o0 = d0 * inv2 * g1[e0] + b1[e0];
    float o1 = d1 * inv2 * g1[e0 + 1] + b1[e0 + 1];
    *(float2*)(ws + ATT_OFF + (size_t)row * EE + e0) = make_float2(o0, o1);
}

// ---------------- K5: FF1 via MFMA + bias + relu -> bf16 swizzled FFHB ----------------
// grid (256 row-tiles, 4 n-blocks of 128). Same core as k2; A = ATT.
__global__ __launch_bounds__(256) void k5_mfma(const float* __restrict__ b1,
                                               float* __restrict__ ws) {
    __shared__ unsigned short As[32 * 128];
    __shared__ unsigned short Bs[128 * 128];
    const int t = threadIdx.x;
    const int rt = blockIdx.x, nb = blockIdx.y;
    const int wave = t >> 6, lane = t & 63;

    const char* bg = (const char*)((const unsigned short*)(ws + W1FF_BF_OFF) + nb * 16384);
    #pragma unroll
    for (int c8 = 0; c8 < 8; ++c8) {
        int off = c8 * 4096 + wave * 1024;
        __builtin_amdgcn_global_load_lds(
            (const __attribute__((address_space(1))) unsigned int*)(bg + off + lane * 16),
            (__attribute__((address_space(3))) unsigned int*)(&Bs[off >> 1]), 16, 0, 0);
    }
    const int bs0 = rt * 32;
    for (int i = t; i < 1024; i += 256) {
        int row = i >> 5, d0 = (i & 31) << 2;
        float4 xv = *(const float4*)&ws[ATT_OFF + (size_t)(bs0 + row) * EE + d0];
        us4 o;
        o[0] = f2bf(xv.x); o[1] = f2bf(xv.y); o[2] = f2bf(xv.z); o[3] = f2bf(xv.w);
        int slot = (d0 >> 3) ^ (row & 7);
        *(us4*)&As[(row << 7) + (slot << 3) + (d0 & 7)] = o;
    }
    __syncthreads();

    const int wr = wave >> 1, wc = wave & 1;
    const int lrow = lane & 15, lq = lane >> 4;
    f32x4 acc[4];
    #pragma unroll
    for (int i = 0; i < 4; i++) acc[i] = (f32x4){0.f, 0.f, 0.f, 0.f};

    #pragma unroll
    for (int ks = 0; ks < 4; ++ks) {
        int G = (ks << 2) + lq;
        int arow = (wr << 4) + lrow;
        short8 a = *(const short8*)&As[(arow << 7) + ((G ^ (arow & 7)) << 3)];
        #pragma unroll
        for (int nf = 0; nf < 4; ++nf) {
            int e = (wc << 6) + (nf << 4) + lrow;
            short8 bf = *(const short8*)&Bs[((G >> 3) << 13) + (e << 6) + (((G & 7) ^ (e & 7)) << 3)];
            acc[nf] = __builtin_amdgcn_mfma_f32_16x16x32_bf16(a, bf, acc[nf], 0, 0, 0);
        }
    }

    unsigned short* ffhb = (unsigned short*)(ws + FFHB_OFF);
    #pragma unroll
    for (int nf = 0; nf < 4; ++nf) {
        int fcol = (nb << 7) + (wc << 6) + (nf << 4) + lrow;
        float bias = b1[fcol];
        int kb = fcol >> 6;
        #pragma unroll
        for (int r = 0; r < 4; ++r) {
            int ss = (wr << 4) + (lq << 2) + r;        // row within 32-tile
            float v = fmaxf(acc[nf][r] + bias, 0.f);
            int slot = ((fcol >> 3) & 7) ^ (ss & 7);
            ffhb[(((size_t)(rt * 8 + kb) * 32 + ss) << 6) + (slot << 3) + (fcol & 7)] = f2bf(v);
        }
    }
}

// ---------------- K6: FF2 via MFMA + bias + residual + LN2 + transposed store ----------------
// A = FFHB (bf16 swizzled, global_load_lds), B = ff_w2 bf16 swizzled. 8 chunks dbuf.
__global__ __launch_bounds__(256) void k6_mfma(const float* __restrict__ b2,
                                               const float* __restrict__ g2, const float* __restrict__ bb2,
                                               float* __restrict__ ws, float* __restrict__ out) {
    __shared__ unsigned short Ab[2][2048];    // 2x4KB
    __shared__ unsigned short Bb[2][8192];    // 2x16KB
    __shared__ float y[32][132];              // 16.9KB
    const int t = threadIdx.x;
    const int wave = t >> 6, lane = t & 63;
    const int rt = blockIdx.x;

    const char* ag = (const char*)((const unsigned short*)(ws + FFHB_OFF) + (size_t)rt * 16384);
    const char* bgc = (const char*)(ws + W2FF_BF_OFF);

    auto stage = [&](int kb, int buf) {
        __builtin_amdgcn_global_load_lds(
            (const __attribute__((address_space(1))) unsigned int*)(ag + kb * 4096 + t * 16),
            (__attribute__((address_space(3))) unsigned int*)(&Ab[buf][(t * 16) >> 1]), 16, 0, 0);
        const char* g = bgc + kb * 16384;
        #pragma unroll
        for (int c4 = 0; c4 < 4; ++c4) {
            int off = c4 * 4096 + wave * 1024;
            __builtin_amdgcn_global_load_lds(
                (const __attribute__((address_space(1))) unsigned int*)(g + off + lane * 16),
                (__attribute__((address_space(3))) unsigned int*)(&Bb[buf][off >> 1]), 16, 0, 0);
        }
    };

    const int wr = wave >> 1, wc = wave & 1;
    const int lrow = lane & 15, lq = lane >> 4;
    f32x4 acc[4];
    #pragma unroll
    for (int i = 0; i < 4; i++) acc[i] = (f32x4){0.f, 0.f, 0.f, 0.f};

    stage(0, 0);
    __syncthreads();
    for (int kb = 0; kb < 8; ++kb) {
        int cur = kb & 1;
        if (kb < 7) stage(kb + 1, cur ^ 1);
        #pragma unroll
        for (int ks = 0; ks < 2; ++ks) {
            int G = (ks << 2) + lq;
            int arow = (wr << 4) + lrow;
            short8 a = *(const short8*)&Ab[cur][(arow << 6) + ((G ^ (arow & 7)) << 3)];
            #pragma unroll
            for (int nf = 0; nf < 4; ++nf) {
                int e = (wc << 6) + (nf << 4) + lrow;
                short8 bf = *(const short8*)&Bb[cur][(e << 6) + ((G ^ (e & 7)) << 3)];
                acc[nf] = __builtin_amdgcn_mfma_f32_16x16x32_bf16(a, bf, acc[nf], 0, 0, 0);
            }
        }
        __syncthreads();
    }

    const int bs0 = rt * 32;
    #pragma unroll
    for (int nf = 0; nf < 4; ++nf) {
        int e = (wc << 6) + (nf << 4) + lrow;
        float bv = b2[e];
        #pragma unroll
        for (int r = 0; r < 4; ++r) {
            int row = (wr << 4) + (lq << 2) + r;
            y[row][e] = acc[nf][r] + bv + ws[ATT_OFF + (size_t)(bs0 + row) * EE + e];
        }
    }
    __syncthreads();
    int e0 = lane * 2;
    for (int rr = 0; rr < 8; rr++) {
        int row = wave * 8 + rr;
        float z0 = y[row][e0], z1 = y[row][e0 + 1];
        float mean = wave_sum(z0 + z1) * (1.f / 128.f);
        float d0 = z0 - mean, d1 = z1 - mean;
        float var = wave_sum(d0 * d0 + d1 * d1) * (1.f / 128.f);
        float inv = rsqrtf(var + 1e-5f);
        y[row][e0]     = d0 * inv * g2[e0] + bb2[e0];
        y[row][e0 + 1] = d1 * inv * g2[e0 + 1] + bb2[e0 + 1];
    }
    __syncthreads();
    int b = bs0 >> 10, s0 = bs0 & 1023;
    int sl = t & 31, eg = t >> 5;
    #pragma unroll
    for (int rep = 0; rep < 16; rep++) {
        int e = eg * 16 + rep;
        out[(size_t)b * EE * SS + (size_t)e * SS + s0 + sl] = y[sl][e];
    }
}

extern "C" void kernel_launch(void* const* d_in, const int* in_sizes, int n_in,
                              void* d_out, int out_size, void* d_ws, size_t ws_size,
                              hipStream_t stream) {
    const float* x        = (const float*)d_in[0];
    const float* conv1_w  = (const float*)d_in[1];
    const float* conv1_b  = (const float*)d_in[2];
    const float* bn1_g    = (const float*)d_in[3];
    const float* bn1_b    = (const float*)d_in[4];
    const float* bn1_m    = (const float*)d_in[5];
    const float* bn1_v    = (const float*)d_in[6];
    const float* conv2_w  = (const float*)d_in[7];
    const float* conv2_b  = (const float*)d_in[8];
    const float* bn2_g    = (const float*)d_in[9];
    const float* bn2_b    = (const float*)d_in[10];
    const float* bn2_m    = (const float*)d_in[11];
    const float* bn2_v    = (const float*)d_in[12];
    const float* wq       = (const float*)d_in[13];
    const float* wk       = (const float*)d_in[14];
    const float* wv       = (const float*)d_in[15];
    const float* rel_tab  = (const float*)d_in[16];
    const float* ln_attn_g = (const float*)d_in[17];
    const float* ln_attn_b = (const float*)d_in[18];
    const float* ln1_g    = (const float*)d_in[19];
    const float* ln1_b    = (const float*)d_in[20];
    const float* ln2_g    = (const float*)d_in[21];
    const float* ln2_b    = (const float*)d_in[22];
    const float* ff_w1    = (const float*)d_in[23];
    const float* ff_b1    = (const float*)d_in[24];
    const float* ff_w2    = (const float*)d_in[25];
    const float* ff_b2    = (const float*)d_in[26];

    float* ws  = (float*)d_ws;
    float* out = (float*)d_out;
    unsigned short* wqkv_bf = (unsigned short*)(ws + WQKV_BF_OFF);

    hipLaunchKernelGGL(k0_pe, dim3(512), dim3(256), 0, stream, ws);
    hipLaunchKernelGGL(k0_bn, dim3(1), dim3(640), 0, stream,
                       conv1_b, bn1_g, bn1_b, bn1_m, bn1_v,
                       conv2_b, bn2_g, bn2_b, bn2_m, bn2_v, ws);
    hipLaunchKernelGGL(k0_castw, dim3(512), dim3(256), 0, stream,
                       conv2_w, (unsigned short*)(ws + W2CONV_BF_OFF), 8192);
    hipLaunchKernelGGL(k0_castw, dim3(8), dim3(256), 0, stream, wq, wqkv_bf, 128);
    hipLaunchKernelGGL(k0_castw, dim3(8), dim3(256), 0, stream, wk, wqkv_bf + 16384, 128);
    hipLaunchKernelGGL(k0_castw, dim3(8), dim3(256), 0, stream, wv, wqkv_bf + 32768, 128);
    hipLaunchKernelGGL(k0_castw, dim3(32), dim3(256), 0, stream,
                       ff_w1, (unsigned short*)(ws + W1FF_BF_OFF), 128);
    hipLaunchKernelGGL(k0_castw, dim3(32), dim3(256), 0, stream,
                       ff_w2, (unsigned short*)(ws + W2FF_BF_OFF), 512);
    hipLaunchKernelGGL(k1_mfma, dim3(512), dim3(256), 0, stream, x, conv1_w, ws);
    hipLaunchKernelGGL(k2_mfma, dim3(256, 3), dim3(256), 0, stream, ws);
    hipLaunchKernelGGL(k3a_flash, dim3(BB * HH, SS / 64), dim3(256), 0, stream, ws);
    hipLaunchKernelGGL(k3b_bias, dim3(HH, SS / 64), dim3(256), 0, stream, rel_tab, ws);
    hipLaunchKernelGGL(k4_ln, dim3(BB * SS / 4), dim3(256), 0, stream, ln_attn_g, ln_attn_b, ln1_g, ln1_b, ws);
    hipLaunchKernelGGL(k5_mfma, dim3(256, 4), dim3(256), 0, stream, ff_b1, ws);
    hipLaunchKernelGGL(k6_mfma, dim3(256), dim3(256), 0, stream, ff_b2, ln2_g, ln2_b, ws, out);
}

// Round 7
// 186.100 us; speedup vs baseline: 7.0391x; 1.3427x over previous
//
#include <hip/hip_runtime.h>
#include <math.h>

// Problem constants
#define BB    8
#define CIN   16
#define SS    1024
#define EE    128
#define HH    8
#define DHH   16
#define O1    512      // E*4
#define DFFN  512
#define K2TOT 8192     // O1*CIN

// Workspace layout (float offsets)
#define PE_OFF    0            // 131072  (S*E)
#define BN1SC_OFF 131072       // 512 (unused now; kept)
#define BN1SH_OFF 131584       // 512
#define BN2SC_OFF 132096       // 128
#define BN2SH_OFF 132224       // 128
#define W1P_OFF   133120       // bf16 folded conv1 taps [512 o][8 u] = 4096 us (2048 floats)
#define WQKV_BF_OFF 135168     // bf16 wq|wk|wv, each 16384 elems
#define W1FF_BF_OFF 159744     // bf16 ff_w1 [4nb][2kb][128][64]
#define W2FF_BF_OFF 192512     // bf16 ff_w2 [8kb][128][64]
#define XSRC_OFF  262144       // 1048576 (B*S*E) fp32
#define Q_OFF     1310720      // QH: f16[B*H*S*16] scaled
#define KK_OFF    2359296      // KH: f16[B*H*S*16]
#define V_OFF     3407872      // VHT: f16[B*H*16*S]
#define ATTN_OFF  4456448      // 1048576 (B,S,E)
#define ATT_OFF   5505024      // 1048576 (B,S,E) post-LN1
#define FFH_OFF   6553600      // 2M floats region: k1 partials P0|P1 (2x1M f32) then k5 bf16 out
#define W2CONV_BF_OFF 8650752  // bf16 conv2_w [128kb][128e][64]
// end: 9175040 floats = 36.7 MB

typedef __attribute__((ext_vector_type(8))) short short8;
typedef __attribute__((ext_vector_type(8))) unsigned short ushort8;
typedef __attribute__((ext_vector_type(4))) unsigned short us4;
typedef __attribute__((ext_vector_type(4))) float f32x4;
typedef _Float16 f16_t;
typedef __attribute__((ext_vector_type(4))) _Float16 half4;
typedef __attribute__((ext_vector_type(8))) _Float16 half8;

__device__ __forceinline__ float wave_sum(float v) {
    #pragma unroll
    for (int o = 32; o > 0; o >>= 1) v += __shfl_xor(v, o);
    return v;
}

__device__ __forceinline__ float gelu_exact(float x) {
    return 0.5f * x * (1.0f + erff(x * 0.7071067811865476f));
}

// x - x/(1+exp(2*inner)), constants pre-doubled: 8 VALU ops
__device__ __forceinline__ float gelu_tanh(float x) {
    float x2 = x * x;
    float y = x * fmaf(0.0713548162f, x2, 1.5957691216f);
    float E = __expf(y);
    float r = __builtin_amdgcn_rcpf(E + 1.0f);
    return fmaf(-x, r, x);
}

__device__ __forceinline__ unsigned short f2bf(float f) {   // RNE fp32->bf16
    unsigned int u = __float_as_uint(f);
    unsigned int r = u + 0x7FFFu + ((u >> 16) & 1u);
    return (unsigned short)(r >> 16);
}

__device__ __forceinline__ float bf2f(unsigned short u) {
    return __uint_as_float(((unsigned int)u) << 16);
}

// generic weight cast fp32 -> bf16, chunk-major, pre-swizzled (m173 pattern)
__device__ __forceinline__ void castw_body(const float* __restrict__ src,
                                           unsigned short* __restrict__ dst, int K, int tid) {
    int g = tid & 7, e = (tid >> 3) & 127, rest = tid >> 10;
    int KB = K >> 6;
    int kb = rest % KB, nb = rest / KB;
    int col = nb * 128 + e;
    const float* s = src + (size_t)col * K + kb * 64 + ((g ^ (e & 7)) << 3);
    ushort8 v;
    #pragma unroll
    for (int j = 0; j < 8; j++) v[j] = f2bf(s[j]);
    *(ushort8*)&dst[(size_t)tid << 3] = v;
}

// ---------------- K0: ALL setup jobs fused (independent; branch on blockIdx) ----------------
__global__ __launch_bounds__(256) void k0_all(const float* __restrict__ conv1_w,
                                              const float* __restrict__ conv1_b,
                                              const float* __restrict__ bn1_g,
                                              const float* __restrict__ bn1_b,
                                              const float* __restrict__ bn1_m,
                                              const float* __restrict__ bn1_v,
                                              const float* __restrict__ conv2_w,
                                              const float* __restrict__ conv2_b,
                                              const float* __restrict__ bn2_g,
                                              const float* __restrict__ bn2_b,
                                              const float* __restrict__ bn2_m,
                                              const float* __restrict__ bn2_v,
                                              const float* __restrict__ wq,
                                              const float* __restrict__ wk,
                                              const float* __restrict__ wv,
                                              const float* __restrict__ ff_w1,
                                              const float* __restrict__ ff_w2,
                                              float* __restrict__ ws) {
    int bid = blockIdx.x, t = threadIdx.x;
    if (bid < 512) {                       // PE table
        int idx = bid * 256 + t;
        int s = idx >> 7, e = idx & 127;
        int i = e >> 1;
        float freq = expf((float)(2 * i) * (-9.210340371976184f / 128.0f));
        float ang = (float)s * freq * 0.125f;
        ws[PE_OFF + idx] = (e & 1) ? cosf(ang) : sinf(ang);
    } else if (bid < 515) {                // BN fold
        int u = (bid - 512) * 256 + t;
        if (u < 512) {
            float sc = bn1_g[u] * rsqrtf(bn1_v[u] + 1e-5f);
            ws[BN1SC_OFF + u] = sc;
            ws[BN1SH_OFF + u] = (conv1_b[u] - bn1_m[u]) * sc + bn1_b[u];
        } else if (u < 640) {
            int e = u - 512;
            float sc = bn2_g[e] * rsqrtf(bn2_v[e] + 1e-5f);
            ws[BN2SC_OFF + e] = sc;
            ws[BN2SH_OFF + e] = (conv2_b[e] - bn2_m[e]) * sc + bn2_b[e];
        }
    } else if (bid < 1027) {               // conv2_w cast (512 blocks)
        castw_body(conv2_w, (unsigned short*)(ws + W2CONV_BF_OFF), 8192, (bid - 515) * 256 + t);
    } else if (bid < 1035) {
        castw_body(wq, (unsigned short*)(ws + WQKV_BF_OFF), 128, (bid - 1027) * 256 + t);
    } else if (bid < 1043) {
        castw_body(wk, (unsigned short*)(ws + WQKV_BF_OFF) + 16384, 128, (bid - 1035) * 256 + t);
    } else if (bid < 1051) {
        castw_body(wv, (unsigned short*)(ws + WQKV_BF_OFF) + 32768, 128, (bid - 1043) * 256 + t);
    } else if (bid < 1083) {
        castw_body(ff_w1, (unsigned short*)(ws + W1FF_BF_OFF), 128, (bid - 1051) * 256 + t);
    } else if (bid < 1115) {
        castw_body(ff_w2, (unsigned short*)(ws + W2FF_BF_OFF), 512, (bid - 1083) * 256 + t);
    } else {                               // folded bf16 conv1 taps: w1p[o][u] = w1[o][u]*sc1[o]
        unsigned short* w1p = (unsigned short*)(ws + W1P_OFF);
        for (int id = t; id < 4096; id += 256) {
            int o = id >> 3, u = id & 7;
            float sc = bn1_g[o] * rsqrtf(bn1_v[o] + 1e-5f);
            float v = (u < 7) ? conv1_w[o * 7 + u] * sc : 0.f;
            w1p[id] = f2bf(v);
        }
    }
}

// ---------------- K1: fused conv1+bn1+gelu -> conv2 (bf16 MFMA), K-split x2 -> partials ------
// grid (512, 2): BM=16 rows, K-half per block (64 chunks). LDS 43.5KB -> 3 blocks/CU.
__global__ __launch_bounds__(256) void k1_mfma(const float* __restrict__ x,
                                               float* __restrict__ ws) {
    __shared__ float xt[CIN][24];                 // 1.5KB
    __shared__ unsigned short w1ps[256 * 8];      // 4KB (this K-half's 256 o-rows)
    __shared__ float sh1s[256];                   // 1KB
    __shared__ unsigned short Ab[2][16 * 64];     // 4KB
    __shared__ unsigned short Bbuf[2][128 * 64];  // 32KB

    const int t = threadIdx.x;
    const int wave = t >> 6, lane = t & 63;
    const int row0 = blockIdx.x * 16;
    const int ks = blockIdx.y;                    // K-split half
    const int b = row0 >> 10, s0 = row0 & 1023;
    const int obase = ks * 256;

    for (int i = t; i < CIN * 22; i += 256) {
        int c = i / 22, j = i % 22;
        int gs = s0 + j - 3;
        xt[c][j] = (gs >= 0 && gs < SS) ? x[(b * CIN + c) * SS + gs] : 0.f;
    }
    {
        const ushort8* w1pg = (const ushort8*)((const unsigned short*)(ws + W1P_OFF)) + obase;
        for (int i = t; i < 256; i += 256) *(ushort8*)&w1ps[i << 3] = w1pg[i];
        for (int i = t; i < 256; i += 256) sh1s[i] = ws[BN1SH_OFF + obase + i];
    }

    const char* w2g = (const char*)(ws + W2CONV_BF_OFF);

    auto stageB = [&](int kbl, int buf) {
        const char* g = w2g + ((size_t)(ks * 64 + kbl) << 14);
        #pragma unroll
        for (int c4 = 0; c4 < 4; ++c4) {
            int off = c4 * 4096 + wave * 1024;
            __builtin_amdgcn_global_load_lds(
                (const __attribute__((address_space(1))) unsigned int*)(g + off + lane * 16),
                (__attribute__((address_space(3))) unsigned int*)(&Bbuf[buf][off >> 1]),
                16, 0, 0);
        }
    };

    stageB(0, 0);
    __syncthreads();                              // xt/w1ps ready; B[0] drained

    // loop-invariant hoists
    const int c_ = lane & 15;
    float xv[10];
    #pragma unroll
    for (int j = 0; j < 10; j++) xv[j] = xt[c_][(wave << 2) + j];
    int wbase[4];
    #pragma unroll
    for (int i = 0; i < 4; i++) {
        int ss = (wave << 2) + i;
        wbase[i] = (ss << 6) + ((((lane >> 3) ^ (ss & 7))) << 3) + (lane & 7);
    }
    unsigned short* abf = &Ab[0][0];

    auto computeH1 = [&](int kbl, int buf) {
        int ol = (kbl << 2) + (lane >> 4);        // 0..255
        ushort8 wv8 = *(const ushort8*)&w1ps[ol << 3];
        float w0 = bf2f(wv8[0]), w1_ = bf2f(wv8[1]), w2_ = bf2f(wv8[2]), w3 = bf2f(wv8[3]);
        float w4 = bf2f(wv8[4]), w5 = bf2f(wv8[5]), w6 = bf2f(wv8[6]);
        float sh = sh1s[ol];
        int boff = buf << 10;
        #pragma unroll
        for (int i = 0; i < 4; i++) {
            float p = xv[i]   * w0 + xv[i+1] * w1_ + xv[i+2] * w2_ + xv[i+3] * w3
                    + xv[i+4] * w4 + xv[i+5] * w5 + xv[i+6] * w6;
            abf[boff + wbase[i]] = f2bf(gelu_tanh(p + sh));
        }
    };

    const int lrow = lane & 15, lq = lane >> 4;
    f32x4 acc[2];
    acc[0] = (f32x4){0.f, 0.f, 0.f, 0.f};
    acc[1] = (f32x4){0.f, 0.f, 0.f, 0.f};

    auto mfmaPhase = [&](int buf) {
        #pragma unroll
        for (int ksname = 0; ksname < 2; ++ksname) {
            int G = (ksname << 2) + lq;
            short8 a = *(const short8*)&Ab[buf][(lrow << 6) + ((G ^ (lrow & 7)) << 3)];
            #pragma unroll
            for (int nf = 0; nf < 2; ++nf) {
                int e = (wave << 5) + (nf << 4) + lrow;
                short8 bf = *(const short8*)&Bbuf[buf][(e << 6) + ((G ^ (e & 7)) << 3)];
                acc[nf] = __builtin_amdgcn_mfma_f32_16x16x32_bf16(a, bf, acc[nf], 0, 0, 0);
            }
        }
    };

    computeH1(0, 0);
    __syncthreads();
    for (int kbl = 0; kbl < 64; ++kbl) {
        int cur = kbl & 1;
        if (kbl < 63) stageB(kbl + 1, cur ^ 1);
        mfmaPhase(cur);
        if (kbl < 63) computeH1(kbl + 1, cur ^ 1);
        __syncthreads();
    }

    // store fp32 partial (no bn2/gelu yet)
    float* P = ws + FFH_OFF + (size_t)ks * 1048576;
    #pragma unroll
    for (int nf = 0; nf < 2; ++nf) {
        int e = (wave << 5) + (nf << 4) + lrow;
        #pragma unroll
        for (int r = 0; r < 4; ++r) {
            int srow = s0 + (lq << 2) + r;
            P[(((size_t)(b * SS + srow)) << 7) + e] = acc[nf][r];
        }
    }
}

// ---------------- K1b: combine partials + bn2 + exact gelu -> x_src ----------------
__global__ __launch_bounds__(256) void k1b_combine(float* __restrict__ ws) {
    int f = (blockIdx.x * 256 + threadIdx.x) * 4;   // 1M elems
    int e0 = f & 127;
    float4 p0 = *(const float4*)&ws[FFH_OFF + f];
    float4 p1 = *(const float4*)&ws[FFH_OFF + 1048576 + f];
    float4 sc = *(const float4*)&ws[BN2SC_OFF + e0];
    float4 sh = *(const float4*)&ws[BN2SH_OFF + e0];
    float4 o;
    o.x = gelu_exact(fmaf(p0.x + p1.x, sc.x, sh.x));
    o.y = gelu_exact(fmaf(p0.y + p1.y, sc.y, sh.y));
    o.z = gelu_exact(fmaf(p0.z + p1.z, sc.z, sh.z));
    o.w = gelu_exact(fmaf(p0.w + p1.w, sc.w, sh.w));
    *(float4*)&ws[XSRC_OFF + f] = o;
}

// ---------------- K2: QKV projection via MFMA -> f16 QH(scaled)/KH/VHT (vector stores) ------
__global__ __launch_bounds__(256) void k2_mfma(float* __restrict__ ws) {
    __shared__ unsigned short As[32 * 128];       // 8KB
    __shared__ unsigned short Bs[128 * 128];      // 32KB
    __shared__ float ys[32][132];                 // 16.9KB
    const int t = threadIdx.x;
    const int rt = blockIdx.x, mat = blockIdx.y;
    const int wave = t >> 6, lane = t & 63;

    const char* bg = (const char*)((const unsigned short*)(ws + WQKV_BF_OFF) + mat * 16384);
    #pragma unroll
    for (int c8 = 0; c8 < 8; ++c8) {
        int off = c8 * 4096 + wave * 1024;
        __builtin_amdgcn_global_load_lds(
            (const __attribute__((address_space(1))) unsigned int*)(bg + off + lane * 16),
            (__attribute__((address_space(3))) unsigned int*)(&Bs[off >> 1]), 16, 0, 0);
    }
    const int bs0 = rt * 32;
    const int sl0 = bs0 & 1023;
    for (int i = t; i < 1024; i += 256) {
        int row = i >> 5, d0 = (i & 31) << 2;
        float4 xvv = *(const float4*)&ws[XSRC_OFF + (size_t)(bs0 + row) * EE + d0];
        float4 pv = *(const float4*)&ws[PE_OFF + (size_t)(sl0 + row) * EE + d0];
        us4 o;
        o[0] = f2bf(xvv.x + pv.x); o[1] = f2bf(xvv.y + pv.y);
        o[2] = f2bf(xvv.z + pv.z); o[3] = f2bf(xvv.w + pv.w);
        int slot = (d0 >> 3) ^ (row & 7);
        *(us4*)&As[(row << 7) + (slot << 3) + (d0 & 7)] = o;
    }
    __syncthreads();

    const int wr = wave >> 1, wc = wave & 1;
    const int lrow = lane & 15, lq = lane >> 4;
    f32x4 acc[4];
    #pragma unroll
    for (int i = 0; i < 4; i++) acc[i] = (f32x4){0.f, 0.f, 0.f, 0.f};

    #pragma unroll
    for (int ksname = 0; ksname < 4; ++ksname) {
        int G = (ksname << 2) + lq;
        int arow = (wr << 4) + lrow;
        short8 a = *(const short8*)&As[(arow << 7) + ((G ^ (arow & 7)) << 3)];
        #pragma unroll
        for (int nf = 0; nf < 4; ++nf) {
            int e = (wc << 6) + (nf << 4) + lrow;
            short8 bf = *(const short8*)&Bs[((G >> 3) << 13) + (e << 6) + (((G & 7) ^ (e & 7)) << 3)];
            acc[nf] = __builtin_amdgcn_mfma_f32_16x16x32_bf16(a, bf, acc[nf], 0, 0, 0);
        }
    }

    // C-frag -> LDS (fp32) for vectorized transposed stores
    #pragma unroll
    for (int nf = 0; nf < 4; ++nf) {
        int e = (wc << 6) + (nf << 4) + lrow;
        #pragma unroll
        for (int r = 0; r < 4; ++r)
            ys[(wr << 4) + (lq << 2) + r][e] = acc[nf][r];
    }
    __syncthreads();

    const int b = bs0 >> 10;
    if (mat <= 1) {
        // thread: row=t>>3 (0..31), h=t&7 -> 16 consecutive d2 -> 2 half8 stores
        int row = t >> 3, h8 = t & 7;
        float scl = (mat == 0) ? 0.08838834764831845f : 1.0f;
        f16_t* dst = (f16_t*)(ws + (mat == 0 ? Q_OFF : KK_OFF))
                   + (((size_t)(b * HH + h8)) * SS + (sl0 + row)) * DHH;
        half8 v0, v1;
        #pragma unroll
        for (int d = 0; d < 8; d++) v0[d] = (f16_t)(ys[row][h8 * 16 + d] * scl);
        #pragma unroll
        for (int d = 0; d < 8; d++) v1[d] = (f16_t)(ys[row][h8 * 16 + 8 + d] * scl);
        *(half8*)&dst[0] = v0;
        *(half8*)&dst[8] = v1;
    } else {
        // thread: col c=t&127, sl-half=t>>7 -> 16 consecutive sl -> 2 half8 stores
        int c = t & 127, hf = t >> 7;
        int h8 = c >> 4, d2 = c & 15;
        f16_t* dst = (f16_t*)(ws + V_OFF)
                   + (((size_t)(b * HH + h8)) * DHH + d2) * SS + sl0 + hf * 16;
        half8 v0, v1;
        #pragma unroll
        for (int r = 0; r < 8; r++) v0[r] = (f16_t)ys[hf * 16 + r][c];
        #pragma unroll
        for (int r = 0; r < 8; r++) v1[r] = (f16_t)ys[hf * 16 + 8 + r][c];
        *(half8*)&dst[0] = v0;
        *(half8*)&dst[8] = v1;
    }
}

// ---------------- K3: flash softmax attention + fused rel-bias (mfma 16x16x16 f16) ----------
// out_i = (sum_j p_ij v_j)/l_i + sum_j tbl[i-j+1023] v_j ; bias MFMA reuses the loaded V-frag.
__global__ __launch_bounds__(256) void k3_attn(const float* __restrict__ rel_tab,
                                               float* __restrict__ ws) {
    __shared__ f16_t rtbl4[4][1088];              // 4 shifted copies for aligned b64 reads
    const int bh = blockIdx.x;                    // b*H + h
    const int h = bh & 7, b = bh >> 3;
    const int i0b = blockIdx.y * 64;
    const int t = threadIdx.x;
    for (int id = t; id < 4 * 1088; id += 256) {
        int p = id >> 10;                         // 1088 = not pow2; use div
        p = id / 1088; int j = id - p * 1088;
        int u = j + p;
        float v = (u < 1087) ? rel_tab[(i0b + 1086 - u) * HH + h] : 0.f;
        rtbl4[p][j] = (f16_t)v;
    }
    __syncthreads();

    const int w = t >> 6, lane = t & 63;
    const int q = lane & 15, g = lane >> 4;
    const int r = w * 16 + q;
    const int i = i0b + r;

    const f16_t* QH  = (const f16_t*)(ws + Q_OFF)  + (size_t)bh * SS * DHH;
    const f16_t* KH  = (const f16_t*)(ws + KK_OFF) + (size_t)bh * SS * DHH;
    const f16_t* VHT = (const f16_t*)(ws + V_OFF)  + (size_t)bh * DHH * SS;

    half4 qf = *(const half4*)&QH[(size_t)i * DHH + 4 * g];
    f32x4 o = {0.f, 0.f, 0.f, 0.f};
    f32x4 bv = {0.f, 0.f, 0.f, 0.f};
    const f32x4 zf = {0.f, 0.f, 0.f, 0.f};
    float lp = 0.f;
    const int p4 = (63 - r + 4 * g) & 3;          // vb mod 4, lane-constant

    #pragma unroll 4
    for (int jt = 0; jt < 64; ++jt) {
        half4 kf = *(const half4*)&KH[(size_t)(jt * 16 + q) * DHH + 4 * g];
        f32x4 s = __builtin_amdgcn_mfma_f32_16x16x16f16(kf, qf, zf, 0, 0, 0);
        float p0 = __expf(s[0]), p1 = __expf(s[1]), p2 = __expf(s[2]), p3 = __expf(s[3]);
        lp += (p0 + p1) + (p2 + p3);
        half4 pf;
        pf[0] = (f16_t)p0; pf[1] = (f16_t)p1; pf[2] = (f16_t)p2; pf[3] = (f16_t)p3;
        half4 vf = *(const half4*)&VHT[(size_t)q * SS + jt * 16 + 4 * g];
        o = __builtin_amdgcn_mfma_f32_16x16x16f16(vf, pf, o, 0, 0, 0);
        int vb = 63 - r + jt * 16 + 4 * g;
        half4 bfrag = *(const half4*)&rtbl4[p4][vb & ~3];
        bv = __builtin_amdgcn_mfma_f32_16x16x16f16(vf, bfrag, bv, 0, 0, 0);
    }
    lp += __shfl_xor(lp, 16);
    lp += __shfl_xor(lp, 32);
    float inv = 1.f / lp;
    float4 ov = make_float4(fmaf(o[0], inv, bv[0]), fmaf(o[1], inv, bv[1]),
                            fmaf(o[2], inv, bv[2]), fmaf(o[3], inv, bv[3]));
    *(float4*)&ws[ATTN_OFF + ((size_t)(b * SS) + i) * EE + h * DHH + 4 * g] = ov;
}

// ---------------- K4: LN(attn) -> +x_src -> LN1 -> att ----------------
__global__ __launch_bounds__(256) void k4_ln(const float* __restrict__ g_attn, const float* __restrict__ b_attn,
                                             const float* __restrict__ g1, const float* __restrict__ b1,
                                             float* __restrict__ ws) {
    int row = blockIdx.x * 4 + (threadIdx.x >> 6);
    int lane = threadIdx.x & 63;
    int e0 = lane * 2;
    const float* ain = ws + ATTN_OFF + (size_t)row * EE;
    const float* xsr = ws + XSRC_OFF + (size_t)row * EE;
    float2 a = *(const float2*)(ain + e0);
    float mean = wave_sum(a.x + a.y) * (1.f / 128.f);
    float dx = a.x - mean, dy = a.y - mean;
    float var = wave_sum(dx * dx + dy * dy) * (1.f / 128.f);
    float inv = rsqrtf(var + 1e-5f);
    float n0 = dx * inv * g_attn[e0] + b_attn[e0];
    float n1 = dy * inv * g_attn[e0 + 1] + b_attn[e0 + 1];
    float2 xs2 = *(const float2*)(xsr + e0);
    float z0 = xs2.x + n0, z1 = xs2.y + n1;
    float m2 = wave_sum(z0 + z1) * (1.f / 128.f);
    float d0 = z0 - m2, d1 = z1 - m2;
    float v2 = wave_sum(d0 * d0 + d1 * d1) * (1.f / 128.f);
    float inv2 = rsqrtf(v2 + 1e-5f);
    float o0 = d0 * inv2 * g1[e0] + b1[e0];
    float o1 = d1 * inv2 * g1[e0 + 1] + b1[e0 + 1];
    *(float2*)(ws + ATT_OFF + (size_t)row * EE + e0) = make_float2(o0, o1);
}

// ---------------- K5: FF1 via MFMA + bias + relu -> bf16 swizzled FFHB (vector stores) ------
__global__ __launch_bounds__(256) void k5_mfma(const float* __restrict__ b1,
                                               float* __restrict__ ws) {
    __shared__ unsigned short As[32 * 128];
    __shared__ unsigned short Bs[128 * 128];
    __shared__ float ys[32][132];
    const int t = threadIdx.x;
    const int rt = blockIdx.x, nb = blockIdx.y;
    const int wave = t >> 6, lane = t & 63;

    const char* bg = (const char*)((const unsigned short*)(ws + W1FF_BF_OFF) + nb * 16384);
    #pragma unroll
    for (int c8 = 0; c8 < 8; ++c8) {
        int off = c8 * 4096 + wave * 1024;
        __builtin_amdgcn_global_load_lds(
            (const __attribute__((address_space(1))) unsigned int*)(bg + off + lane * 16),
            (__attribute__((address_space(3))) unsigned int*)(&Bs[off >> 1]), 16, 0, 0);
    }
    const int bs0 = rt * 32;
    for (int i = t; i < 1024; i += 256) {
        int row = i >> 5, d0 = (i & 31) << 2;
        float4 xvv = *(const float4*)&ws[ATT_OFF + (size_t)(bs0 + row) * EE + d0];
        us4 o;
        o[0] = f2bf(xvv.x); o[1] = f2bf(xvv.y); o[2] = f2bf(xvv.z); o[3] = f2bf(xvv.w);
        int slot = (d0 >> 3) ^ (row & 7);
        *(us4*)&As[(row << 7) + (slot << 3) + (d0 & 7)] = o;
    }
    __syncthreads();

    const int wr = wave >> 1, wc = wave & 1;
    const int lrow = lane & 15, lq = lane >> 4;
    f32x4 acc[4];
    #pragma unroll
    for (int i = 0; i < 4; i++) acc[i] = (f32x4){0.f, 0.f, 0.f, 0.f};

    #pragma unroll
    for (int ksname = 0; ksname < 4; ++ksname) {
        int G = (ksname << 2) + lq;
        int arow = (wr << 4) + lrow;
        short8 a = *(const short8*)&As[(arow << 7) + ((G ^ (arow & 7)) << 3)];
        #pragma unroll
        for (int nf = 0; nf < 4; ++nf) {
            int e = (wc << 6) + (nf << 4) + lrow;
            short8 bf = *(const short8*)&Bs[((G >> 3) << 13) + (e << 6) + (((G & 7) ^ (e & 7)) << 3)];
            acc[nf] = __builtin_amdgcn_mfma_f32_16x16x32_bf16(a, bf, acc[nf], 0, 0, 0);
        }
    }

    // bias+relu at ys-write
    #pragma unroll
    for (int nf = 0; nf < 4; ++nf) {
        int col = (wc << 6) + (nf << 4) + lrow;
        float bias = b1[(nb << 7) + col];
        #pragma unroll
        for (int r = 0; r < 4; ++r)
            ys[(wr << 4) + (lq << 2) + r][col] = fmaxf(acc[nf][r] + bias, 0.f);
    }
    __syncthreads();

    // packed swizzled stores: 2 tasks/thread, each one ushort8
    unsigned short* ffhb = (unsigned short*)(ws + FFH_OFF);
    #pragma unroll
    for (int kk = 0; kk < 2; ++kk) {
        int id = t + kk * 256;
        int ssr = id >> 4, fg = id & 15;
        float4 v0 = *(const float4*)&ys[ssr][fg * 8];
        float4 v1 = *(const float4*)&ys[ssr][fg * 8 + 4];
        ushort8 ov;
        ov[0] = f2bf(v0.x); ov[1] = f2bf(v0.y); ov[2] = f2bf(v0.z); ov[3] = f2bf(v0.w);
        ov[4] = f2bf(v1.x); ov[5] = f2bf(v1.y); ov[6] = f2bf(v1.z); ov[7] = f2bf(v1.w);
        int kb = (nb << 1) + (fg >> 3);
        int slot = (fg & 7) ^ (ssr & 7);
        *(ushort8*)&ffhb[(((size_t)(rt * 8 + kb) * 32 + ssr) << 6) + (slot << 3)] = ov;
    }
}

// ---------------- K6: FF2 via MFMA + bias + residual + LN2 + transposed store ----------------
__global__ __launch_bounds__(256) void k6_mfma(const float* __restrict__ b2,
                                               const float* __restrict__ g2, const float* __restrict__ bb2,
                                               float* __restrict__ ws, float* __restrict__ out) {
    __shared__ unsigned short Ab[2][2048];    // 2x4KB
    __shared__ unsigned short Bb[2][8192];    // 2x16KB
    __shared__ float y[32][132];              // 16.9KB
    const int t = threadIdx.x;
    const int wave = t >> 6, lane = t & 63;
    const int rt = blockIdx.x;

    const char* ag = (const char*)((const unsigned short*)(ws + FFH_OFF) + (size_t)rt * 16384);
    const char* bgc = (const char*)(ws + W2FF_BF_OFF);

    auto stage = [&](int kb, int buf) {
        __builtin_amdgcn_global_load_lds(
            (const __attribute__((address_space(1))) unsigned int*)(ag + kb * 4096 + t * 16),
            (__attribute__((address_space(3))) unsigned int*)(&Ab[buf][(t * 16) >> 1]), 16, 0, 0);
        const char* g = bgc + kb * 16384;
        #pragma unroll
        for (int c4 = 0; c4 < 4; ++c4) {
            int off = c4 * 4096 + wave * 1024;
            __builtin_amdgcn_global_load_lds(
                (const __attribute__((address_space(1))) unsigned int*)(g + off + lane * 16),
                (__attribute__((address_space(3))) unsigned int*)(&Bb[buf][off >> 1]), 16, 0, 0);
        }
    };

    const int wr = wave >> 1, wc = wave & 1;
    const int lrow = lane & 15, lq = lane >> 4;
    f32x4 acc[4];
    #pragma unroll
    for (int i = 0; i < 4; i++) acc[i] = (f32x4){0.f, 0.f, 0.f, 0.f};

    stage(0, 0);
    __syncthreads();
    for (int kb = 0; kb < 8; ++kb) {
        int cur = kb & 1;
        if (kb < 7) stage(kb + 1, cur ^ 1);
        #pragma unroll
        for (int ksname = 0; ksname < 2; ++ksname) {
            int G = (ksname << 2) + lq;
            int arow = (wr << 4) + lrow;
            short8 a = *(const short8*)&Ab[cur][(arow << 6) + ((G ^ (arow & 7)) << 3)];
            #pragma unroll
            for (int nf = 0; nf < 4; ++nf) {
                int e = (wc << 6) + (nf << 4) + lrow;
                short8 bf = *(const short8*)&Bb[cur][(e << 6) + ((G ^ (e & 7)) << 3)];
                acc[nf] = __builtin_amdgcn_mfma_f32_16x16x32_bf16(a, bf, acc[nf], 0, 0, 0);
            }
        }
        __syncthreads();
    }

    const int bs0 = rt * 32;
    #pragma unroll
    for (int nf = 0; nf < 4; ++nf) {
        int e = (wc << 6) + (nf << 4) + lrow;
        float bvv = b2[e];
        #pragma unroll
        for (int r = 0; r < 4; ++r) {
            int row = (wr << 4) + (lq << 2) + r;
            y[row][e] = acc[nf][r] + bvv + ws[ATT_OFF + (size_t)(bs0 + row) * EE + e];
        }
    }
    __syncthreads();
    int e0 = lane * 2;
    for (int rr = 0; rr < 8; rr++) {
        int row = wave * 8 + rr;
        float z0 = y[row][e0], z1 = y[row][e0 + 1];
        float mean = wave_sum(z0 + z1) * (1.f / 128.f);
        float d0 = z0 - mean, d1 = z1 - mean;
        float var = wave_sum(d0 * d0 + d1 * d1) * (1.f / 128.f);
        float inv = rsqrtf(var + 1e-5f);
        y[row][e0]     = d0 * inv * g2[e0] + bb2[e0];
        y[row][e0 + 1] = d1 * inv * g2[e0 + 1] + bb2[e0 + 1];
    }
    __syncthreads();
    int b = bs0 >> 10, s0 = bs0 & 1023;
    int sl = t & 31, eg = t >> 5;
    #pragma unroll
    for (int rep = 0; rep < 16; rep++) {
        int e = eg * 16 + rep;
        out[(size_t)b * EE * SS + (size_t)e * SS + s0 + sl] = y[sl][e];
    }
}

extern "C" void kernel_launch(void* const* d_in, const int* in_sizes, int n_in,
                              void* d_out, int out_size, void* d_ws, size_t ws_size,
                              hipStream_t stream) {
    const float* x        = (const float*)d_in[0];
    const float* conv1_w  = (const float*)d_in[1];
    const float* conv1_b  = (const float*)d_in[2];
    const float* bn1_g    = (const float*)d_in[3];
    const float* bn1_b    = (const float*)d_in[4];
    const float* bn1_m    = (const float*)d_in[5];
    const float* bn1_v    = (const float*)d_in[6];
    const float* conv2_w  = (const float*)d_in[7];
    const float* conv2_b  = (const float*)d_in[8];
    const float* bn2_g    = (const float*)d_in[9];
    const float* bn2_b    = (const float*)d_in[10];
    const float* bn2_m    = (const float*)d_in[11];
    const float* bn2_v    = (const float*)d_in[12];
    const float* wq       = (const float*)d_in[13];
    const float* wk       = (const float*)d_in[14];
    const float* wv       = (const float*)d_in[15];
    const float* rel_tab  = (const float*)d_in[16];
    const float* ln_attn_g = (const float*)d_in[17];
    const float* ln_attn_b = (const float*)d_in[18];
    const float* ln1_g    = (const float*)d_in[19];
    const float* ln1_b    = (const float*)d_in[20];
    const float* ln2_g    = (const float*)d_in[21];
    const float* ln2_b    = (const float*)d_in[22];
    const float* ff_w1    = (const float*)d_in[23];
    const float* ff_b1    = (const float*)d_in[24];
    const float* ff_w2    = (const float*)d_in[25];
    const float* ff_b2    = (const float*)d_in[26];

    float* ws  = (float*)d_ws;
    float* out = (float*)d_out;

    hipLaunchKernelGGL(k0_all, dim3(1116), dim3(256), 0, stream,
                       conv1_w, conv1_b, bn1_g, bn1_b, bn1_m, bn1_v,
                       conv2_w, conv2_b, bn2_g, bn2_b, bn2_m, bn2_v,
                       wq, wk, wv, ff_w1, ff_w2, ws);
    hipLaunchKernelGGL(k1_mfma, dim3(512, 2), dim3(256), 0, stream, x, ws);
    hipLaunchKernelGGL(k1b_combine, dim3(1024), dim3(256), 0, stream, ws);
    hipLaunchKernelGGL(k2_mfma, dim3(256, 3), dim3(256), 0, stream, ws);
    hipLaunchKernelGGL(k3_attn, dim3(BB * HH, SS / 64), dim3(256), 0, stream, rel_tab, ws);
    hipLaunchKernelGGL(k4_ln, dim3(BB * SS / 4), dim3(256), 0, stream, ln_attn_g, ln_attn_b, ln1_g, ln1_b, ws);
    hipLaunchKernelGGL(k5_mfma, dim3(256, 4), dim3(256), 0, stream, ff_b1, ws);
    hipLaunchKernelGGL(k6_mfma, dim3(256), dim3(256), 0, stream, ff_b2, ln2_g, ln2_b, ws, out);
}

// Round 8
// 167.971 us; speedup vs baseline: 7.7988x; 1.1079x over previous
//
#include <hip/hip_runtime.h>
#include <math.h>

// Problem constants
#define BB    8
#define CIN   16
#define SS    1024
#define EE    128
#define HH    8
#define DHH   16
#define O1    512      // E*4
#define DFFN  512
#define K2TOT 8192     // O1*CIN

// Workspace layout (float offsets)
#define PE_OFF    0            // 131072  (S*E)
#define BN1SC_OFF 131072       // 512 (unused now; kept)
#define BN1SH_OFF 131584       // 512
#define BN2SC_OFF 132096       // 128
#define BN2SH_OFF 132224       // 128
#define W1P_OFF   133120       // bf16 folded conv1 taps [512 o][8 u]
#define WQKV_BF_OFF 135168     // bf16 wq|wk|wv, each 16384 elems
#define W1FF_BF_OFF 159744     // bf16 ff_w1 [4nb][2kb][128][64]
#define W2FF_BF_OFF 192512     // bf16 ff_w2 [8kb][128][64]
#define XSRC_OFF  262144       // 1048576 (B*S*E) fp32
#define Q_OFF     1310720      // QH: f16[B*H*S*16] scaled
#define KK_OFF    2359296      // KH: f16[B*H*S*16]
#define V_OFF     3407872      // VHT: f16[B*H*16*S]
#define ATTN_OFF  4456448      // 1048576 (B,S,E)
#define ATT_OFF   5505024      // 1048576 (B,S,E) post-LN1
#define FFH_OFF   6553600      // 2M floats region: k1 partials P0|P1 (2x1M f32) then k5 bf16 out
#define W2CONV_BF_OFF 8650752  // bf16 conv2_w [128kb][128e][64]
// end: 9175040 floats = 36.7 MB

typedef __attribute__((ext_vector_type(8))) short short8;
typedef __attribute__((ext_vector_type(8))) unsigned short ushort8;
typedef __attribute__((ext_vector_type(4))) unsigned short us4;
typedef __attribute__((ext_vector_type(4))) float f32x4;
typedef _Float16 f16_t;
typedef __attribute__((ext_vector_type(4))) _Float16 half4;
typedef __attribute__((ext_vector_type(8))) _Float16 half8;

__device__ __forceinline__ float wave_sum(float v) {
    #pragma unroll
    for (int o = 32; o > 0; o >>= 1) v += __shfl_xor(v, o);
    return v;
}

__device__ __forceinline__ float gelu_exact(float x) {
    return 0.5f * x * (1.0f + erff(x * 0.7071067811865476f));
}

// x - x/(1+exp(2*inner)), constants pre-doubled
__device__ __forceinline__ float gelu_tanh(float x) {
    float x2 = x * x;
    float y = x * fmaf(0.0713548162f, x2, 1.5957691216f);
    float E = __expf(y);
    float r = __builtin_amdgcn_rcpf(E + 1.0f);
    return fmaf(-x, r, x);
}

__device__ __forceinline__ unsigned short f2bf(float f) {   // RNE fp32->bf16
    unsigned int u = __float_as_uint(f);
    unsigned int r = u + 0x7FFFu + ((u >> 16) & 1u);
    return (unsigned short)(r >> 16);
}

__device__ __forceinline__ float bf2f(unsigned short u) {
    return __uint_as_float(((unsigned int)u) << 16);
}

// generic weight cast fp32 -> bf16, chunk-major, pre-swizzled (m173 pattern)
__device__ __forceinline__ void castw_body(const float* __restrict__ src,
                                           unsigned short* __restrict__ dst, int K, int tid) {
    int g = tid & 7, e = (tid >> 3) & 127, rest = tid >> 10;
    int KB = K >> 6;
    int kb = rest % KB, nb = rest / KB;
    int col = nb * 128 + e;
    const float* s = src + (size_t)col * K + kb * 64 + ((g ^ (e & 7)) << 3);
    ushort8 v;
    #pragma unroll
    for (int j = 0; j < 8; j++) v[j] = f2bf(s[j]);
    *(ushort8*)&dst[(size_t)tid << 3] = v;
}

// ---------------- K0: ALL setup jobs fused (independent; branch on blockIdx) ----------------
__global__ __launch_bounds__(256) void k0_all(const float* __restrict__ conv1_w,
                                              const float* __restrict__ conv1_b,
                                              const float* __restrict__ bn1_g,
                                              const float* __restrict__ bn1_b,
                                              const float* __restrict__ bn1_m,
                                              const float* __restrict__ bn1_v,
                                              const float* __restrict__ conv2_w,
                                              const float* __restrict__ conv2_b,
                                              const float* __restrict__ bn2_g,
                                              const float* __restrict__ bn2_b,
                                              const float* __restrict__ bn2_m,
                                              const float* __restrict__ bn2_v,
                                              const float* __restrict__ wq,
                                              const float* __restrict__ wk,
                                              const float* __restrict__ wv,
                                              const float* __restrict__ ff_w1,
                                              const float* __restrict__ ff_w2,
                                              float* __restrict__ ws) {
    int bid = blockIdx.x, t = threadIdx.x;
    if (bid < 512) {                       // PE table
        int idx = bid * 256 + t;
        int s = idx >> 7, e = idx & 127;
        int i = e >> 1;
        float freq = expf((float)(2 * i) * (-9.210340371976184f / 128.0f));
        float ang = (float)s * freq * 0.125f;
        ws[PE_OFF + idx] = (e & 1) ? cosf(ang) : sinf(ang);
    } else if (bid < 515) {                // BN fold
        int u = (bid - 512) * 256 + t;
        if (u < 512) {
            float sc = bn1_g[u] * rsqrtf(bn1_v[u] + 1e-5f);
            ws[BN1SC_OFF + u] = sc;
            ws[BN1SH_OFF + u] = (conv1_b[u] - bn1_m[u]) * sc + bn1_b[u];
        } else if (u < 640) {
            int e = u - 512;
            float sc = bn2_g[e] * rsqrtf(bn2_v[e] + 1e-5f);
            ws[BN2SC_OFF + e] = sc;
            ws[BN2SH_OFF + e] = (conv2_b[e] - bn2_m[e]) * sc + bn2_b[e];
        }
    } else if (bid < 1027) {               // conv2_w cast (512 blocks)
        castw_body(conv2_w, (unsigned short*)(ws + W2CONV_BF_OFF), 8192, (bid - 515) * 256 + t);
    } else if (bid < 1035) {
        castw_body(wq, (unsigned short*)(ws + WQKV_BF_OFF), 128, (bid - 1027) * 256 + t);
    } else if (bid < 1043) {
        castw_body(wk, (unsigned short*)(ws + WQKV_BF_OFF) + 16384, 128, (bid - 1035) * 256 + t);
    } else if (bid < 1051) {
        castw_body(wv, (unsigned short*)(ws + WQKV_BF_OFF) + 32768, 128, (bid - 1043) * 256 + t);
    } else if (bid < 1083) {
        castw_body(ff_w1, (unsigned short*)(ws + W1FF_BF_OFF), 128, (bid - 1051) * 256 + t);
    } else if (bid < 1115) {
        castw_body(ff_w2, (unsigned short*)(ws + W2FF_BF_OFF), 512, (bid - 1083) * 256 + t);
    } else {                               // folded bf16 conv1 taps: w1p[o][u] = w1[o][u]*sc1[o]
        unsigned short* w1p = (unsigned short*)(ws + W1P_OFF);
        for (int id = t; id < 4096; id += 256) {
            int o = id >> 3, u = id & 7;
            float sc = bn1_g[o] * rsqrtf(bn1_v[o] + 1e-5f);
            float v = (u < 7) ? conv1_w[o * 7 + u] * sc : 0.f;
            w1p[id] = f2bf(v);
        }
    }
}

// ---------------- K1: fused conv1+bn1+gelu -> conv2 (bf16 MFMA), K-split x2 -> partials ------
// BM=32, grid (256, 2). B (w2) streamed GLOBAL->REGISTERS (no global_load_lds, no B in LDS):
// the per-chunk barrier only orders the 8KB A dbuf, and reg deps let loads pipeline.
// 2x-unrolled chunk pairs with named reg sets bA/bB (static indexing).
__global__ __launch_bounds__(256, 3) void k1_mfma(const float* __restrict__ x,
                                                  float* __restrict__ ws) {
    __shared__ float xt[CIN][40];                 // 2.5KB: x[b,c, s0-3 .. s0+34]
    __shared__ unsigned short w1ps[256 * 8];      // 4KB (this K-half's 256 o-rows)
    __shared__ float sh1s[256];                   // 1KB
    __shared__ unsigned short Ab[2][32 * 64];     // 2x4KB A dbuf

    const int t = threadIdx.x;
    const int wave = t >> 6, lane = t & 63;
    const int row0 = blockIdx.x * 32;
    const int ksplit = blockIdx.y;                // K-split half
    const int b = row0 >> 10, s0 = row0 & 1023;
    const int obase = ksplit * 256;

    for (int i = t; i < CIN * 38; i += 256) {
        int c = i / 38, j = i % 38;
        int gs = s0 + j - 3;
        xt[c][j] = (gs >= 0 && gs < SS) ? x[(b * CIN + c) * SS + gs] : 0.f;
    }
    {
        const ushort8* w1pg = (const ushort8*)((const unsigned short*)(ws + W1P_OFF)) + obase;
        if (t < 256) *(ushort8*)&w1ps[t << 3] = w1pg[t];
        if (t < 256) sh1s[t] = ws[BN1SH_OFF + obase + t];
    }
    __syncthreads();                              // xt/w1ps ready

    const char* w2g = (const char*)(ws + W2CONV_BF_OFF);
    const int wr = wave >> 1, wc = wave & 1;
    const int lrow = lane & 15, lq = lane >> 4;

    // lane-constant B byte offsets within a chunk (8 frags: ks2*4+nf)
    int boff[8];
    #pragma unroll
    for (int ks2 = 0; ks2 < 2; ++ks2) {
        int G = (ks2 << 2) + lq;
        #pragma unroll
        for (int nf = 0; nf < 4; ++nf) {
            int e = (wc << 6) + (nf << 4) + lrow;
            boff[ks2 * 4 + nf] = (e << 7) + ((G ^ (e & 7)) << 4);
        }
    }

    auto loadB = [&](int kbl, short8 (&dst)[8]) {
        const char* g = w2g + ((size_t)(ksplit * 64 + kbl) << 14);
        #pragma unroll
        for (int i = 0; i < 8; ++i)
            dst[i] = *(const short8*)(g + boff[i]);
    };

    // kb-invariant hoists for computeH1 (thread: k=lane, rows wave*8..+8)
    const int c_ = lane & 15;
    float xv[14];
    #pragma unroll
    for (int j = 0; j < 14; j++) xv[j] = xt[c_][(wave << 3) + j];
    int wbase[8];
    #pragma unroll
    for (int i = 0; i < 8; i++) {
        int ss = (wave << 3) + i;
        wbase[i] = (ss << 6) + ((((lane >> 3) ^ (ss & 7))) << 3) + (lane & 7);
    }

    auto computeH1 = [&](int kbl, int buf) {
        int ol = (kbl << 2) + (lane >> 4);        // 0..255
        ushort8 wv8 = *(const ushort8*)&w1ps[ol << 3];
        float w0 = bf2f(wv8[0]), w1_ = bf2f(wv8[1]), w2_ = bf2f(wv8[2]), w3 = bf2f(wv8[3]);
        float w4 = bf2f(wv8[4]), w5 = bf2f(wv8[5]), w6 = bf2f(wv8[6]);
        float sh = sh1s[ol];
        unsigned short* abf = &Ab[buf][0];
        #pragma unroll
        for (int i = 0; i < 8; i++) {
            float p = xv[i]   * w0 + xv[i+1] * w1_ + xv[i+2] * w2_ + xv[i+3] * w3
                    + xv[i+4] * w4 + xv[i+5] * w5 + xv[i+6] * w6;
            abf[wbase[i]] = f2bf(gelu_tanh(p + sh));
        }
    };

    f32x4 acc[4];
    #pragma unroll
    for (int i = 0; i < 4; i++) acc[i] = (f32x4){0.f, 0.f, 0.f, 0.f};

    auto mfmaPhase = [&](short8 (&bb)[8], int buf) {
        #pragma unroll
        for (int ks2 = 0; ks2 < 2; ++ks2) {
            int G = (ks2 << 2) + lq;
            int arow = (wr << 4) + lrow;
            short8 a = *(const short8*)&Ab[buf][(arow << 6) + ((G ^ (arow & 7)) << 3)];
            #pragma unroll
            for (int nf = 0; nf < 4; ++nf)
                acc[nf] = __builtin_amdgcn_mfma_f32_16x16x32_bf16(a, bb[ks2 * 4 + nf], acc[nf], 0, 0, 0);
        }
    };

    short8 bA[8], bB[8];
    loadB(0, bA);
    computeH1(0, 0);
    __syncthreads();                              // A[0] ready
    for (int kb2 = 0; kb2 < 64; kb2 += 2) {
        loadB(kb2 + 1, bB);                       // regs; pipelines under MFMA+VALU
        mfmaPhase(bA, 0);
        computeH1(kb2 + 1, 1);
        __syncthreads();
        if (kb2 + 2 < 64) loadB(kb2 + 2, bA);
        mfmaPhase(bB, 1);
        if (kb2 + 2 < 64) {
            computeH1(kb2 + 2, 0);
            __syncthreads();
        }
    }

    // store fp32 partial (no bn2/gelu yet)
    float* P = ws + FFH_OFF + (size_t)ksplit * 1048576;
    #pragma unroll
    for (int nf = 0; nf < 4; ++nf) {
        int e = (wc << 6) + (nf << 4) + lrow;
        #pragma unroll
        for (int r = 0; r < 4; ++r) {
            int srow = s0 + (wr << 4) + (lq << 2) + r;
            P[(((size_t)(b * SS + srow)) << 7) + e] = acc[nf][r];
        }
    }
}

// ---------------- K1b: combine partials + bn2 + exact gelu -> x_src ----------------
__global__ __launch_bounds__(256) void k1b_combine(float* __restrict__ ws) {
    int f = (blockIdx.x * 256 + threadIdx.x) * 4;   // 1M elems
    int e0 = f & 127;
    float4 p0 = *(const float4*)&ws[FFH_OFF + f];
    float4 p1 = *(const float4*)&ws[FFH_OFF + 1048576 + f];
    float4 sc = *(const float4*)&ws[BN2SC_OFF + e0];
    float4 sh = *(const float4*)&ws[BN2SH_OFF + e0];
    float4 o;
    o.x = gelu_exact(fmaf(p0.x + p1.x, sc.x, sh.x));
    o.y = gelu_exact(fmaf(p0.y + p1.y, sc.y, sh.y));
    o.z = gelu_exact(fmaf(p0.z + p1.z, sc.z, sh.z));
    o.w = gelu_exact(fmaf(p0.w + p1.w, sc.w, sh.w));
    *(float4*)&ws[XSRC_OFF + f] = o;
}

// ---------------- K2: QKV projection via MFMA -> f16 QH(scaled)/KH/VHT (vector stores) ------
__global__ __launch_bounds__(256) void k2_mfma(float* __restrict__ ws) {
    __shared__ unsigned short As[32 * 128];       // 8KB
    __shared__ unsigned short Bs[128 * 128];      // 32KB
    __shared__ float ys[32][132];                 // 16.9KB
    const int t = threadIdx.x;
    const int rt = blockIdx.x, mat = blockIdx.y;
    const int wave = t >> 6, lane = t & 63;

    const char* bg = (const char*)((const unsigned short*)(ws + WQKV_BF_OFF) + mat * 16384);
    #pragma unroll
    for (int c8 = 0; c8 < 8; ++c8) {
        int off = c8 * 4096 + wave * 1024;
        __builtin_amdgcn_global_load_lds(
            (const __attribute__((address_space(1))) unsigned int*)(bg + off + lane * 16),
            (__attribute__((address_space(3))) unsigned int*)(&Bs[off >> 1]), 16, 0, 0);
    }
    const int bs0 = rt * 32;
    const int sl0 = bs0 & 1023;
    for (int i = t; i < 1024; i += 256) {
        int row = i >> 5, d0 = (i & 31) << 2;
        float4 xvv = *(const float4*)&ws[XSRC_OFF + (size_t)(bs0 + row) * EE + d0];
        float4 pv = *(const float4*)&ws[PE_OFF + (size_t)(sl0 + row) * EE + d0];
        us4 o;
        o[0] = f2bf(xvv.x + pv.x); o[1] = f2bf(xvv.y + pv.y);
        o[2] = f2bf(xvv.z + pv.z); o[3] = f2bf(xvv.w + pv.w);
        int slot = (d0 >> 3) ^ (row & 7);
        *(us4*)&As[(row << 7) + (slot << 3) + (d0 & 7)] = o;
    }
    __syncthreads();

    const int wr = wave >> 1, wc = wave & 1;
    const int lrow = lane & 15, lq = lane >> 4;
    f32x4 acc[4];
    #pragma unroll
    for (int i = 0; i < 4; i++) acc[i] = (f32x4){0.f, 0.f, 0.f, 0.f};

    #pragma unroll
    for (int ksname = 0; ksname < 4; ++ksname) {
        int G = (ksname << 2) + lq;
        int arow = (wr << 4) + lrow;
        short8 a = *(const short8*)&As[(arow << 7) + ((G ^ (arow & 7)) << 3)];
        #pragma unroll
        for (int nf = 0; nf < 4; ++nf) {
            int e = (wc << 6) + (nf << 4) + lrow;
            short8 bf = *(const short8*)&Bs[((G >> 3) << 13) + (e << 6) + (((G & 7) ^ (e & 7)) << 3)];
            acc[nf] = __builtin_amdgcn_mfma_f32_16x16x32_bf16(a, bf, acc[nf], 0, 0, 0);
        }
    }

    // C-frag -> LDS (fp32) for vectorized transposed stores
    #pragma unroll
    for (int nf = 0; nf < 4; ++nf) {
        int e = (wc << 6) + (nf << 4) + lrow;
        #pragma unroll
        for (int r = 0; r < 4; ++r)
            ys[(wr << 4) + (lq << 2) + r][e] = acc[nf][r];
    }
    __syncthreads();

    const int b = bs0 >> 10;
    if (mat <= 1) {
        int row = t >> 3, h8 = t & 7;
        float scl = (mat == 0) ? 0.08838834764831845f : 1.0f;
        f16_t* dst = (f16_t*)(ws + (mat == 0 ? Q_OFF : KK_OFF))
                   + (((size_t)(b * HH + h8)) * SS + (sl0 + row)) * DHH;
        half8 v0, v1;
        #pragma unroll
        for (int d = 0; d < 8; d++) v0[d] = (f16_t)(ys[row][h8 * 16 + d] * scl);
        #pragma unroll
        for (int d = 0; d < 8; d++) v1[d] = (f16_t)(ys[row][h8 * 16 + 8 + d] * scl);
        *(half8*)&dst[0] = v0;
        *(half8*)&dst[8] = v1;
    } else {
        int c = t & 127, hf = t >> 7;
        int h8 = c >> 4, d2 = c & 15;
        f16_t* dst = (f16_t*)(ws + V_OFF)
                   + (((size_t)(b * HH + h8)) * DHH + d2) * SS + sl0 + hf * 16;
        half8 v0, v1;
        #pragma unroll
        for (int r = 0; r < 8; r++) v0[r] = (f16_t)ys[hf * 16 + r][c];
        #pragma unroll
        for (int r = 0; r < 8; r++) v1[r] = (f16_t)ys[hf * 16 + 8 + r][c];
        *(half8*)&dst[0] = v0;
        *(half8*)&dst[8] = v1;
    }
}

// ---------------- K3: flash softmax attention + fused rel-bias (mfma 16x16x16 f16) ----------
__global__ __launch_bounds__(256) void k3_attn(const float* __restrict__ rel_tab,
                                               float* __restrict__ ws) {
    __shared__ f16_t rtbl4[4][1088];              // 4 shifted copies for aligned b64 reads
    const int bh = blockIdx.x;                    // b*H + h
    const int h = bh & 7, b = bh >> 3;
    const int i0b = blockIdx.y * 64;
    const int t = threadIdx.x;
    for (int id = t; id < 4 * 1088; id += 256) {
        int p = id / 1088; int j = id - p * 1088;
        int u = j + p;
        float v = (u < 1087) ? rel_tab[(i0b + 1086 - u) * HH + h] : 0.f;
        rtbl4[p][j] = (f16_t)v;
    }
    __syncthreads();

    const int w = t >> 6, lane = t & 63;
    const int q = lane & 15, g = lane >> 4;
    const int r = w * 16 + q;
    const int i = i0b + r;

    const f16_t* QH  = (const f16_t*)(ws + Q_OFF)  + (size_t)bh * SS * DHH;
    const f16_t* KH  = (const f16_t*)(ws + KK_OFF) + (size_t)bh * SS * DHH;
    const f16_t* VHT = (const f16_t*)(ws + V_OFF)  + (size_t)bh * DHH * SS;

    half4 qf = *(const half4*)&QH[(size_t)i * DHH + 4 * g];
    f32x4 o = {0.f, 0.f, 0.f, 0.f};
    f32x4 bv = {0.f, 0.f, 0.f, 0.f};
    const f32x4 zf = {0.f, 0.f, 0.f, 0.f};
    float lp = 0.f;
    const int p4 = (63 - r + 4 * g) & 3;          // vb mod 4, lane-constant

    #pragma unroll 4
    for (int jt = 0; jt < 64; ++jt) {
        half4 kf = *(const half4*)&KH[(size_t)(jt * 16 + q) * DHH + 4 * g];
        f32x4 s = __builtin_amdgcn_mfma_f32_16x16x16f16(kf, qf, zf, 0, 0, 0);
        float p0 = __expf(s[0]), p1 = __expf(s[1]), p2 = __expf(s[2]), p3 = __expf(s[3]);
        lp += (p0 + p1) + (p2 + p3);
        half4 pf;
        pf[0] = (f16_t)p0; pf[1] = (f16_t)p1; pf[2] = (f16_t)p2; pf[3] = (f16_t)p3;
        half4 vf = *(const half4*)&VHT[(size_t)q * SS + jt * 16 + 4 * g];
        o = __builtin_amdgcn_mfma_f32_16x16x16f16(vf, pf, o, 0, 0, 0);
        int vb = 63 - r + jt * 16 + 4 * g;
        half4 bfrag = *(const half4*)&rtbl4[p4][vb & ~3];
        bv = __builtin_amdgcn_mfma_f32_16x16x16f16(vf, bfrag, bv, 0, 0, 0);
    }
    lp += __shfl_xor(lp, 16);
    lp += __shfl_xor(lp, 32);
    float inv = 1.f / lp;
    float4 ov = make_float4(fmaf(o[0], inv, bv[0]), fmaf(o[1], inv, bv[1]),
                            fmaf(o[2], inv, bv[2]), fmaf(o[3], inv, bv[3]));
    *(float4*)&ws[ATTN_OFF + ((size_t)(b * SS) + i) * EE + h * DHH + 4 * g] = ov;
}

// ---------------- K4: LN(attn) -> +x_src -> LN1 -> att ----------------
__global__ __launch_bounds__(256) void k4_ln(const float* __restrict__ g_attn, const float* __restrict__ b_attn,
                                             const float* __restrict__ g1, const float* __restrict__ b1,
                                             float* __restrict__ ws) {
    int row = blockIdx.x * 4 + (threadIdx.x >> 6);
    int lane = threadIdx.x & 63;
    int e0 = lane * 2;
    const float* ain = ws + ATTN_OFF + (size_t)row * EE;
    const float* xsr = ws + XSRC_OFF + (size_t)row * EE;
    float2 a = *(const float2*)(ain + e0);
    float mean = wave_sum(a.x + a.y) * (1.f / 128.f);
    float dx = a.x - mean, dy = a.y - mean;
    float var = wave_sum(dx * dx + dy * dy) * (1.f / 128.f);
    float inv = rsqrtf(var + 1e-5f);
    float n0 = dx * inv * g_attn[e0] + b_attn[e0];
    float n1 = dy * inv * g_attn[e0 + 1] + b_attn[e0 + 1];
    float2 xs2 = *(const float2*)(xsr + e0);
    float z0 = xs2.x + n0, z1 = xs2.y + n1;
    float m2 = wave_sum(z0 + z1) * (1.f / 128.f);
    float d0 = z0 - m2, d1 = z1 - m2;
    float v2 = wave_sum(d0 * d0 + d1 * d1) * (1.f / 128.f);
    float inv2 = rsqrtf(v2 + 1e-5f);
    float o0 = d0 * inv2 * g1[e0] + b1[e0];
    float o1 = d1 * inv2 * g1[e0 + 1] + b1[e0 + 1];
    *(float2*)(ws + ATT_OFF + (size_t)row * EE + e0) = make_float2(o0, o1);
}

// ---------------- K5: FF1 via MFMA + bias + relu -> bf16 swizzled FFHB (vector stores) ------
__global__ __launch_bounds__(256) void k5_mfma(const float* __restrict__ b1,
                                               float* __restrict__ ws) {
    __shared__ unsigned short As[32 * 128];
    __shared__ unsigned short Bs[128 * 128];
    __shared__ float ys[32][132];
    const int t = threadIdx.x;
    const int rt = blockIdx.x, nb = blockIdx.y;
    const int wave = t >> 6, lane = t & 63;

    const char* bg = (const char*)((const unsigned short*)(ws + W1FF_BF_OFF) + nb * 16384);
    #pragma unroll
    for (int c8 = 0; c8 < 8; ++c8) {
        int off = c8 * 4096 + wave * 1024;
        __builtin_amdgcn_global_load_lds(
            (const __attribute__((address_space(1))) unsigned int*)(bg + off + lane * 16),
            (__attribute__((address_space(3))) unsigned int*)(&Bs[off >> 1]), 16, 0, 0);
    }
    const int bs0 = rt * 32;
    for (int i = t; i < 1024; i += 256) {
        int row = i >> 5, d0 = (i & 31) << 2;
        float4 xvv = *(const float4*)&ws[ATT_OFF + (size_t)(bs0 + row) * EE + d0];
        us4 o;
        o[0] = f2bf(xvv.x); o[1] = f2bf(xvv.y); o[2] = f2bf(xvv.z); o[3] = f2bf(xvv.w);
        int slot = (d0 >> 3) ^ (row & 7);
        *(us4*)&As[(row << 7) + (slot << 3) + (d0 & 7)] = o;
    }
    __syncthreads();

    const int wr = wave >> 1, wc = wave & 1;
    const int lrow = lane & 15, lq = lane >> 4;
    f32x4 acc[4];
    #pragma unroll
    for (int i = 0; i < 4; i++) acc[i] = (f32x4){0.f, 0.f, 0.f, 0.f};

    #pragma unroll
    for (int ksname = 0; ksname < 4; ++ksname) {
        int G = (ksname << 2) + lq;
        int arow = (wr << 4) + lrow;
        short8 a = *(const short8*)&As[(arow << 7) + ((G ^ (arow & 7)) << 3)];
        #pragma unroll
        for (int nf = 0; nf < 4; ++nf) {
            int e = (wc << 6) + (nf << 4) + lrow;
            short8 bf = *(const short8*)&Bs[((G >> 3) << 13) + (e << 6) + (((G & 7) ^ (e & 7)) << 3)];
            acc[nf] = __builtin_amdgcn_mfma_f32_16x16x32_bf16(a, bf, acc[nf], 0, 0, 0);
        }
    }

    #pragma unroll
    for (int nf = 0; nf < 4; ++nf) {
        int col = (wc << 6) + (nf << 4) + lrow;
        float bias = b1[(nb << 7) + col];
        #pragma unroll
        for (int r = 0; r < 4; ++r)
            ys[(wr << 4) + (lq << 2) + r][col] = fmaxf(acc[nf][r] + bias, 0.f);
    }
    __syncthreads();

    unsigned short* ffhb = (unsigned short*)(ws + FFH_OFF);
    #pragma unroll
    for (int kk = 0; kk < 2; ++kk) {
        int id = t + kk * 256;
        int ssr = id >> 4, fg = id & 15;
        float4 v0 = *(const float4*)&ys[ssr][fg * 8];
        float4 v1 = *(const float4*)&ys[ssr][fg * 8 + 4];
        ushort8 ov;
        ov[0] = f2bf(v0.x); ov[1] = f2bf(v0.y); ov[2] = f2bf(v0.z); ov[3] = f2bf(v0.w);
        ov[4] = f2bf(v1.x); ov[5] = f2bf(v1.y); ov[6] = f2bf(v1.z); ov[7] = f2bf(v1.w);
        int kb = (nb << 1) + (fg >> 3);
        int slot = (fg & 7) ^ (ssr & 7);
        *(ushort8*)&ffhb[(((size_t)(rt * 8 + kb) * 32 + ssr) << 6) + (slot << 3)] = ov;
    }
}

// ---------------- K6: FF2 via MFMA + bias + residual + LN2 + transposed store ----------------
__global__ __launch_bounds__(256) void k6_mfma(const float* __restrict__ b2,
                                               const float* __restrict__ g2, const float* __restrict__ bb2,
                                               float* __restrict__ ws, float* __restrict__ out) {
    __shared__ unsigned short Ab[2][2048];    // 2x4KB
    __shared__ unsigned short Bb[2][8192];    // 2x16KB
    __shared__ float y[32][132];              // 16.9KB
    const int t = threadIdx.x;
    const int wave = t >> 6, lane = t & 63;
    const int rt = blockIdx.x;

    const char* ag = (const char*)((const unsigned short*)(ws + FFH_OFF) + (size_t)rt * 16384);
    const char* bgc = (const char*)(ws + W2FF_BF_OFF);

    auto stage = [&](int kb, int buf) {
        __builtin_amdgcn_global_load_lds(
            (const __attribute__((address_space(1))) unsigned int*)(ag + kb * 4096 + t * 16),
            (__attribute__((address_space(3))) unsigned int*)(&Ab[buf][(t * 16) >> 1]), 16, 0, 0);
        const char* g = bgc + kb * 16384;
        #pragma unroll
        for (int c4 = 0; c4 < 4; ++c4) {
            int off = c4 * 4096 + wave * 1024;
            __builtin_amdgcn_global_load_lds(
                (const __attribute__((address_space(1))) unsigned int*)(g + off + lane * 16),
                (__attribute__((address_space(3))) unsigned int*)(&Bb[buf][off >> 1]), 16, 0, 0);
        }
    };

    const int wr = wave >> 1, wc = wave & 1;
    const int lrow = lane & 15, lq = lane >> 4;
    f32x4 acc[4];
    #pragma unroll
    for (int i = 0; i < 4; i++) acc[i] = (f32x4){0.f, 0.f, 0.f, 0.f};

    stage(0, 0);
    __syncthreads();
    for (int kb = 0; kb < 8; ++kb) {
        int cur = kb & 1;
        if (kb < 7) stage(kb + 1, cur ^ 1);
        #pragma unroll
        for (int ksname = 0; ksname < 2; ++ksname) {
            int G = (ksname << 2) + lq;
            int arow = (wr << 4) + lrow;
            short8 a = *(const short8*)&Ab[cur][(arow << 6) + ((G ^ (arow & 7)) << 3)];
            #pragma unroll
            for (int nf = 0; nf < 4; ++nf) {
                int e = (wc << 6) + (nf << 4) + lrow;
                short8 bf = *(const short8*)&Bb[cur][(e << 6) + ((G ^ (e & 7)) << 3)];
                acc[nf] = __builtin_amdgcn_mfma_f32_16x16x32_bf16(a, bf, acc[nf], 0, 0, 0);
            }
        }
        __syncthreads();
    }

    const int bs0 = rt * 32;
    #pragma unroll
    for (int nf = 0; nf < 4; ++nf) {
        int e = (wc << 6) + (nf << 4) + lrow;
        float bvv = b2[e];
        #pragma unroll
        for (int r = 0; r < 4; ++r) {
            int row = (wr << 4) + (lq << 2) + r;
            y[row][e] = acc[nf][r] + bvv + ws[ATT_OFF + (size_t)(bs0 + row) * EE + e];
        }
    }
    __syncthreads();
    int e0 = lane * 2;
    for (int rr = 0; rr < 8; rr++) {
        int row = wave * 8 + rr;
        float z0 = y[row][e0], z1 = y[row][e0 + 1];
        float mean = wave_sum(z0 + z1) * (1.f / 128.f);
        float d0 = z0 - mean, d1 = z1 - mean;
        float var = wave_sum(d0 * d0 + d1 * d1) * (1.f / 128.f);
        float inv = rsqrtf(var + 1e-5f);
        y[row][e0]     = d0 * inv * g2[e0] + bb2[e0];
        y[row][e0 + 1] = d1 * inv * g2[e0 + 1] + bb2[e0 + 1];
    }
    __syncthreads();
    int b = bs0 >> 10, s0 = bs0 & 1023;
    int sl = t & 31, eg = t >> 5;
    #pragma unroll
    for (int rep = 0; rep < 16; rep++) {
        int e = eg * 16 + rep;
        out[(size_t)b * EE * SS + (size_t)e * SS + s0 + sl] = y[sl][e];
    }
}

extern "C" void kernel_launch(void* const* d_in, const int* in_sizes, int n_in,
                              void* d_out, int out_size, void* d_ws, size_t ws_size,
                              hipStream_t stream) {
    const float* x        = (const float*)d_in[0];
    const float* conv1_w  = (const float*)d_in[1];
    const float* conv1_b  = (const float*)d_in[2];
    const float* bn1_g    = (const float*)d_in[3];
    const float* bn1_b    = (const float*)d_in[4];
    const float* bn1_m    = (const float*)d_in[5];
    const float* bn1_v    = (const float*)d_in[6];
    const float* conv2_w  = (const float*)d_in[7];
    const float* conv2_b  = (const float*)d_in[8];
    const float* bn2_g    = (const float*)d_in[9];
    const float* bn2_b    = (const float*)d_in[10];
    const float* bn2_m    = (const float*)d_in[11];
    const float* bn2_v    = (const float*)d_in[12];
    const float* wq       = (const float*)d_in[13];
    const float* wk       = (const float*)d_in[14];
    const float* wv       = (const float*)d_in[15];
    const float* rel_tab  = (const float*)d_in[16];
    const float* ln_attn_g = (const float*)d_in[17];
    const float* ln_attn_b = (const float*)d_in[18];
    const float* ln1_g    = (const float*)d_in[19];
    const float* ln1_b    = (const float*)d_in[20];
    const float* ln2_g    = (const float*)d_in[21];
    const float* ln2_b    = (const float*)d_in[22];
    const float* ff_w1    = (const float*)d_in[23];
    const float* ff_b1    = (const float*)d_in[24];
    const float* ff_w2    = (const float*)d_in[25];
    const float* ff_b2    = (const float*)d_in[26];

    float* ws  = (float*)d_ws;
    float* out = (float*)d_out;

    hipLaunchKernelGGL(k0_all, dim3(1116), dim3(256), 0, stream,
                       conv1_w, conv1_b, bn1_g, bn1_b, bn1_m, bn1_v,
                       conv2_w, conv2_b, bn2_g, bn2_b, bn2_m, bn2_v,
                       wq, wk, wv, ff_w1, ff_w2, ws);
    hipLaunchKernelGGL(k1_mfma, dim3(256, 2), dim3(256), 0, stream, x, ws);
    hipLaunchKernelGGL(k1b_combine, dim3(1024), dim3(256), 0, stream, ws);
    hipLaunchKernelGGL(k2_mfma, dim3(256, 3), dim3(256), 0, stream, ws);
    hipLaunchKernelGGL(k3_attn, dim3(BB * HH, SS / 64), dim3(256), 0, stream, rel_tab, ws);
    hipLaunchKernelGGL(k4_ln, dim3(BB * SS / 4), dim3(256), 0, stream, ln_attn_g, ln_attn_b, ln1_g, ln1_b, ws);
    hipLaunchKernelGGL(k5_mfma, dim3(256, 4), dim3(256), 0, stream, ff_b1, ws);
    hipLaunchKernelGGL(k6_mfma, dim3(256), dim3(256), 0, stream, ff_b2, ln2_g, ln2_b, ws, out);
}

// Round 9
// 157.084 us; speedup vs baseline: 8.3393x; 1.0693x over previous
//
#include <hip/hip_runtime.h>
#include <math.h>

// Problem constants
#define BB    8
#define CIN   16
#define SS    1024
#define EE    128
#define HH    8
#define DHH   16
#define O1    512      // E*4
#define DFFN  512
#define K2TOT 8192     // O1*CIN

// Workspace layout (float offsets)
#define PE_OFF    0            // 131072  (S*E)
#define BN1SC_OFF 131072       // 512 (unused now; kept)
#define BN1SH_OFF 131584       // 512
#define BN2SC_OFF 132096       // 128
#define BN2SH_OFF 132224       // 128
#define W1P_OFF   133120       // bf16 folded conv1 taps [512 o][8 u]
#define WQKV_BF_OFF 135168     // bf16 wq|wk|wv, each 16384 elems
#define W1FF_BF_OFF 159744     // bf16 ff_w1 [4nb][2kb][128][64]
#define W2FF_BF_OFF 192512     // bf16 ff_w2 [8kb][128][64]
#define XSRC_OFF  262144       // 1048576 (B*S*E) fp32
#define Q_OFF     1310720      // QH: f16[B*H*S*16] scaled | k1 partial P0 (fp32, 1M)
#define KK_OFF    2359296      // KH                        | k1 partial P1
#define V_OFF     3407872      // VHT                       | k1 partial P2
#define ATTN_OFF  4456448      // (B,S,E) attn out          | k1 partial P3
#define ATT_OFF   5505024      // 1048576 (B,S,E) post-LN1
#define FFH_OFF   6553600      // k5 bf16 out (2M floats region)
#define W2CONV_BF_OFF 8650752  // bf16 conv2_w [128kb][128e][64]
// end: 9175040 floats = 36.7 MB
// NOTE: k1 writes fp32 partials into Q/K/V/ATTN regions; k1b consumes them into
// XSRC before k2/k3 overwrite those regions. Launch order guarantees safety.

typedef __attribute__((ext_vector_type(8))) short short8;
typedef __attribute__((ext_vector_type(8))) unsigned short ushort8;
typedef __attribute__((ext_vector_type(4))) unsigned short us4;
typedef __attribute__((ext_vector_type(4))) float f32x4;
typedef _Float16 f16_t;
typedef __attribute__((ext_vector_type(4))) _Float16 half4;
typedef __attribute__((ext_vector_type(8))) _Float16 half8;

__device__ __forceinline__ float wave_sum(float v) {
    #pragma unroll
    for (int o = 32; o > 0; o >>= 1) v += __shfl_xor(v, o);
    return v;
}

__device__ __forceinline__ float gelu_exact(float x) {
    return 0.5f * x * (1.0f + erff(x * 0.7071067811865476f));
}

// x - x/(1+exp(2*inner)), constants pre-doubled
__device__ __forceinline__ float gelu_tanh(float x) {
    float x2 = x * x;
    float y = x * fmaf(0.0713548162f, x2, 1.5957691216f);
    float E = __expf(y);
    float r = __builtin_amdgcn_rcpf(E + 1.0f);
    return fmaf(-x, r, x);
}

__device__ __forceinline__ unsigned short f2bf(float f) {   // RNE fp32->bf16
    unsigned int u = __float_as_uint(f);
    unsigned int r = u + 0x7FFFu + ((u >> 16) & 1u);
    return (unsigned short)(r >> 16);
}

__device__ __forceinline__ float bf2f(unsigned short u) {
    return __uint_as_float(((unsigned int)u) << 16);
}

// generic weight cast fp32 -> bf16, chunk-major, pre-swizzled (m173 pattern)
__device__ __forceinline__ void castw_body(const float* __restrict__ src,
                                           unsigned short* __restrict__ dst, int K, int tid) {
    int g = tid & 7, e = (tid >> 3) & 127, rest = tid >> 10;
    int KB = K >> 6;
    int kb = rest % KB, nb = rest / KB;
    int col = nb * 128 + e;
    const float* s = src + (size_t)col * K + kb * 64 + ((g ^ (e & 7)) << 3);
    ushort8 v;
    #pragma unroll
    for (int j = 0; j < 8; j++) v[j] = f2bf(s[j]);
    *(ushort8*)&dst[(size_t)tid << 3] = v;
}

// ---------------- K0: ALL setup jobs fused (independent; branch on blockIdx) ----------------
__global__ __launch_bounds__(256) void k0_all(const float* __restrict__ conv1_w,
                                              const float* __restrict__ conv1_b,
                                              const float* __restrict__ bn1_g,
                                              const float* __restrict__ bn1_b,
                                              const float* __restrict__ bn1_m,
                                              const float* __restrict__ bn1_v,
                                              const float* __restrict__ conv2_w,
                                              const float* __restrict__ conv2_b,
                                              const float* __restrict__ bn2_g,
                                              const float* __restrict__ bn2_b,
                                              const float* __restrict__ bn2_m,
                                              const float* __restrict__ bn2_v,
                                              const float* __restrict__ wq,
                                              const float* __restrict__ wk,
                                              const float* __restrict__ wv,
                                              const float* __restrict__ ff_w1,
                                              const float* __restrict__ ff_w2,
                                              float* __restrict__ ws) {
    int bid = blockIdx.x, t = threadIdx.x;
    if (bid < 512) {                       // PE table
        int idx = bid * 256 + t;
        int s = idx >> 7, e = idx & 127;
        int i = e >> 1;
        float freq = expf((float)(2 * i) * (-9.210340371976184f / 128.0f));
        float ang = (float)s * freq * 0.125f;
        ws[PE_OFF + idx] = (e & 1) ? cosf(ang) : sinf(ang);
    } else if (bid < 515) {                // BN fold
        int u = (bid - 512) * 256 + t;
        if (u < 512) {
            float sc = bn1_g[u] * rsqrtf(bn1_v[u] + 1e-5f);
            ws[BN1SC_OFF + u] = sc;
            ws[BN1SH_OFF + u] = (conv1_b[u] - bn1_m[u]) * sc + bn1_b[u];
        } else if (u < 640) {
            int e = u - 512;
            float sc = bn2_g[e] * rsqrtf(bn2_v[e] + 1e-5f);
            ws[BN2SC_OFF + e] = sc;
            ws[BN2SH_OFF + e] = (conv2_b[e] - bn2_m[e]) * sc + bn2_b[e];
        }
    } else if (bid < 1027) {               // conv2_w cast (512 blocks)
        castw_body(conv2_w, (unsigned short*)(ws + W2CONV_BF_OFF), 8192, (bid - 515) * 256 + t);
    } else if (bid < 1035) {
        castw_body(wq, (unsigned short*)(ws + WQKV_BF_OFF), 128, (bid - 1027) * 256 + t);
    } else if (bid < 1043) {
        castw_body(wk, (unsigned short*)(ws + WQKV_BF_OFF) + 16384, 128, (bid - 1035) * 256 + t);
    } else if (bid < 1051) {
        castw_body(wv, (unsigned short*)(ws + WQKV_BF_OFF) + 32768, 128, (bid - 1043) * 256 + t);
    } else if (bid < 1083) {
        castw_body(ff_w1, (unsigned short*)(ws + W1FF_BF_OFF), 128, (bid - 1051) * 256 + t);
    } else if (bid < 1115) {
        castw_body(ff_w2, (unsigned short*)(ws + W2FF_BF_OFF), 512, (bid - 1083) * 256 + t);
    } else {                               // folded bf16 conv1 taps: w1p[o][u] = w1[o][u]*sc1[o]
        unsigned short* w1p = (unsigned short*)(ws + W1P_OFF);
        for (int id = t; id < 4096; id += 256) {
            int o = id >> 3, u = id & 7;
            float sc = bn1_g[o] * rsqrtf(bn1_v[o] + 1e-5f);
            float v = (u < 7) ? conv1_w[o * 7 + u] * sc : 0.f;
            w1p[id] = f2bf(v);
        }
    }
}

// ---------------- K1: fused conv1+bn1+gelu -> conv2 (bf16 MFMA), BARRIER-FREE main loop -----
// BM=64, 4 waves; wave w owns output rows [w*16, w*16+16) x ALL 128 e.
// A-fragment computed DIRECTLY in registers in MFMA layout: lane (lrow, lq) at chunk kbl,
// half ks2 holds k = ks2*32 + lq*8 + j  =>  o = kbl*4 + ks2*2 + (lq>>1), c = (lq&1)*8 + j.
// c-set is lane-constant => 56 x-taps hoisted to VGPRs once. No A-LDS, no barriers.
// B (w2 bf16, pre-swizzled) streamed global->regs. K-split x4, partials to Q/K/V/ATTN regions.
__global__ __launch_bounds__(256) void k1_mfma(const float* __restrict__ x,
                                               float* __restrict__ ws) {
    __shared__ float xt[CIN][72];                 // 4.5KB: x[b,c, s0-3 .. s0+66]
    __shared__ unsigned short w1ps[128 * 8];      // 2KB (this K-quarter's 128 o-rows)
    __shared__ float sh1s[128];                   // 0.5KB

    const int t = threadIdx.x;
    const int wave = t >> 6, lane = t & 63;
    const int row0 = blockIdx.x * 64;
    const int ksplit = blockIdx.y;                // K-quarter
    const int b = row0 >> 10, s0 = row0 & 1023;
    const int obase = ksplit * 128;

    for (int i = t; i < CIN * 70; i += 256) {
        int c = i / 70, j = i % 70;
        int gs = s0 + j - 3;
        xt[c][j] = (gs >= 0 && gs < SS) ? x[(b * CIN + c) * SS + gs] : 0.f;
    }
    if (t < 128) {
        *(ushort8*)&w1ps[t << 3] =
            ((const ushort8*)((const unsigned short*)(ws + W1P_OFF)))[obase + t];
        sh1s[t] = ws[BN1SH_OFF + obase + t];
    }
    __syncthreads();                              // the ONLY barrier

    const int lrow = lane & 15, lq = lane >> 4;
    const int srow_local = (wave << 4) + lrow;    // 0..63
    const int cbase = (lq & 1) << 3;

    // hoist the 56 x-taps (8 c x 7 u) for this lane's fixed row
    float xv[56];
    #pragma unroll
    for (int c8 = 0; c8 < 8; ++c8)
        #pragma unroll
        for (int u = 0; u < 7; ++u)
            xv[c8 * 7 + u] = xt[cbase + c8][srow_local + u];

    // lane-constant B byte offsets within a 16KB chunk: i = ks2*8+nf
    int boff[16];
    #pragma unroll
    for (int ks2 = 0; ks2 < 2; ++ks2) {
        int G = (ks2 << 2) + lq;
        #pragma unroll
        for (int nf = 0; nf < 8; ++nf) {
            int e = (nf << 4) + lrow;
            boff[ks2 * 8 + nf] = (e << 7) + ((G ^ (e & 7)) << 4);
        }
    }

    const char* w2g = (const char*)(ws + W2CONV_BF_OFF);
    const int olq = lq >> 1;

    auto computeA = [&](int kbl, int ks2) -> short8 {
        int ol = (kbl << 2) + (ks2 << 1) + olq;
        ushort8 w8 = *(const ushort8*)&w1ps[ol << 3];
        float w0 = bf2f(w8[0]), w1_ = bf2f(w8[1]), w2_ = bf2f(w8[2]), w3 = bf2f(w8[3]);
        float w4 = bf2f(w8[4]), w5 = bf2f(w8[5]), w6 = bf2f(w8[6]);
        float sh = sh1s[ol];
        short8 a;
        #pragma unroll
        for (int j = 0; j < 8; ++j) {
            float p = xv[j*7]   * w0 + xv[j*7+1] * w1_ + xv[j*7+2] * w2_ + xv[j*7+3] * w3
                    + xv[j*7+4] * w4 + xv[j*7+5] * w5 + xv[j*7+6] * w6;
            a[j] = (short)f2bf(gelu_tanh(p + sh));
        }
        return a;
    };

    f32x4 acc[8];
    #pragma unroll
    for (int i = 0; i < 8; ++i) acc[i] = (f32x4){0.f, 0.f, 0.f, 0.f};

    #pragma unroll 1
    for (int kbl = 0; kbl < 32; ++kbl) {
        const char* g = w2g + ((size_t)((ksplit << 5) + kbl) << 14);
        short8 bA_[8];
        #pragma unroll
        for (int i = 0; i < 8; ++i) bA_[i] = *(const short8*)(g + boff[i]);
        short8 a0 = computeA(kbl, 0);             // VALU overlaps the loads above
        short8 bB_[8];
        #pragma unroll
        for (int i = 0; i < 8; ++i) bB_[i] = *(const short8*)(g + boff[8 + i]);
        #pragma unroll
        for (int nf = 0; nf < 8; ++nf)
            acc[nf] = __builtin_amdgcn_mfma_f32_16x16x32_bf16(a0, bA_[nf], acc[nf], 0, 0, 0);
        short8 a1 = computeA(kbl, 1);
        #pragma unroll
        for (int nf = 0; nf < 8; ++nf)
            acc[nf] = __builtin_amdgcn_mfma_f32_16x16x32_bf16(a1, bB_[nf], acc[nf], 0, 0, 0);
    }

    // store fp32 partial (no bn2/gelu yet) into Q/K/V/ATTN region for this split
    float* P = ws + Q_OFF + (size_t)ksplit * 1048576;
    #pragma unroll
    for (int nf = 0; nf < 8; ++nf) {
        int e = (nf << 4) + lrow;
        #pragma unroll
        for (int r = 0; r < 4; ++r) {
            int srow = s0 + (wave << 4) + (lq << 2) + r;
            P[(((size_t)(b * SS + srow)) << 7) + e] = acc[nf][r];
        }
    }
}

// ---------------- K1b: combine 4 partials + bn2 + exact gelu -> x_src ----------------
__global__ __launch_bounds__(256) void k1b_combine(float* __restrict__ ws) {
    int f = (blockIdx.x * 256 + threadIdx.x) * 4;   // 1M elems
    int e0 = f & 127;
    float4 p0 = *(const float4*)&ws[Q_OFF + f];
    float4 p1 = *(const float4*)&ws[KK_OFF + f];
    float4 p2 = *(const float4*)&ws[V_OFF + f];
    float4 p3 = *(const float4*)&ws[ATTN_OFF + f];
    float4 sc = *(const float4*)&ws[BN2SC_OFF + e0];
    float4 sh = *(const float4*)&ws[BN2SH_OFF + e0];
    float4 o;
    o.x = gelu_exact(fmaf((p0.x + p1.x) + (p2.x + p3.x), sc.x, sh.x));
    o.y = gelu_exact(fmaf((p0.y + p1.y) + (p2.y + p3.y), sc.y, sh.y));
    o.z = gelu_exact(fmaf((p0.z + p1.z) + (p2.z + p3.z), sc.z, sh.z));
    o.w = gelu_exact(fmaf((p0.w + p1.w) + (p2.w + p3.w), sc.w, sh.w));
    *(float4*)&ws[XSRC_OFF + f] = o;
}

// ---------------- K2: QKV projection via MFMA -> f16 QH(scaled)/KH/VHT (vector stores) ------
__global__ __launch_bounds__(256) void k2_mfma(float* __restrict__ ws) {
    __shared__ unsigned short As[32 * 128];       // 8KB
    __shared__ unsigned short Bs[128 * 128];      // 32KB
    __shared__ float ys[32][132];                 // 16.9KB
    const int t = threadIdx.x;
    const int rt = blockIdx.x, mat = blockIdx.y;
    const int wave = t >> 6, lane = t & 63;

    const char* bg = (const char*)((const unsigned short*)(ws + WQKV_BF_OFF) + mat * 16384);
    #pragma unroll
    for (int c8 = 0; c8 < 8; ++c8) {
        int off = c8 * 4096 + wave * 1024;
        __builtin_amdgcn_global_load_lds(
            (const __attribute__((address_space(1))) unsigned int*)(bg + off + lane * 16),
            (__attribute__((address_space(3))) unsigned int*)(&Bs[off >> 1]), 16, 0, 0);
    }
    const int bs0 = rt * 32;
    const int sl0 = bs0 & 1023;
    for (int i = t; i < 1024; i += 256) {
        int row = i >> 5, d0 = (i & 31) << 2;
        float4 xvv = *(const float4*)&ws[XSRC_OFF + (size_t)(bs0 + row) * EE + d0];
        float4 pv = *(const float4*)&ws[PE_OFF + (size_t)(sl0 + row) * EE + d0];
        us4 o;
        o[0] = f2bf(xvv.x + pv.x); o[1] = f2bf(xvv.y + pv.y);
        o[2] = f2bf(xvv.z + pv.z); o[3] = f2bf(xvv.w + pv.w);
        int slot = (d0 >> 3) ^ (row & 7);
        *(us4*)&As[(row << 7) + (slot << 3) + (d0 & 7)] = o;
    }
    __syncthreads();

    const int wr = wave >> 1, wc = wave & 1;
    const int lrow = lane & 15, lq = lane >> 4;
    f32x4 acc[4];
    #pragma unroll
    for (int i = 0; i < 4; i++) acc[i] = (f32x4){0.f, 0.f, 0.f, 0.f};

    #pragma unroll
    for (int ksname = 0; ksname < 4; ++ksname) {
        int G = (ksname << 2) + lq;
        int arow = (wr << 4) + lrow;
        short8 a = *(const short8*)&As[(arow << 7) + ((G ^ (arow & 7)) << 3)];
        #pragma unroll
        for (int nf = 0; nf < 4; ++nf) {
            int e = (wc << 6) + (nf << 4) + lrow;
            short8 bf = *(const short8*)&Bs[((G >> 3) << 13) + (e << 6) + (((G & 7) ^ (e & 7)) << 3)];
            acc[nf] = __builtin_amdgcn_mfma_f32_16x16x32_bf16(a, bf, acc[nf], 0, 0, 0);
        }
    }

    // C-frag -> LDS (fp32) for vectorized transposed stores
    #pragma unroll
    for (int nf = 0; nf < 4; ++nf) {
        int e = (wc << 6) + (nf << 4) + lrow;
        #pragma unroll
        for (int r = 0; r < 4; ++r)
            ys[(wr << 4) + (lq << 2) + r][e] = acc[nf][r];
    }
    __syncthreads();

    const int b = bs0 >> 10;
    if (mat <= 1) {
        int row = t >> 3, h8 = t & 7;
        float scl = (mat == 0) ? 0.08838834764831845f : 1.0f;
        f16_t* dst = (f16_t*)(ws + (mat == 0 ? Q_OFF : KK_OFF))
                   + (((size_t)(b * HH + h8)) * SS + (sl0 + row)) * DHH;
        half8 v0, v1;
        #pragma unroll
        for (int d = 0; d < 8; d++) v0[d] = (f16_t)(ys[row][h8 * 16 + d] * scl);
        #pragma unroll
        for (int d = 0; d < 8; d++) v1[d] = (f16_t)(ys[row][h8 * 16 + 8 + d] * scl);
        *(half8*)&dst[0] = v0;
        *(half8*)&dst[8] = v1;
    } else {
        int c = t & 127, hf = t >> 7;
        int h8 = c >> 4, d2 = c & 15;
        f16_t* dst = (f16_t*)(ws + V_OFF)
                   + (((size_t)(b * HH + h8)) * DHH + d2) * SS + sl0 + hf * 16;
        half8 v0, v1;
        #pragma unroll
        for (int r = 0; r < 8; r++) v0[r] = (f16_t)ys[hf * 16 + r][c];
        #pragma unroll
        for (int r = 0; r < 8; r++) v1[r] = (f16_t)ys[hf * 16 + 8 + r][c];
        *(half8*)&dst[0] = v0;
        *(half8*)&dst[8] = v1;
    }
}

// ---------------- K3: flash softmax attention + fused rel-bias (mfma 16x16x16 f16) ----------
__global__ __launch_bounds__(256) void k3_attn(const float* __restrict__ rel_tab,
                                               float* __restrict__ ws) {
    __shared__ f16_t rtbl4[4][1088];              // 4 shifted copies for aligned b64 reads
    const int bh = blockIdx.x;                    // b*H + h
    const int h = bh & 7, b = bh >> 3;
    const int i0b = blockIdx.y * 64;
    const int t = threadIdx.x;
    for (int id = t; id < 4 * 1088; id += 256) {
        int p = id / 1088; int j = id - p * 1088;
        int u = j + p;
        float v = (u < 1087) ? rel_tab[(i0b + 1086 - u) * HH + h] : 0.f;
        rtbl4[p][j] = (f16_t)v;
    }
    __syncthreads();

    const int w = t >> 6, lane = t & 63;
    const int q = lane & 15, g = lane >> 4;
    const int r = w * 16 + q;
    const int i = i0b + r;

    const f16_t* QH  = (const f16_t*)(ws + Q_OFF)  + (size_t)bh * SS * DHH;
    const f16_t* KH  = (const f16_t*)(ws + KK_OFF) + (size_t)bh * SS * DHH;
    const f16_t* VHT = (const f16_t*)(ws + V_OFF)  + (size_t)bh * DHH * SS;

    half4 qf = *(const half4*)&QH[(size_t)i * DHH + 4 * g];
    f32x4 o = {0.f, 0.f, 0.f, 0.f};
    f32x4 bv = {0.f, 0.f, 0.f, 0.f};
    const f32x4 zf = {0.f, 0.f, 0.f, 0.f};
    float lp = 0.f;
    const int p4 = (63 - r + 4 * g) & 3;          // vb mod 4, lane-constant

    #pragma unroll 4
    for (int jt = 0; jt < 64; ++jt) {
        half4 kf = *(const half4*)&KH[(size_t)(jt * 16 + q) * DHH + 4 * g];
        f32x4 s = __builtin_amdgcn_mfma_f32_16x16x16f16(kf, qf, zf, 0, 0, 0);
        float p0 = __expf(s[0]), p1 = __expf(s[1]), p2 = __expf(s[2]), p3 = __expf(s[3]);
        lp += (p0 + p1) + (p2 + p3);
        half4 pf;
        pf[0] = (f16_t)p0; pf[1] = (f16_t)p1; pf[2] = (f16_t)p2; pf[3] = (f16_t)p3;
        half4 vf = *(const half4*)&VHT[(size_t)q * SS + jt * 16 + 4 * g];
        o = __builtin_amdgcn_mfma_f32_16x16x16f16(vf, pf, o, 0, 0, 0);
        int vb = 63 - r + jt * 16 + 4 * g;
        half4 bfrag = *(const half4*)&rtbl4[p4][vb & ~3];
        bv = __builtin_amdgcn_mfma_f32_16x16x16f16(vf, bfrag, bv, 0, 0, 0);
    }
    lp += __shfl_xor(lp, 16);
    lp += __shfl_xor(lp, 32);
    float inv = 1.f / lp;
    float4 ov = make_float4(fmaf(o[0], inv, bv[0]), fmaf(o[1], inv, bv[1]),
                            fmaf(o[2], inv, bv[2]), fmaf(o[3], inv, bv[3]));
    *(float4*)&ws[ATTN_OFF + ((size_t)(b * SS) + i) * EE + h * DHH + 4 * g] = ov;
}

// ---------------- K4: LN(attn) -> +x_src -> LN1 -> att ----------------
__global__ __launch_bounds__(256) void k4_ln(const float* __restrict__ g_attn, const float* __restrict__ b_attn,
                                             const float* __restrict__ g1, const float* __restrict__ b1,
                                             float* __restrict__ ws) {
    int row = blockIdx.x * 4 + (threadIdx.x >> 6);
    int lane = threadIdx.x & 63;
    int e0 = lane * 2;
    const float* ain = ws + ATTN_OFF + (size_t)row * EE;
    const float* xsr = ws + XSRC_OFF + (size_t)row * EE;
    float2 a = *(const float2*)(ain + e0);
    float mean = wave_sum(a.x + a.y) * (1.f / 128.f);
    float dx = a.x - mean, dy = a.y - mean;
    float var = wave_sum(dx * dx + dy * dy) * (1.f / 128.f);
    float inv = rsqrtf(var + 1e-5f);
    float n0 = dx * inv * g_attn[e0] + b_attn[e0];
    float n1 = dy * inv * g_attn[e0 + 1] + b_attn[e0 + 1];
    float2 xs2 = *(const float2*)(xsr + e0);
    float z0 = xs2.x + n0, z1 = xs2.y + n1;
    float m2 = wave_sum(z0 + z1) * (1.f / 128.f);
    float d0 = z0 - m2, d1 = z1 - m2;
    float v2 = wave_sum(d0 * d0 + d1 * d1) * (1.f / 128.f);
    float inv2 = rsqrtf(v2 + 1e-5f);
    float o0 = d0 * inv2 * g1[e0] + b1[e0];
    float o1 = d1 * inv2 * g1[e0 + 1] + b1[e0 + 1];
    *(float2*)(ws + ATT_OFF + (size_t)row * EE + e0) = make_float2(o0, o1);
}

// ---------------- K5: FF1 via MFMA + bias + relu -> bf16 swizzled FFHB (vector stores) ------
__global__ __launch_bounds__(256) void k5_mfma(const float* __restrict__ b1,
                                               float* __restrict__ ws) {
    __shared__ unsigned short As[32 * 128];
    __shared__ unsigned short Bs[128 * 128];
    __shared__ float ys[32][132];
    const int t = threadIdx.x;
    const int rt = blockIdx.x, nb = blockIdx.y;
    const int wave = t >> 6, lane = t & 63;

    const char* bg = (const char*)((const unsigned short*)(ws + W1FF_BF_OFF) + nb * 16384);
    #pragma unroll
    for (int c8 = 0; c8 < 8; ++c8) {
        int off = c8 * 4096 + wave * 1024;
        __builtin_amdgcn_global_load_lds(
            (const __attribute__((address_space(1))) unsigned int*)(bg + off + lane * 16),
            (__attribute__((address_space(3))) unsigned int*)(&Bs[off >> 1]), 16, 0, 0);
    }
    const int bs0 = rt * 32;
    for (int i = t; i < 1024; i += 256) {
        int row = i >> 5, d0 = (i & 31) << 2;
        float4 xvv = *(const float4*)&ws[ATT_OFF + (size_t)(bs0 + row) * EE + d0];
        us4 o;
        o[0] = f2bf(xvv.x); o[1] = f2bf(xvv.y); o[2] = f2bf(xvv.z); o[3] = f2bf(xvv.w);
        int slot = (d0 >> 3) ^ (row & 7);
        *(us4*)&As[(row << 7) + (slot << 3) + (d0 & 7)] = o;
    }
    __syncthreads();

    const int wr = wave >> 1, wc = wave & 1;
    const int lrow = lane & 15, lq = lane >> 4;
    f32x4 acc[4];
    #pragma unroll
    for (int i = 0; i < 4; i++) acc[i] = (f32x4){0.f, 0.f, 0.f, 0.f};

    #pragma unroll
    for (int ksname = 0; ksname < 4; ++ksname) {
        int G = (ksname << 2) + lq;
        int arow = (wr << 4) + lrow;
        short8 a = *(const short8*)&As[(arow << 7) + ((G ^ (arow & 7)) << 3)];
        #pragma unroll
        for (int nf = 0; nf < 4; ++nf) {
            int e = (wc << 6) + (nf << 4) + lrow;
            short8 bf = *(const short8*)&Bs[((G >> 3) << 13) + (e << 6) + (((G & 7) ^ (e & 7)) << 3)];
            acc[nf] = __builtin_amdgcn_mfma_f32_16x16x32_bf16(a, bf, acc[nf], 0, 0, 0);
        }
    }

    #pragma unroll
    for (int nf = 0; nf < 4; ++nf) {
        int col = (wc << 6) + (nf << 4) + lrow;
        float bias = b1[(nb << 7) + col];
        #pragma unroll
        for (int r = 0; r < 4; ++r)
            ys[(wr << 4) + (lq << 2) + r][col] = fmaxf(acc[nf][r] + bias, 0.f);
    }
    __syncthreads();

    unsigned short* ffhb = (unsigned short*)(ws + FFH_OFF);
    #pragma unroll
    for (int kk = 0; kk < 2; ++kk) {
        int id = t + kk * 256;
        int ssr = id >> 4, fg = id & 15;
        float4 v0 = *(const float4*)&ys[ssr][fg * 8];
        float4 v1 = *(const float4*)&ys[ssr][fg * 8 + 4];
        ushort8 ov;
        ov[0] = f2bf(v0.x); ov[1] = f2bf(v0.y); ov[2] = f2bf(v0.z); ov[3] = f2bf(v0.w);
        ov[4] = f2bf(v1.x); ov[5] = f2bf(v1.y); ov[6] = f2bf(v1.z); ov[7] = f2bf(v1.w);
        int kb = (nb << 1) + (fg >> 3);
        int slot = (fg & 7) ^ (ssr & 7);
        *(ushort8*)&ffhb[(((size_t)(rt * 8 + kb) * 32 + ssr) << 6) + (slot << 3)] = ov;
    }
}

// ---------------- K6: FF2 via MFMA + bias + residual + LN2 + transposed store ----------------
__global__ __launch_bounds__(256) void k6_mfma(const float* __restrict__ b2,
                                               const float* __restrict__ g2, const float* __restrict__ bb2,
                                               float* __restrict__ ws, float* __restrict__ out) {
    __shared__ unsigned short Ab[2][2048];    // 2x4KB
    __shared__ unsigned short Bb[2][8192];    // 2x16KB
    __shared__ float y[32][132];              // 16.9KB
    const int t = threadIdx.x;
    const int wave = t >> 6, lane = t & 63;
    const int rt = blockIdx.x;

    const char* ag = (const char*)((const unsigned short*)(ws + FFH_OFF) + (size_t)rt * 16384);
    const char* bgc = (const char*)(ws + W2FF_BF_OFF);

    auto stage = [&](int kb, int buf) {
        __builtin_amdgcn_global_load_lds(
            (const __attribute__((address_space(1))) unsigned int*)(ag + kb * 4096 + t * 16),
            (__attribute__((address_space(3))) unsigned int*)(&Ab[buf][(t * 16) >> 1]), 16, 0, 0);
        const char* g = bgc + kb * 16384;
        #pragma unroll
        for (int c4 = 0; c4 < 4; ++c4) {
            int off = c4 * 4096 + wave * 1024;
            __builtin_amdgcn_global_load_lds(
                (const __attribute__((address_space(1))) unsigned int*)(g + off + lane * 16),
                (__attribute__((address_space(3))) unsigned int*)(&Bb[buf][off >> 1]), 16, 0, 0);
        }
    };

    const int wr = wave >> 1, wc = wave & 1;
    const int lrow = lane & 15, lq = lane >> 4;
    f32x4 acc[4];
    #pragma unroll
    for (int i = 0; i < 4; i++) acc[i] = (f32x4){0.f, 0.f, 0.f, 0.f};

    stage(0, 0);
    __syncthreads();
    for (int kb = 0; kb < 8; ++kb) {
        int cur = kb & 1;
        if (kb < 7) stage(kb + 1, cur ^ 1);
        #pragma unroll
        for (int ksname = 0; ksname < 2; ++ksname) {
            int G = (ksname << 2) + lq;
            int arow = (wr << 4) + lrow;
            short8 a = *(const short8*)&Ab[cur][(arow << 6) + ((G ^ (arow & 7)) << 3)];
            #pragma unroll
            for (int nf = 0; nf < 4; ++nf) {
                int e = (wc << 6) + (nf << 4) + lrow;
                short8 bf = *(const short8*)&Bb[cur][(e << 6) + ((G ^ (e & 7)) << 3)];
                acc[nf] = __builtin_amdgcn_mfma_f32_16x16x32_bf16(a, bf, acc[nf], 0, 0, 0);
            }
        }
        __syncthreads();
    }

    const int bs0 = rt * 32;
    #pragma unroll
    for (int nf = 0; nf < 4; ++nf) {
        int e = (wc << 6) + (nf << 4) + lrow;
        float bvv = b2[e];
        #pragma unroll
        for (int r = 0; r < 4; ++r) {
            int row = (wr << 4) + (lq << 2) + r;
            y[row][e] = acc[nf][r] + bvv + ws[ATT_OFF + (size_t)(bs0 + row) * EE + e];
        }
    }
    __syncthreads();
    int e0 = lane * 2;
    for (int rr = 0; rr < 8; rr++) {
        int row = wave * 8 + rr;
        float z0 = y[row][e0], z1 = y[row][e0 + 1];
        float mean = wave_sum(z0 + z1) * (1.f / 128.f);
        float d0 = z0 - mean, d1 = z1 - mean;
        float var = wave_sum(d0 * d0 + d1 * d1) * (1.f / 128.f);
        float inv = rsqrtf(var + 1e-5f);
        y[row][e0]     = d0 * inv * g2[e0] + bb2[e0];
        y[row][e0 + 1] = d1 * inv * g2[e0 + 1] + bb2[e0 + 1];
    }
    __syncthreads();
    int b = bs0 >> 10, s0 = bs0 & 1023;
    int sl = t & 31, eg = t >> 5;
    #pragma unroll
    for (int rep = 0; rep < 16; rep++) {
        int e = eg * 16 + rep;
        out[(size_t)b * EE * SS + (size_t)e * SS + s0 + sl] = y[sl][e];
    }
}

extern "C" void kernel_launch(void* const* d_in, const int* in_sizes, int n_in,
                              void* d_out, int out_size, void* d_ws, size_t ws_size,
                              hipStream_t stream) {
    const float* x        = (const float*)d_in[0];
    const float* conv1_w  = (const float*)d_in[1];
    const float* conv1_b  = (const float*)d_in[2];
    const float* bn1_g    = (const float*)d_in[3];
    const float* bn1_b    = (const float*)d_in[4];
    const float* bn1_m    = (const float*)d_in[5];
    const float* bn1_v    = (const float*)d_in[6];
    const float* conv2_w  = (const float*)d_in[7];
    const float* conv2_b  = (const float*)d_in[8];
    const float* bn2_g    = (const float*)d_in[9];
    const float* bn2_b    = (const float*)d_in[10];
    const float* bn2_m    = (const float*)d_in[11];
    const float* bn2_v    = (const float*)d_in[12];
    const float* wq       = (const float*)d_in[13];
    const float* wk       = (const float*)d_in[14];
    const float* wv       = (const float*)d_in[15];
    const float* rel_tab  = (const float*)d_in[16];
    const float* ln_attn_g = (const float*)d_in[17];
    const float* ln_attn_b = (const float*)d_in[18];
    const float* ln1_g    = (const float*)d_in[19];
    const float* ln1_b    = (const float*)d_in[20];
    const float* ln2_g    = (const float*)d_in[21];
    const float* ln2_b    = (const float*)d_in[22];
    const float* ff_w1    = (const float*)d_in[23];
    const float* ff_b1    = (const float*)d_in[24];
    const float* ff_w2    = (const float*)d_in[25];
    const float* ff_b2    = (const float*)d_in[26];

    float* ws  = (float*)d_ws;
    float* out = (float*)d_out;

    hipLaunchKernelGGL(k0_all, dim3(1116), dim3(256), 0, stream,
                       conv1_w, conv1_b, bn1_g, bn1_b, bn1_m, bn1_v,
                       conv2_w, conv2_b, bn2_g, bn2_b, bn2_m, bn2_v,
                       wq, wk, wv, ff_w1, ff_w2, ws);
    hipLaunchKernelGGL(k1_mfma, dim3(128, 4), dim3(256), 0, stream, x, ws);
    hipLaunchKernelGGL(k1b_combine, dim3(1024), dim3(256), 0, stream, ws);
    hipLaunchKernelGGL(k2_mfma, dim3(256, 3), dim3(256), 0, stream, ws);
    hipLaunchKernelGGL(k3_attn, dim3(BB * HH, SS / 64), dim3(256), 0, stream, rel_tab, ws);
    hipLaunchKernelGGL(k4_ln, dim3(BB * SS / 4), dim3(256), 0, stream, ln_attn_g, ln_attn_b, ln1_g, ln1_b, ws);
    hipLaunchKernelGGL(k5_mfma, dim3(256, 4), dim3(256), 0, stream, ff_b1, ws);
    hipLaunchKernelGGL(k6_mfma, dim3(256), dim3(256), 0, stream, ff_b2, ln2_g, ln2_b, ws, out);
}